// Round 3
// baseline (3071.975 us; speedup 1.0000x reference)
//
#include <hip/hip_runtime.h>
#include <hip/hip_bf16.h>

typedef __hip_bfloat16 bf16;
typedef __hip_bfloat162 bf162;

#define N_AUTHOR 20000
#define N_PAPER  40000
#define NEDGE    400000
#define HID      128
#define HEADS    8
#define DIMH     16
#define NCLS     16

__device__ __forceinline__ void stf(float* p, float v){ *p = v; }
__device__ __forceinline__ void stf(bf16* p, float v){ *p = __float2bfloat16(v); }

// ---------------------------------------------------------------------------
// Skinny GEMM: C[M,128] = act(A[M,K]) @ W[K,128] + bias   (all inputs f32)
// EPI==0: store C (type TC: float or bf16).
// EPI==1: tanh epilogue, dot with q, block-reduce, atomicAdd to score.
// RELU_A: relu on A load (klin consumes relu(agg) without materializing it)
// ---------------------------------------------------------------------------
template<typename TC, int K, bool RELU_A, int EPI>
__global__ __launch_bounds__(256) void gemm_kernel(
    const float* __restrict__ A, const float* __restrict__ W, const float* __restrict__ B,
    TC* __restrict__ C, const float* __restrict__ qv, float* __restrict__ score, int M)
{
    __shared__ float As[64][33];
    __shared__ float Ws[32][129];
    const int tid = threadIdx.x;
    const int tx = tid & 15;        // col group: 8 consecutive cols
    const int ty = tid >> 4;        // row group: 4 consecutive rows
    const int row0 = blockIdx.x * 64;

    float acc[4][8];
    #pragma unroll
    for (int r = 0; r < 4; r++)
        #pragma unroll
        for (int c = 0; c < 8; c++) acc[r][c] = 0.f;

    for (int k0 = 0; k0 < K; k0 += 32) {
        #pragma unroll
        for (int i = 0; i < 8; i++) {
            int idx = tid * 8 + i;          // 0..2047 -> 64x32 tile
            int r = idx >> 5, k = idx & 31;
            int gr = row0 + r;
            float v = 0.f;
            if (gr < M) v = A[(long)gr * K + k0 + k];
            if (RELU_A) v = fmaxf(v, 0.f);
            As[r][k] = v;
        }
        #pragma unroll
        for (int i = 0; i < 16; i++) {
            int idx = tid * 16 + i;         // 0..4095 -> 32x128 tile
            int k = idx >> 7, c = idx & 127;
            Ws[k][c] = W[(k0 + k) * HID + c];
        }
        __syncthreads();
        #pragma unroll 8
        for (int kk = 0; kk < 32; kk++) {
            float a0 = As[ty*4+0][kk];
            float a1 = As[ty*4+1][kk];
            float a2 = As[ty*4+2][kk];
            float a3 = As[ty*4+3][kk];
            #pragma unroll
            for (int c = 0; c < 8; c++) {
                float w = Ws[kk][tx*8+c];
                acc[0][c] = fmaf(a0, w, acc[0][c]);
                acc[1][c] = fmaf(a1, w, acc[1][c]);
                acc[2][c] = fmaf(a2, w, acc[2][c]);
                acc[3][c] = fmaf(a3, w, acc[3][c]);
            }
        }
        __syncthreads();
    }

    float bcol[8];
    #pragma unroll
    for (int c = 0; c < 8; c++) bcol[c] = B ? B[tx*8+c] : 0.f;

    if (EPI == 0) {
        #pragma unroll
        for (int r = 0; r < 4; r++) {
            int gr = row0 + ty*4 + r;
            if (gr < M) {
                #pragma unroll
                for (int c = 0; c < 8; c++)
                    stf(&C[(long)gr * HID + tx*8 + c], acc[r][c] + bcol[c]);
            }
        }
    } else {
        float qc[8];
        #pragma unroll
        for (int c = 0; c < 8; c++) qc[c] = qv[tx*8+c];
        float part = 0.f;
        #pragma unroll
        for (int r = 0; r < 4; r++) {
            int gr = row0 + ty*4 + r;
            if (gr < M) {
                #pragma unroll
                for (int c = 0; c < 8; c++)
                    part += qc[c] * tanhf(acc[r][c] + bcol[c]);
            }
        }
        __shared__ float red[256];
        red[tid] = part;
        __syncthreads();
        for (int s = 128; s > 0; s >>= 1) {
            if (tid < s) red[tid] += red[tid + s];
            __syncthreads();
        }
        if (tid == 0) atomicAdd(score, red[0]);
    }
}

// a[n,h] = sum_d xh[n, h*16+d] * att[h,d]   (xh in bf16, att f32)
__global__ void node_att_kernel(const bf16* __restrict__ xh, const float* __restrict__ att,
                                float* __restrict__ out, int N)
{
    int i = blockIdx.x * blockDim.x + threadIdx.x;
    if (i >= N * HEADS) return;
    int n = i >> 3, h = i & 7;
    const bf16* row = xh + (long)n * HID + h * DIMH;
    float s = 0.f;
    #pragma unroll
    for (int d = 0; d < DIMH; d++)
        s += __bfloat162float(row[d]) * att[h*DIMH + d];
    out[i] = s;
}

// denom[d,h] += exp(leaky(a_src[s,h] + a_dst[d,h]))
__global__ void edge_denom_kernel(const int* __restrict__ si, const int* __restrict__ di,
                                  const float* __restrict__ as_, const float* __restrict__ ad_,
                                  float* __restrict__ denom, int E)
{
    int e = blockIdx.x * blockDim.x + threadIdx.x;
    if (e >= E) return;
    int s = si[e], d = di[e];
    const float4* ps = (const float4*)(as_ + (long)s * 8);
    const float4* pd = (const float4*)(ad_ + (long)d * 8);
    float4 s0 = ps[0], s1 = ps[1], d0 = pd[0], d1 = pd[1];
    float al[8] = { s0.x+d0.x, s0.y+d0.y, s0.z+d0.z, s0.w+d0.w,
                    s1.x+d1.x, s1.y+d1.y, s1.z+d1.z, s1.w+d1.w };
    #pragma unroll
    for (int h = 0; h < 8; h++) {
        float a = al[h];
        a = a >= 0.f ? a : 0.2f * a;
        a = fminf(a, 60.f);
        atomicAdd(&denom[(long)d * 8 + h], __expf(a));
    }
}

// one wave per edge: agg[d,:] += (exp(alpha)/denom) * xh[s,:]   (xh in bf16)
__global__ __launch_bounds__(256) void edge_scatter_kernel(
    const int* __restrict__ si, const int* __restrict__ di,
    const float* __restrict__ as_, const float* __restrict__ ad_,
    const float* __restrict__ denom, const bf16* __restrict__ xh,
    float* __restrict__ agg, int E)
{
    int gid = blockIdx.x * blockDim.x + threadIdx.x;
    int e = gid >> 6;
    int lane = gid & 63;
    if (e >= E) return;
    int s = si[e], d = di[e];
    int h = lane >> 3;                       // head of feature pair (2*lane, 2*lane+1)
    float a = as_[(long)s * 8 + h] + ad_[(long)d * 8 + h];
    a = a >= 0.f ? a : 0.2f * a;
    a = fminf(a, 60.f);
    float w = __expf(a) / (denom[(long)d * 8 + h] + 1e-16f);
    bf162 x2 = *(const bf162*)(xh + (long)s * HID + lane * 2);
    atomicAdd(&agg[(long)d * HID + lane*2],     __bfloat162float(x2.x) * w);
    atomicAdd(&agg[(long)d * HID + lane*2 + 1], __bfloat162float(x2.y) * w);
}

// paper semantic combine: softmax over 2 metapath scores, blend relu(agg); in-place safe
__global__ void combine_kernel(const float* __restrict__ a0, const float* __restrict__ a1,
                               const float* __restrict__ score, float* __restrict__ out, int n)
{
    int i = blockIdx.x * blockDim.x + threadIdx.x;
    if (i >= n) return;
    float s0 = score[0] * (1.f / N_PAPER);
    float s1 = score[1] * (1.f / N_PAPER);
    float m = fmaxf(s0, s1);
    float e0 = __expf(s0 - m), e1 = __expf(s1 - m);
    float inv = 1.f / (e0 + e1);
    out[i] = fmaxf(a0[i], 0.f) * (e0 * inv) + fmaxf(a1[i], 0.f) * (e1 * inv);
}

__global__ void relu_inplace_kernel(float* __restrict__ p, int n)
{
    int i = blockIdx.x * blockDim.x + threadIdx.x;
    if (i < n) p[i] = fmaxf(p[i], 0.f);
}

__global__ void zero_kernel(float4* __restrict__ p, int n4)
{
    int i = blockIdx.x * blockDim.x + threadIdx.x;
    if (i < n4) p[i] = make_float4(0.f, 0.f, 0.f, 0.f);
}

// out[n,c] = x[n,:] @ lin_w[:,c] + lin_b[c]  (f32 out)
__global__ __launch_bounds__(256) void final_lin_kernel(
    const float* __restrict__ X, const float* __restrict__ W,
    const float* __restrict__ B, float* __restrict__ out)
{
    __shared__ float Ws[HID * NCLS];
    int tid = threadIdx.x;
    for (int i = tid; i < HID * NCLS; i += 256) Ws[i] = W[i];
    __syncthreads();
    int i = blockIdx.x * 256 + tid;
    if (i >= N_PAPER * NCLS) return;
    int n = i >> 4, c = i & 15;
    float acc = B[c];
    const float* x = X + (long)n * HID;
    #pragma unroll 16
    for (int k = 0; k < HID; k++) acc = fmaf(x[k], Ws[k * NCLS + c], acc);
    out[i] = acc;
}

extern "C" void kernel_launch(void* const* d_in, const int* in_sizes, int n_in,
                              void* d_out, int out_size, void* d_ws, size_t ws_size,
                              hipStream_t stream)
{
    const float* x_author = (const float*)d_in[0];
    const float* x_paper  = (const float*)d_in[1];
    const float* Wa       = (const float*)d_in[2];
    const float* proj_w   = (const float*)d_in[3];
    const float* proj_b   = (const float*)d_in[4];
    const float* att_src  = (const float*)d_in[5];
    const float* att_dst  = (const float*)d_in[6];
    const float* klin_w   = (const float*)d_in[7];
    const float* klin_b   = (const float*)d_in[8];
    const float* qv       = (const float*)d_in[9];
    const float* lin_w    = (const float*)d_in[10];
    const float* lin_b    = (const float*)d_in[11];
    const int*  ei_w      = (const int*)d_in[12];
    const int*  ei_wb     = (const int*)d_in[13];
    const int*  ei_c      = (const int*)d_in[14];
    float* out = (float*)d_out;
    (void)ws_size; (void)in_sizes; (void)n_in; (void)out_size;

    // --- byte-based workspace allocator, 256B aligned chunks (~76 MB total) ---
    char* base = (char*)d_ws;
    size_t off = 0;
    auto alloc = [&](size_t bytes) {
        void* p = base + off;
        off = (off + bytes + 255) & ~(size_t)255;
        return p;
    };
    // read-mostly region (fully written before read every layer)
    bf16*  xh_a  = (bf16*) alloc((size_t)N_AUTHOR * HID * 2);
    bf16*  xh_p  = (bf16*) alloc((size_t)N_PAPER  * HID * 2);
    float* a_e0s = (float*)alloc((size_t)N_AUTHOR * HEADS * 4);
    float* a_e0d = (float*)alloc((size_t)N_PAPER  * HEADS * 4);
    float* a_e1s = (float*)alloc((size_t)N_PAPER  * HEADS * 4);
    float* a_e1d = (float*)alloc((size_t)N_AUTHOR * HEADS * 4);
    float* a_e2s = (float*)alloc((size_t)N_PAPER  * HEADS * 4);
    float* a_e2d = (float*)alloc((size_t)N_PAPER  * HEADS * 4);
    // zero region (contiguous; zeroed after proj gemms each layer)
    size_t zero_begin = off;
    float* buf_a  = (float*)alloc((size_t)N_AUTHOR * HID * 4);  // cur_a / agg_a
    float* buf_p  = (float*)alloc((size_t)N_PAPER  * HID * 4);  // cur_p / agg_p0
    float* agg_p1 = (float*)alloc((size_t)N_PAPER  * HID * 4);
    float* den_e0 = (float*)alloc((size_t)N_PAPER  * HEADS * 4);
    float* den_e1 = (float*)alloc((size_t)N_AUTHOR * HEADS * 4);
    float* den_e2 = (float*)alloc((size_t)N_PAPER  * HEADS * 4);
    float* score  = (float*)alloc(64);
    size_t zero_bytes = off - zero_begin;          // multiple of 256
    int zero_n4 = (int)(zero_bytes / 16);

    const int GA = (N_AUTHOR + 63) / 64;   // 313
    const int GP = (N_PAPER  + 63) / 64;   // 625
    const int GE  = (NEDGE + 255) / 256;
    const int GES = NEDGE / 4;             // wave per edge, 4 waves/block

    // input projection: author 64 -> 128 (f32 into buf_a); paper uses x_paper directly
    gemm_kernel<float, 64, false, 0><<<GA, 256, 0, stream>>>(
        x_author, Wa, nullptr, buf_a, nullptr, nullptr, N_AUTHOR);

    for (int l = 0; l < 2; l++) {
        const bool last = (l == 1);
        const float* cur_a = buf_a;
        const float* cur_p = (l == 0) ? x_paper : buf_p;
        const float* pw_a = proj_w + (size_t)(l*2 + 0) * HID * HID;
        const float* pw_p = proj_w + (size_t)(l*2 + 1) * HID * HID;
        const float* pb_a = proj_b + (size_t)(l*2 + 0) * HID;
        const float* pb_p = proj_b + (size_t)(l*2 + 1) * HID;

        // projection reads cur_*, writes xh_* (bf16); buf_* dead afterwards
        gemm_kernel<bf16, 128, false, 0><<<GA, 256, 0, stream>>>(
            cur_a, pw_a, pb_a, xh_a, nullptr, nullptr, N_AUTHOR);
        gemm_kernel<bf16, 128, false, 0><<<GP, 256, 0, stream>>>(
            cur_p, pw_p, pb_p, xh_p, nullptr, nullptr, N_PAPER);

        // reuse buf_* as aggregation buffers: zero agg + denom + score
        zero_kernel<<<(zero_n4 + 255)/256, 256, 0, stream>>>((float4*)(base + zero_begin), zero_n4);

        const float* as0 = att_src + (size_t)(l*3 + 0) * HID;
        const float* ad0 = att_dst + (size_t)(l*3 + 0) * HID;
        const float* as1 = att_src + (size_t)(l*3 + 1) * HID;
        const float* ad1 = att_dst + (size_t)(l*3 + 1) * HID;
        const float* as2 = att_src + (size_t)(l*3 + 2) * HID;
        const float* ad2 = att_dst + (size_t)(l*3 + 2) * HID;

        node_att_kernel<<<(N_AUTHOR*HEADS + 255)/256, 256, 0, stream>>>(xh_a, as0, a_e0s, N_AUTHOR);
        node_att_kernel<<<(N_PAPER *HEADS + 255)/256, 256, 0, stream>>>(xh_p, ad0, a_e0d, N_PAPER);
        if (!last) {
            node_att_kernel<<<(N_PAPER *HEADS + 255)/256, 256, 0, stream>>>(xh_p, as1, a_e1s, N_PAPER);
            node_att_kernel<<<(N_AUTHOR*HEADS + 255)/256, 256, 0, stream>>>(xh_a, ad1, a_e1d, N_AUTHOR);
        }
        node_att_kernel<<<(N_PAPER*HEADS + 255)/256, 256, 0, stream>>>(xh_p, as2, a_e2s, N_PAPER);
        node_att_kernel<<<(N_PAPER*HEADS + 255)/256, 256, 0, stream>>>(xh_p, ad2, a_e2d, N_PAPER);

        edge_denom_kernel<<<GE, 256, 0, stream>>>(ei_w,  ei_w  + NEDGE, a_e0s, a_e0d, den_e0, NEDGE);
        if (!last)
            edge_denom_kernel<<<GE, 256, 0, stream>>>(ei_wb, ei_wb + NEDGE, a_e1s, a_e1d, den_e1, NEDGE);
        edge_denom_kernel<<<GE, 256, 0, stream>>>(ei_c,  ei_c  + NEDGE, a_e2s, a_e2d, den_e2, NEDGE);

        // scatter: e0 author->paper (agg=buf_p); e1 paper->author (buf_a); e2 paper->paper (agg_p1)
        edge_scatter_kernel<<<GES, 256, 0, stream>>>(ei_w,  ei_w  + NEDGE, a_e0s, a_e0d, den_e0, xh_a, buf_p, NEDGE);
        if (!last)
            edge_scatter_kernel<<<GES, 256, 0, stream>>>(ei_wb, ei_wb + NEDGE, a_e1s, a_e1d, den_e1, xh_p, buf_a, NEDGE);
        edge_scatter_kernel<<<GES, 256, 0, stream>>>(ei_c,  ei_c  + NEDGE, a_e2s, a_e2d, den_e2, xh_p, agg_p1, NEDGE);

        // paper semantic attention scores (author has M=1 -> weight 1, skip)
        const float* kw = klin_w + (size_t)l * HID * HID;
        const float* kb = klin_b + (size_t)l * HID;
        const float* qq = qv     + (size_t)l * HID;
        gemm_kernel<float, 128, true, 1><<<GP, 256, 0, stream>>>(
            buf_p, kw, kb, (float*)nullptr, qq, score + 0, N_PAPER);
        gemm_kernel<float, 128, true, 1><<<GP, 256, 0, stream>>>(
            agg_p1, kw, kb, (float*)nullptr, qq, score + 1, N_PAPER);

        // combine writes buf_p in place (elementwise); relu buf_a in place
        combine_kernel<<<(N_PAPER*HID + 255)/256, 256, 0, stream>>>(buf_p, agg_p1, score, buf_p, N_PAPER*HID);
        if (!last)
            relu_inplace_kernel<<<(N_AUTHOR*HID + 255)/256, 256, 0, stream>>>(buf_a, N_AUTHOR*HID);
    }

    final_lin_kernel<<<(N_PAPER*NCLS + 255)/256, 256, 0, stream>>>(buf_p, lin_w, lin_b, out);
}

// Round 4
// 1068.152 us; speedup vs baseline: 2.8760x; 2.8760x over previous
//
#include <hip/hip_runtime.h>
#include <hip/hip_bf16.h>

typedef __hip_bfloat16 bf16;
typedef __hip_bfloat162 bf162;

#define N_AUTHOR 20000
#define N_PAPER  40000
#define NEDGE    400000
#define HID      128
#define HEADS    8
#define DIMH     16
#define NCLS     16

__device__ __forceinline__ void stf(float* p, float v){ *p = v; }
__device__ __forceinline__ void stf(bf16* p, float v){ *p = __float2bfloat16(v); }

// ---------------------------------------------------------------------------
// Skinny GEMM: C[M,128] = A[M,K] @ W[K,128] + bias   (all inputs f32)
// EPI==0: store C (type TC: float or bf16).
// EPI==1: tanh epilogue, dot with q, block-reduce, atomicAdd to score.
// ---------------------------------------------------------------------------
template<typename TC, int K, int EPI>
__global__ __launch_bounds__(256) void gemm_kernel(
    const float* __restrict__ A, const float* __restrict__ W, const float* __restrict__ B,
    TC* __restrict__ C, const float* __restrict__ qv, float* __restrict__ score, int M)
{
    __shared__ float As[64][33];
    __shared__ float Ws[32][129];
    const int tid = threadIdx.x;
    const int tx = tid & 15;        // col group: 8 consecutive cols
    const int ty = tid >> 4;        // row group: 4 consecutive rows
    const int row0 = blockIdx.x * 64;

    float acc[4][8];
    #pragma unroll
    for (int r = 0; r < 4; r++)
        #pragma unroll
        for (int c = 0; c < 8; c++) acc[r][c] = 0.f;

    for (int k0 = 0; k0 < K; k0 += 32) {
        #pragma unroll
        for (int i = 0; i < 8; i++) {
            int idx = tid * 8 + i;          // 0..2047 -> 64x32 tile
            int r = idx >> 5, k = idx & 31;
            int gr = row0 + r;
            float v = 0.f;
            if (gr < M) v = A[(long)gr * K + k0 + k];
            As[r][k] = v;
        }
        #pragma unroll
        for (int i = 0; i < 16; i++) {
            int idx = tid * 16 + i;         // 0..4095 -> 32x128 tile
            int k = idx >> 7, c = idx & 127;
            Ws[k][c] = W[(k0 + k) * HID + c];
        }
        __syncthreads();
        #pragma unroll 8
        for (int kk = 0; kk < 32; kk++) {
            float a0 = As[ty*4+0][kk];
            float a1 = As[ty*4+1][kk];
            float a2 = As[ty*4+2][kk];
            float a3 = As[ty*4+3][kk];
            #pragma unroll
            for (int c = 0; c < 8; c++) {
                float w = Ws[kk][tx*8+c];
                acc[0][c] = fmaf(a0, w, acc[0][c]);
                acc[1][c] = fmaf(a1, w, acc[1][c]);
                acc[2][c] = fmaf(a2, w, acc[2][c]);
                acc[3][c] = fmaf(a3, w, acc[3][c]);
            }
        }
        __syncthreads();
    }

    float bcol[8];
    #pragma unroll
    for (int c = 0; c < 8; c++) bcol[c] = B ? B[tx*8+c] : 0.f;

    if (EPI == 0) {
        #pragma unroll
        for (int r = 0; r < 4; r++) {
            int gr = row0 + ty*4 + r;
            if (gr < M) {
                #pragma unroll
                for (int c = 0; c < 8; c++)
                    stf(&C[(long)gr * HID + tx*8 + c], acc[r][c] + bcol[c]);
            }
        }
    } else {
        float qc[8];
        #pragma unroll
        for (int c = 0; c < 8; c++) qc[c] = qv[tx*8+c];
        float part = 0.f;
        #pragma unroll
        for (int r = 0; r < 4; r++) {
            int gr = row0 + ty*4 + r;
            if (gr < M) {
                #pragma unroll
                for (int c = 0; c < 8; c++)
                    part += qc[c] * tanhf(acc[r][c] + bcol[c]);
            }
        }
        __shared__ float red[256];
        red[tid] = part;
        __syncthreads();
        for (int s = 128; s > 0; s >>= 1) {
            if (tid < s) red[tid] += red[tid + s];
            __syncthreads();
        }
        if (tid == 0) atomicAdd(score, red[0]);
    }
}

// a[n,h] = sum_d xh[n, h*16+d] * att[h,d]   (xh in bf16, att f32)
__global__ void node_att_kernel(const bf16* __restrict__ xh, const float* __restrict__ att,
                                float* __restrict__ out, int N)
{
    int i = blockIdx.x * blockDim.x + threadIdx.x;
    if (i >= N * HEADS) return;
    int n = i >> 3, h = i & 7;
    const bf16* row = xh + (long)n * HID + h * DIMH;
    float s = 0.f;
    #pragma unroll
    for (int d = 0; d < DIMH; d++)
        s += __bfloat162float(row[d]) * att[h*DIMH + d];
    out[i] = s;
}

// ---------------- CSR build (once; edge lists are layer-invariant) ----------
__global__ void zero_int_kernel(int4* __restrict__ p, int n4)
{
    int i = blockIdx.x * blockDim.x + threadIdx.x;
    if (i < n4) p[i] = make_int4(0, 0, 0, 0);
}

__global__ void hist_kernel(const int* __restrict__ di, int* __restrict__ cnt, int E)
{
    int e = blockIdx.x * blockDim.x + threadIdx.x;
    if (e < E) atomicAdd(&cnt[di[e]], 1);
}

// single-block exclusive scan: roff[0..n] from cnt[0..n-1]
__global__ __launch_bounds__(256) void scan_kernel(const int* __restrict__ cnt,
                                                   int* __restrict__ roff, int n)
{
    __shared__ int sums[256];
    int tid = threadIdx.x;
    int chunk = (n + 255) / 256;
    int beg = tid * chunk, end = min(beg + chunk, n);
    int s = 0;
    for (int i = beg; i < end; i++) s += cnt[i];
    sums[tid] = s;
    __syncthreads();
    for (int off = 1; off < 256; off <<= 1) {
        int v = (tid >= off) ? sums[tid - off] : 0;
        __syncthreads();
        sums[tid] += v;
        __syncthreads();
    }
    int run = (tid > 0) ? sums[tid - 1] : 0;
    for (int i = beg; i < end; i++) { roff[i] = run; run += cnt[i]; }
    if (tid == 255) roff[n] = sums[255];
}

__global__ void csr_fill_kernel(const int* __restrict__ si, const int* __restrict__ di,
                                const int* __restrict__ roff, int* __restrict__ cur,
                                int* __restrict__ csrc, int E)
{
    int e = blockIdx.x * blockDim.x + threadIdx.x;
    if (e >= E) return;
    int d = di[e];
    int pos = roff[d] + atomicAdd(&cur[d], 1);
    csrc[pos] = si[e];
}

// ---------------------------------------------------------------------------
// Fused gather: one wave per destination. Single pass: accumulate
// denom_h and unnormalized weighted features; normalize + relu at end.
// out[d,:] = relu( sum_e w_e * xh[src_e,:] / sum_e w_e ),  w_e = exp(leaky(alpha))
// ---------------------------------------------------------------------------
__global__ __launch_bounds__(256) void edge_gather_kernel(
    const int* __restrict__ roff, const int* __restrict__ csrc,
    const float* __restrict__ as_, const float* __restrict__ ad_,
    const bf16* __restrict__ xh, float* __restrict__ out, int Ndst)
{
    int w = blockIdx.x * 4 + (threadIdx.x >> 6);   // destination node
    int lane = threadIdx.x & 63;
    if (w >= Ndst) return;
    int h = lane >> 3;                              // head of feature pair
    int beg = roff[w], end = roff[w + 1];
    float ad = ad_[(long)w * 8 + h];
    float den = 0.f, acc0 = 0.f, acc1 = 0.f;
    for (int e = beg; e < end; e++) {
        int s = csrc[e];
        float a = as_[(long)s * 8 + h] + ad;
        a = a >= 0.f ? a : 0.2f * a;
        float wt = __expf(fminf(a, 60.f));
        den += wt;
        bf162 x2 = *(const bf162*)(xh + (long)s * HID + lane * 2);
        acc0 = fmaf(__bfloat162float(x2.x), wt, acc0);
        acc1 = fmaf(__bfloat162float(x2.y), wt, acc1);
    }
    float inv = 1.f / (den + 1e-16f);
    out[(long)w * HID + lane * 2]     = fmaxf(acc0 * inv, 0.f);
    out[(long)w * HID + lane * 2 + 1] = fmaxf(acc1 * inv, 0.f);
}

// paper semantic combine: softmax over 2 metapath scores, blend (inputs already relu'd)
__global__ void combine_kernel(const float* __restrict__ a0, const float* __restrict__ a1,
                               const float* __restrict__ score, float* __restrict__ out, int n)
{
    int i = blockIdx.x * blockDim.x + threadIdx.x;
    if (i >= n) return;
    float s0 = score[0] * (1.f / N_PAPER);
    float s1 = score[1] * (1.f / N_PAPER);
    float m = fmaxf(s0, s1);
    float e0 = __expf(s0 - m), e1 = __expf(s1 - m);
    float inv = 1.f / (e0 + e1);
    out[i] = a0[i] * (e0 * inv) + a1[i] * (e1 * inv);
}

__global__ void zero_f_kernel(float* __restrict__ p, int n)
{
    int i = blockIdx.x * blockDim.x + threadIdx.x;
    if (i < n) p[i] = 0.f;
}

// out[n,c] = x[n,:] @ lin_w[:,c] + lin_b[c]  (f32 out)
__global__ __launch_bounds__(256) void final_lin_kernel(
    const float* __restrict__ X, const float* __restrict__ W,
    const float* __restrict__ B, float* __restrict__ out)
{
    __shared__ float Ws[HID * NCLS];
    int tid = threadIdx.x;
    for (int i = tid; i < HID * NCLS; i += 256) Ws[i] = W[i];
    __syncthreads();
    int i = blockIdx.x * 256 + tid;
    if (i >= N_PAPER * NCLS) return;
    int n = i >> 4, c = i & 15;
    float acc = B[c];
    const float* x = X + (long)n * HID;
    #pragma unroll 16
    for (int k = 0; k < HID; k++) acc = fmaf(x[k], Ws[k * NCLS + c], acc);
    out[i] = acc;
}

extern "C" void kernel_launch(void* const* d_in, const int* in_sizes, int n_in,
                              void* d_out, int out_size, void* d_ws, size_t ws_size,
                              hipStream_t stream)
{
    const float* x_author = (const float*)d_in[0];
    const float* x_paper  = (const float*)d_in[1];
    const float* Wa       = (const float*)d_in[2];
    const float* proj_w   = (const float*)d_in[3];
    const float* proj_b   = (const float*)d_in[4];
    const float* att_src  = (const float*)d_in[5];
    const float* att_dst  = (const float*)d_in[6];
    const float* klin_w   = (const float*)d_in[7];
    const float* klin_b   = (const float*)d_in[8];
    const float* qv       = (const float*)d_in[9];
    const float* lin_w    = (const float*)d_in[10];
    const float* lin_b    = (const float*)d_in[11];
    const int*  ei_w      = (const int*)d_in[12];
    const int*  ei_wb     = (const int*)d_in[13];
    const int*  ei_c      = (const int*)d_in[14];
    float* out = (float*)d_out;
    (void)ws_size; (void)in_sizes; (void)n_in; (void)out_size;

    // --- workspace allocator, 256B-aligned chunks (~78 MB total) ---
    char* base = (char*)d_ws;
    size_t off = 0;
    auto alloc = [&](size_t bytes) {
        void* p = base + off;
        off = (off + bytes + 255) & ~(size_t)255;
        return p;
    };
    bf16*  xh_a  = (bf16*) alloc((size_t)N_AUTHOR * HID * 2);
    bf16*  xh_p  = (bf16*) alloc((size_t)N_PAPER  * HID * 2);
    float* a_e0s = (float*)alloc((size_t)N_AUTHOR * HEADS * 4);
    float* a_e0d = (float*)alloc((size_t)N_PAPER  * HEADS * 4);
    float* a_e1s = (float*)alloc((size_t)N_PAPER  * HEADS * 4);
    float* a_e1d = (float*)alloc((size_t)N_AUTHOR * HEADS * 4);
    float* a_e2s = (float*)alloc((size_t)N_PAPER  * HEADS * 4);
    float* a_e2d = (float*)alloc((size_t)N_PAPER  * HEADS * 4);
    float* buf_a  = (float*)alloc((size_t)N_AUTHOR * HID * 4);  // cur_a / agg_a
    float* buf_p  = (float*)alloc((size_t)N_PAPER  * HID * 4);  // cur_p / agg_p0
    float* agg_p1 = (float*)alloc((size_t)N_PAPER  * HID * 4);
    float* score  = (float*)alloc(64);
    // CSR structures (built once, reused both layers)
    int* roff0 = (int*)alloc((size_t)(N_PAPER  + 1) * 4);
    int* roff1 = (int*)alloc((size_t)(N_AUTHOR + 1) * 4);
    int* roff2 = (int*)alloc((size_t)(N_PAPER  + 1) * 4);
    int* csrc0 = (int*)alloc((size_t)NEDGE * 4);
    int* csrc1 = (int*)alloc((size_t)NEDGE * 4);
    int* csrc2 = (int*)alloc((size_t)NEDGE * 4);
    int* cnt   = (int*)alloc((size_t)N_PAPER * 4);   // scratch counters (reused)

    const int GA = (N_AUTHOR + 63) / 64;   // 313
    const int GP = (N_PAPER  + 63) / 64;   // 625
    const int GE = (NEDGE + 255) / 256;

    // ---- build 3 CSRs (dst-bucketed source lists) ----
    {
        struct { const int* si; const int* di; int* roff; int* csrc; int nd; } jobs[3] = {
            { ei_w,          ei_w  + NEDGE, roff0, csrc0, N_PAPER  },
            { ei_wb,         ei_wb + NEDGE, roff1, csrc1, N_AUTHOR },
            { ei_c,          ei_c  + NEDGE, roff2, csrc2, N_PAPER  },
        };
        for (int j = 0; j < 3; j++) {
            int n4 = (jobs[j].nd + 3) / 4;
            zero_int_kernel<<<(n4 + 255)/256, 256, 0, stream>>>((int4*)cnt, n4);
            hist_kernel<<<GE, 256, 0, stream>>>(jobs[j].di, cnt, NEDGE);
            scan_kernel<<<1, 256, 0, stream>>>(cnt, jobs[j].roff, jobs[j].nd);
            zero_int_kernel<<<(n4 + 255)/256, 256, 0, stream>>>((int4*)cnt, n4);
            csr_fill_kernel<<<GE, 256, 0, stream>>>(jobs[j].si, jobs[j].di, jobs[j].roff, cnt, jobs[j].csrc, NEDGE);
        }
    }

    // input projection: author 64 -> 128 (f32 into buf_a); paper uses x_paper directly
    gemm_kernel<float, 64, 0><<<GA, 256, 0, stream>>>(
        x_author, Wa, nullptr, buf_a, nullptr, nullptr, N_AUTHOR);

    for (int l = 0; l < 2; l++) {
        const bool last = (l == 1);
        const float* cur_a = buf_a;
        const float* cur_p = (l == 0) ? x_paper : buf_p;
        const float* pw_a = proj_w + (size_t)(l*2 + 0) * HID * HID;
        const float* pw_p = proj_w + (size_t)(l*2 + 1) * HID * HID;
        const float* pb_a = proj_b + (size_t)(l*2 + 0) * HID;
        const float* pb_p = proj_b + (size_t)(l*2 + 1) * HID;

        // projection reads cur_*, writes xh_* (bf16); buf_* dead afterwards
        gemm_kernel<bf16, 128, 0><<<GA, 256, 0, stream>>>(
            cur_a, pw_a, pb_a, xh_a, nullptr, nullptr, N_AUTHOR);
        gemm_kernel<bf16, 128, 0><<<GP, 256, 0, stream>>>(
            cur_p, pw_p, pb_p, xh_p, nullptr, nullptr, N_PAPER);

        zero_f_kernel<<<1, 64, 0, stream>>>(score, 16);

        const float* as0 = att_src + (size_t)(l*3 + 0) * HID;
        const float* ad0 = att_dst + (size_t)(l*3 + 0) * HID;
        const float* as1 = att_src + (size_t)(l*3 + 1) * HID;
        const float* ad1 = att_dst + (size_t)(l*3 + 1) * HID;
        const float* as2 = att_src + (size_t)(l*3 + 2) * HID;
        const float* ad2 = att_dst + (size_t)(l*3 + 2) * HID;

        node_att_kernel<<<(N_AUTHOR*HEADS + 255)/256, 256, 0, stream>>>(xh_a, as0, a_e0s, N_AUTHOR);
        node_att_kernel<<<(N_PAPER *HEADS + 255)/256, 256, 0, stream>>>(xh_p, ad0, a_e0d, N_PAPER);
        if (!last) {
            node_att_kernel<<<(N_PAPER *HEADS + 255)/256, 256, 0, stream>>>(xh_p, as1, a_e1s, N_PAPER);
            node_att_kernel<<<(N_AUTHOR*HEADS + 255)/256, 256, 0, stream>>>(xh_a, ad1, a_e1d, N_AUTHOR);
        }
        node_att_kernel<<<(N_PAPER*HEADS + 255)/256, 256, 0, stream>>>(xh_p, as2, a_e2s, N_PAPER);
        node_att_kernel<<<(N_PAPER*HEADS + 255)/256, 256, 0, stream>>>(xh_p, ad2, a_e2d, N_PAPER);

        // fused gathers (denominator + weighted sum + normalize + relu in one pass)
        edge_gather_kernel<<<(N_PAPER + 3)/4, 256, 0, stream>>>(
            roff0, csrc0, a_e0s, a_e0d, xh_a, buf_p, N_PAPER);
        if (!last)
            edge_gather_kernel<<<(N_AUTHOR + 3)/4, 256, 0, stream>>>(
                roff1, csrc1, a_e1s, a_e1d, xh_p, buf_a, N_AUTHOR);
        edge_gather_kernel<<<(N_PAPER + 3)/4, 256, 0, stream>>>(
            roff2, csrc2, a_e2s, a_e2d, xh_p, agg_p1, N_PAPER);

        // paper semantic attention scores (author has M=1 -> weight 1, skip)
        const float* kw = klin_w + (size_t)l * HID * HID;
        const float* kb = klin_b + (size_t)l * HID;
        const float* qq = qv     + (size_t)l * HID;
        gemm_kernel<float, 128, 1><<<GP, 256, 0, stream>>>(
            buf_p, kw, kb, (float*)nullptr, qq, score + 0, N_PAPER);
        gemm_kernel<float, 128, 1><<<GP, 256, 0, stream>>>(
            agg_p1, kw, kb, (float*)nullptr, qq, score + 1, N_PAPER);

        // combine writes buf_p in place (elementwise, inputs already relu'd)
        combine_kernel<<<(N_PAPER*HID + 255)/256, 256, 0, stream>>>(buf_p, agg_p1, score, buf_p, N_PAPER*HID);
    }

    final_lin_kernel<<<(N_PAPER*NCLS + 255)/256, 256, 0, stream>>>(buf_p, lin_w, lin_b, out);
}

// Round 5
// 919.626 us; speedup vs baseline: 3.3405x; 1.1615x over previous
//
#include <hip/hip_runtime.h>
#include <hip/hip_bf16.h>

typedef __hip_bfloat16 bf16;
typedef __hip_bfloat162 bf162;

#define N_AUTHOR 20000
#define N_PAPER  40000
#define NEDGE    400000
#define HID      128
#define HEADS    8
#define DIMH     16
#define NCLS     16

__device__ __forceinline__ void stf(float* p, float v){ *p = v; }
__device__ __forceinline__ void stf(bf16* p, float v){ *p = __float2bfloat16(v); }

// ---------------------------------------------------------------------------
// Skinny GEMM: C[M,128] = A[M,K] @ W[K,128] + bias   (all inputs f32)
// EPI==0: store C (type TC: float or bf16).
// EPI==1: tanh epilogue, dot with q, block-reduce, atomicAdd to score.
// ---------------------------------------------------------------------------
template<typename TC, int K, int EPI>
__global__ __launch_bounds__(256) void gemm_kernel(
    const float* __restrict__ A, const float* __restrict__ W, const float* __restrict__ B,
    TC* __restrict__ C, const float* __restrict__ qv, float* __restrict__ score, int M)
{
    __shared__ float As[64][33];
    __shared__ float Ws[32][129];
    const int tid = threadIdx.x;
    const int tx = tid & 15;        // col group: 8 consecutive cols
    const int ty = tid >> 4;        // row group: 4 consecutive rows
    const int row0 = blockIdx.x * 64;

    float acc[4][8];
    #pragma unroll
    for (int r = 0; r < 4; r++)
        #pragma unroll
        for (int c = 0; c < 8; c++) acc[r][c] = 0.f;

    for (int k0 = 0; k0 < K; k0 += 32) {
        #pragma unroll
        for (int i = 0; i < 8; i++) {
            int idx = tid * 8 + i;          // 0..2047 -> 64x32 tile
            int r = idx >> 5, k = idx & 31;
            int gr = row0 + r;
            float v = 0.f;
            if (gr < M) v = A[(long)gr * K + k0 + k];
            As[r][k] = v;
        }
        #pragma unroll
        for (int i = 0; i < 16; i++) {
            int idx = tid * 16 + i;         // 0..4095 -> 32x128 tile
            int k = idx >> 7, c = idx & 127;
            Ws[k][c] = W[(k0 + k) * HID + c];
        }
        __syncthreads();
        #pragma unroll 8
        for (int kk = 0; kk < 32; kk++) {
            float a0 = As[ty*4+0][kk];
            float a1 = As[ty*4+1][kk];
            float a2 = As[ty*4+2][kk];
            float a3 = As[ty*4+3][kk];
            #pragma unroll
            for (int c = 0; c < 8; c++) {
                float w = Ws[kk][tx*8+c];
                acc[0][c] = fmaf(a0, w, acc[0][c]);
                acc[1][c] = fmaf(a1, w, acc[1][c]);
                acc[2][c] = fmaf(a2, w, acc[2][c]);
                acc[3][c] = fmaf(a3, w, acc[3][c]);
            }
        }
        __syncthreads();
    }

    float bcol[8];
    #pragma unroll
    for (int c = 0; c < 8; c++) bcol[c] = B ? B[tx*8+c] : 0.f;

    if (EPI == 0) {
        #pragma unroll
        for (int r = 0; r < 4; r++) {
            int gr = row0 + ty*4 + r;
            if (gr < M) {
                #pragma unroll
                for (int c = 0; c < 8; c++)
                    stf(&C[(long)gr * HID + tx*8 + c], acc[r][c] + bcol[c]);
            }
        }
    } else {
        float qc[8];
        #pragma unroll
        for (int c = 0; c < 8; c++) qc[c] = qv[tx*8+c];
        float part = 0.f;
        #pragma unroll
        for (int r = 0; r < 4; r++) {
            int gr = row0 + ty*4 + r;
            if (gr < M) {
                #pragma unroll
                for (int c = 0; c < 8; c++)
                    part += qc[c] * tanhf(acc[r][c] + bcol[c]);
            }
        }
        __shared__ float red[256];
        red[tid] = part;
        __syncthreads();
        for (int s = 128; s > 0; s >>= 1) {
            if (tid < s) red[tid] += red[tid + s];
            __syncthreads();
        }
        if (tid == 0) atomicAdd(score, red[0]);
    }
}

// multi-output node attention dots: O_k[n,h] = sum_d xh[n,h*16+d] * A_k[h,d]
// reads xh once for up to 4 attention vectors (null = skip)
__global__ void node_att_multi_kernel(const bf16* __restrict__ xh,
    const float* __restrict__ A0, const float* __restrict__ A1,
    const float* __restrict__ A2, const float* __restrict__ A3,
    float* __restrict__ O0, float* __restrict__ O1,
    float* __restrict__ O2, float* __restrict__ O3, int N)
{
    int i = blockIdx.x * blockDim.x + threadIdx.x;
    if (i >= N * HEADS) return;
    int n = i >> 3, h = i & 7;
    const bf16* row = xh + (long)n * HID + h * DIMH;
    float x[DIMH];
    #pragma unroll
    for (int d = 0; d < DIMH; d++) x[d] = __bfloat162float(row[d]);
    if (A0) { float s = 0.f;
        #pragma unroll
        for (int d = 0; d < DIMH; d++) s += x[d] * A0[h*DIMH + d];
        O0[i] = s; }
    if (A1) { float s = 0.f;
        #pragma unroll
        for (int d = 0; d < DIMH; d++) s += x[d] * A1[h*DIMH + d];
        O1[i] = s; }
    if (A2) { float s = 0.f;
        #pragma unroll
        for (int d = 0; d < DIMH; d++) s += x[d] * A2[h*DIMH + d];
        O2[i] = s; }
    if (A3) { float s = 0.f;
        #pragma unroll
        for (int d = 0; d < DIMH; d++) s += x[d] * A3[h*DIMH + d];
        O3[i] = s; }
}

// ---------------- CSR build (once; edge lists are layer-invariant) ----------
__global__ void zero_int_kernel(int4* __restrict__ p, int n4)
{
    int i = blockIdx.x * blockDim.x + threadIdx.x;
    if (i < n4) p[i] = make_int4(0, 0, 0, 0);
}

__global__ void hist_kernel(const int* __restrict__ di, int* __restrict__ cnt, int E)
{
    int e = blockIdx.x * blockDim.x + threadIdx.x;
    if (e < E) atomicAdd(&cnt[di[e]], 1);
}

// 3-phase multi-block exclusive scan of cnt[0..n) -> roff[0..n]
// A: per-block sums; B: scan block sums (<=256 blocks) + write roff[n]; C: per-block scan+offset
__global__ __launch_bounds__(256) void scan_a_kernel(const int* __restrict__ cnt,
                                                     int* __restrict__ bsum, int n)
{
    __shared__ int s[256];
    int tid = threadIdx.x;
    int i = blockIdx.x * 256 + tid;
    s[tid] = (i < n) ? cnt[i] : 0;
    __syncthreads();
    for (int st = 128; st > 0; st >>= 1) {
        if (tid < st) s[tid] += s[tid + st];
        __syncthreads();
    }
    if (tid == 0) bsum[blockIdx.x] = s[0];
}

__global__ __launch_bounds__(256) void scan_b_kernel(int* __restrict__ bsum,
                                                     int* __restrict__ roff, int nb, int n)
{
    __shared__ int s[256];
    int tid = threadIdx.x;
    int v = (tid < nb) ? bsum[tid] : 0;
    s[tid] = v;
    __syncthreads();
    for (int off = 1; off < 256; off <<= 1) {
        int t = (tid >= off) ? s[tid - off] : 0;
        __syncthreads();
        s[tid] += t;
        __syncthreads();
    }
    if (tid < nb) bsum[tid] = s[tid] - v;     // exclusive
    if (tid == 255) roff[n] = s[255];          // total
}

__global__ __launch_bounds__(256) void scan_c_kernel(const int* __restrict__ cnt,
                                                     const int* __restrict__ bsum,
                                                     int* __restrict__ roff, int n)
{
    __shared__ int s[256];
    int tid = threadIdx.x;
    int i = blockIdx.x * 256 + tid;
    int v = (i < n) ? cnt[i] : 0;
    s[tid] = v;
    __syncthreads();
    for (int off = 1; off < 256; off <<= 1) {
        int t = (tid >= off) ? s[tid - off] : 0;
        __syncthreads();
        s[tid] += t;
        __syncthreads();
    }
    if (i < n) roff[i] = bsum[blockIdx.x] + s[tid] - v;
}

__global__ void csr_fill_kernel(const int* __restrict__ si, const int* __restrict__ di,
                                const int* __restrict__ roff, int* __restrict__ cur,
                                int* __restrict__ csrc, int E)
{
    int e = blockIdx.x * blockDim.x + threadIdx.x;
    if (e >= E) return;
    int d = di[e];
    int pos = roff[d] + atomicAdd(&cur[d], 1);
    csrc[pos] = si[e];
}

// ---------------------------------------------------------------------------
// Fused gather: one wave per destination. Single pass: accumulate
// denom_h and unnormalized weighted features; normalize + relu at end.
// ---------------------------------------------------------------------------
__global__ __launch_bounds__(256) void edge_gather_kernel(
    const int* __restrict__ roff, const int* __restrict__ csrc,
    const float* __restrict__ as_, const float* __restrict__ ad_,
    const bf16* __restrict__ xh, float* __restrict__ out, int Ndst)
{
    int w = blockIdx.x * 4 + (threadIdx.x >> 6);   // destination node
    int lane = threadIdx.x & 63;
    if (w >= Ndst) return;
    int h = lane >> 3;                              // head of feature pair
    int beg = roff[w], end = roff[w + 1];
    float ad = ad_[(long)w * 8 + h];
    float den = 0.f, acc0 = 0.f, acc1 = 0.f;
    for (int e = beg; e < end; e++) {
        int s = csrc[e];
        float a = as_[(long)s * 8 + h] + ad;
        a = a >= 0.f ? a : 0.2f * a;
        float wt = __expf(fminf(a, 60.f));
        den += wt;
        bf162 x2 = *(const bf162*)(xh + (long)s * HID + lane * 2);
        acc0 = fmaf(__bfloat162float(x2.x), wt, acc0);
        acc1 = fmaf(__bfloat162float(x2.y), wt, acc1);
    }
    float inv = 1.f / (den + 1e-16f);
    out[(long)w * HID + lane * 2]     = fmaxf(acc0 * inv, 0.f);
    out[(long)w * HID + lane * 2 + 1] = fmaxf(acc1 * inv, 0.f);
}

// paper semantic combine: softmax over 2 metapath scores, blend (inputs already relu'd)
__global__ void combine_kernel(const float* __restrict__ a0, const float* __restrict__ a1,
                               const float* __restrict__ score, float* __restrict__ out, int n)
{
    int i = blockIdx.x * blockDim.x + threadIdx.x;
    if (i >= n) return;
    float s0 = score[0] * (1.f / N_PAPER);
    float s1 = score[1] * (1.f / N_PAPER);
    float m = fmaxf(s0, s1);
    float e0 = __expf(s0 - m), e1 = __expf(s1 - m);
    float inv = 1.f / (e0 + e1);
    out[i] = a0[i] * (e0 * inv) + a1[i] * (e1 * inv);
}

__global__ void zero_f_kernel(float* __restrict__ p, int n)
{
    int i = blockIdx.x * blockDim.x + threadIdx.x;
    if (i < n) p[i] = 0.f;
}

// out[n,c] = x[n,:] @ lin_w[:,c] + lin_b[c]  (f32 out)
__global__ __launch_bounds__(256) void final_lin_kernel(
    const float* __restrict__ X, const float* __restrict__ W,
    const float* __restrict__ B, float* __restrict__ out)
{
    __shared__ float Ws[HID * NCLS];
    int tid = threadIdx.x;
    for (int i = tid; i < HID * NCLS; i += 256) Ws[i] = W[i];
    __syncthreads();
    int i = blockIdx.x * 256 + tid;
    if (i >= N_PAPER * NCLS) return;
    int n = i >> 4, c = i & 15;
    float acc = B[c];
    const float* x = X + (long)n * HID;
    #pragma unroll 16
    for (int k = 0; k < HID; k++) acc = fmaf(x[k], Ws[k * NCLS + c], acc);
    out[i] = acc;
}

extern "C" void kernel_launch(void* const* d_in, const int* in_sizes, int n_in,
                              void* d_out, int out_size, void* d_ws, size_t ws_size,
                              hipStream_t stream)
{
    const float* x_author = (const float*)d_in[0];
    const float* x_paper  = (const float*)d_in[1];
    const float* Wa       = (const float*)d_in[2];
    const float* proj_w   = (const float*)d_in[3];
    const float* proj_b   = (const float*)d_in[4];
    const float* att_src  = (const float*)d_in[5];
    const float* att_dst  = (const float*)d_in[6];
    const float* klin_w   = (const float*)d_in[7];
    const float* klin_b   = (const float*)d_in[8];
    const float* qv       = (const float*)d_in[9];
    const float* lin_w    = (const float*)d_in[10];
    const float* lin_b    = (const float*)d_in[11];
    const int*  ei_w      = (const int*)d_in[12];
    const int*  ei_wb     = (const int*)d_in[13];
    const int*  ei_c      = (const int*)d_in[14];
    float* out = (float*)d_out;
    (void)ws_size; (void)in_sizes; (void)n_in; (void)out_size;

    // --- workspace allocator, 256B-aligned chunks (~78 MB total) ---
    char* base = (char*)d_ws;
    size_t off = 0;
    auto alloc = [&](size_t bytes) {
        void* p = base + off;
        off = (off + bytes + 255) & ~(size_t)255;
        return p;
    };
    bf16*  xh_a  = (bf16*) alloc((size_t)N_AUTHOR * HID * 2);
    bf16*  xh_p  = (bf16*) alloc((size_t)N_PAPER  * HID * 2);
    float* a_e0s = (float*)alloc((size_t)N_AUTHOR * HEADS * 4);
    float* a_e0d = (float*)alloc((size_t)N_PAPER  * HEADS * 4);
    float* a_e1s = (float*)alloc((size_t)N_PAPER  * HEADS * 4);
    float* a_e1d = (float*)alloc((size_t)N_AUTHOR * HEADS * 4);
    float* a_e2s = (float*)alloc((size_t)N_PAPER  * HEADS * 4);
    float* a_e2d = (float*)alloc((size_t)N_PAPER  * HEADS * 4);
    float* buf_a  = (float*)alloc((size_t)N_AUTHOR * HID * 4);  // cur_a / agg_a
    float* buf_p  = (float*)alloc((size_t)N_PAPER  * HID * 4);  // cur_p / agg_p0
    float* agg_p1 = (float*)alloc((size_t)N_PAPER  * HID * 4);
    float* score  = (float*)alloc(64);
    // CSR structures (built once, reused both layers)
    int* roff0 = (int*)alloc((size_t)(N_PAPER  + 1) * 4);
    int* roff1 = (int*)alloc((size_t)(N_AUTHOR + 1) * 4);
    int* roff2 = (int*)alloc((size_t)(N_PAPER  + 1) * 4);
    int* csrc0 = (int*)alloc((size_t)NEDGE * 4);
    int* csrc1 = (int*)alloc((size_t)NEDGE * 4);
    int* csrc2 = (int*)alloc((size_t)NEDGE * 4);
    int* cnt   = (int*)alloc((size_t)N_PAPER * 4);   // scratch counters (reused)
    int* bsum  = (int*)alloc(256 * 4);               // scan block sums (reused)

    const int GA = (N_AUTHOR + 63) / 64;   // 313
    const int GP = (N_PAPER  + 63) / 64;   // 625
    const int GE = (NEDGE + 255) / 256;

    // ---- build 3 CSRs (dst-bucketed source lists) ----
    {
        struct { const int* si; const int* di; int* roff; int* csrc; int nd; } jobs[3] = {
            { ei_w,  ei_w  + NEDGE, roff0, csrc0, N_PAPER  },
            { ei_wb, ei_wb + NEDGE, roff1, csrc1, N_AUTHOR },
            { ei_c,  ei_c  + NEDGE, roff2, csrc2, N_PAPER  },
        };
        for (int j = 0; j < 3; j++) {
            int nd = jobs[j].nd;
            int n4 = (nd + 3) / 4;
            int nb = (nd + 255) / 256;             // <= 157, fits scan_b's 256
            zero_int_kernel<<<(n4 + 255)/256, 256, 0, stream>>>((int4*)cnt, n4);
            hist_kernel<<<GE, 256, 0, stream>>>(jobs[j].di, cnt, NEDGE);
            scan_a_kernel<<<nb, 256, 0, stream>>>(cnt, bsum, nd);
            scan_b_kernel<<<1, 256, 0, stream>>>(bsum, jobs[j].roff, nb, nd);
            scan_c_kernel<<<nb, 256, 0, stream>>>(cnt, bsum, jobs[j].roff, nd);
            zero_int_kernel<<<(n4 + 255)/256, 256, 0, stream>>>((int4*)cnt, n4);
            csr_fill_kernel<<<GE, 256, 0, stream>>>(jobs[j].si, jobs[j].di, jobs[j].roff, cnt, jobs[j].csrc, NEDGE);
        }
    }

    // input projection: author 64 -> 128 (f32 into buf_a); paper uses x_paper directly
    gemm_kernel<float, 64, 0><<<GA, 256, 0, stream>>>(
        x_author, Wa, nullptr, buf_a, nullptr, nullptr, N_AUTHOR);

    for (int l = 0; l < 2; l++) {
        const bool last = (l == 1);
        const float* cur_a = buf_a;
        const float* cur_p = (l == 0) ? x_paper : buf_p;
        const float* pw_a = proj_w + (size_t)(l*2 + 0) * HID * HID;
        const float* pw_p = proj_w + (size_t)(l*2 + 1) * HID * HID;
        const float* pb_a = proj_b + (size_t)(l*2 + 0) * HID;
        const float* pb_p = proj_b + (size_t)(l*2 + 1) * HID;

        // projection reads cur_*, writes xh_* (bf16); buf_* dead afterwards
        gemm_kernel<bf16, 128, 0><<<GA, 256, 0, stream>>>(
            cur_a, pw_a, pb_a, xh_a, nullptr, nullptr, N_AUTHOR);
        gemm_kernel<bf16, 128, 0><<<GP, 256, 0, stream>>>(
            cur_p, pw_p, pb_p, xh_p, nullptr, nullptr, N_PAPER);

        zero_f_kernel<<<1, 64, 0, stream>>>(score, 16);

        const float* as0 = att_src + (size_t)(l*3 + 0) * HID;
        const float* ad0 = att_dst + (size_t)(l*3 + 0) * HID;
        const float* as1 = att_src + (size_t)(l*3 + 1) * HID;
        const float* ad1 = att_dst + (size_t)(l*3 + 1) * HID;
        const float* as2 = att_src + (size_t)(l*3 + 2) * HID;
        const float* ad2 = att_dst + (size_t)(l*3 + 2) * HID;

        // author: as0 always, ad1 only if !last; paper: ad0/as2/ad2 always, as1 if !last
        node_att_multi_kernel<<<(N_AUTHOR*HEADS + 255)/256, 256, 0, stream>>>(
            xh_a, as0, last ? nullptr : ad1, nullptr, nullptr,
            a_e0s, a_e1d, nullptr, nullptr, N_AUTHOR);
        node_att_multi_kernel<<<(N_PAPER*HEADS + 255)/256, 256, 0, stream>>>(
            xh_p, ad0, last ? nullptr : as1, as2, ad2,
            a_e0d, a_e1s, a_e2s, a_e2d, N_PAPER);

        // fused gathers (denominator + weighted sum + normalize + relu in one pass)
        edge_gather_kernel<<<(N_PAPER + 3)/4, 256, 0, stream>>>(
            roff0, csrc0, a_e0s, a_e0d, xh_a, buf_p, N_PAPER);
        if (!last)
            edge_gather_kernel<<<(N_AUTHOR + 3)/4, 256, 0, stream>>>(
                roff1, csrc1, a_e1s, a_e1d, xh_p, buf_a, N_AUTHOR);
        edge_gather_kernel<<<(N_PAPER + 3)/4, 256, 0, stream>>>(
            roff2, csrc2, a_e2s, a_e2d, xh_p, agg_p1, N_PAPER);

        // paper semantic attention scores (author has M=1 -> weight 1, skip)
        const float* kw = klin_w + (size_t)l * HID * HID;
        const float* kb = klin_b + (size_t)l * HID;
        const float* qq = qv     + (size_t)l * HID;
        gemm_kernel<float, 128, 1><<<GP, 256, 0, stream>>>(
            buf_p, kw, kb, (float*)nullptr, qq, score + 0, N_PAPER);
        gemm_kernel<float, 128, 1><<<GP, 256, 0, stream>>>(
            agg_p1, kw, kb, (float*)nullptr, qq, score + 1, N_PAPER);

        // combine writes buf_p in place (elementwise, inputs already relu'd)
        combine_kernel<<<(N_PAPER*HID + 255)/256, 256, 0, stream>>>(buf_p, agg_p1, score, buf_p, N_PAPER*HID);
    }

    final_lin_kernel<<<(N_PAPER*NCLS + 255)/256, 256, 0, stream>>>(buf_p, lin_w, lin_b, out);
}

// Round 6
// 707.561 us; speedup vs baseline: 4.3416x; 1.2997x over previous
//
#include <hip/hip_runtime.h>
#include <hip/hip_bf16.h>

typedef __hip_bfloat16 bf16;
typedef __hip_bfloat162 bf162;

#define N_AUTHOR 20000
#define N_PAPER  40000
#define NEDGE    400000
#define HID      128
#define HEADS    8
#define DIMH     16
#define NCLS     16

typedef short short4v __attribute__((ext_vector_type(4)));
typedef short short8v __attribute__((ext_vector_type(8)));
typedef float f32x4   __attribute__((ext_vector_type(4)));

__device__ __forceinline__ void stf(float* p, float v){ *p = v; }
__device__ __forceinline__ void stf(bf16* p, float v){ *p = __float2bfloat16(v); }

// float -> bf16 bits (round-to-nearest-even; finite inputs only)
__device__ __forceinline__ short f2bs(float v){
    unsigned u = __float_as_uint(v);
    unsigned r = (u + 0x7FFFu + ((u >> 16) & 1u)) >> 16;
    return (short)r;
}

// ---------------------------------------------------------------------------
// MFMA GEMM: C[M,128] = act(A[M,128]) @ W[128,128] + bias
// A,W f32 in global; converted to bf16 in-register; f32 accumulate (MFMA).
// Block = 256 thr = 4 waves; wave computes 16 rows x 128 cols.
// W staged to LDS transposed Wt[col][k], stride 136 (16B-aligned rows).
// EPI==0: store C (TC float/bf16).  EPI==1: tanh, dot q, reduce, atomicAdd.
// ---------------------------------------------------------------------------
template<typename TC, bool RELU_A, int EPI>
__global__ __launch_bounds__(256) void mfma_gemm_kernel(
    const float* __restrict__ A, const float* __restrict__ W, const float* __restrict__ Bb,
    TC* __restrict__ C, const float* __restrict__ qv, float* __restrict__ score, int M)
{
    __shared__ short Wt[128 * 136];     // Wt[c][k]
    const int tid = threadIdx.x;
    // stage W^T: thread handles (c, k0..k0+3); global reads coalesced over c
    #pragma unroll
    for (int i = 0; i < 16; i++) {
        int pair = tid + 256 * i;        // 0..4095
        int c  = pair & 127;
        int k0 = (pair >> 7) * 4;
        short4v s;
        #pragma unroll
        for (int j = 0; j < 4; j++)
            s[j] = f2bs(W[(k0 + j) * HID + c]);
        *(short4v*)&Wt[c * 136 + k0] = s;
    }
    __syncthreads();

    const int lane = tid & 63;
    const int wv   = tid >> 6;
    const int lr   = lane & 15;
    const int quad = lane >> 4;
    const int row0 = blockIdx.x * 64 + wv * 16;   // wave's row tile
    const int arow_i = row0 + lr;                 // row this lane loads for A-frag
    const bool rowok = arow_i < M;
    const float* arow = A + (long)arow_i * HID;

    // A fragments: lane holds A[lr][kc*32 + quad*8 + j]
    short8v afrag[4];
    #pragma unroll
    for (int kc = 0; kc < 4; kc++) {
        short8v f;
        #pragma unroll
        for (int j = 0; j < 8; j++) {
            float v = rowok ? arow[kc * 32 + quad * 8 + j] : 0.f;
            if (RELU_A) v = fmaxf(v, 0.f);
            f[j] = f2bs(v);
        }
        afrag[kc] = f;
    }

    f32x4 acc[8];
    #pragma unroll
    for (int ct = 0; ct < 8; ct++) acc[ct] = (f32x4){0.f, 0.f, 0.f, 0.f};

    #pragma unroll
    for (int ct = 0; ct < 8; ct++) {
        #pragma unroll
        for (int kc = 0; kc < 4; kc++) {
            short8v bfrag = *(const short8v*)&Wt[(ct * 16 + lr) * 136 + kc * 32 + quad * 8];
            acc[ct] = __builtin_amdgcn_mfma_f32_16x16x32_bf16(afrag[kc], bfrag, acc[ct], 0, 0, 0);
        }
    }

    // D mapping: row = row0 + quad*4 + r, col = ct*16 + lr
    if (EPI == 0) {
        #pragma unroll
        for (int ct = 0; ct < 8; ct++) {
            float bc = Bb ? Bb[ct * 16 + lr] : 0.f;
            #pragma unroll
            for (int r = 0; r < 4; r++) {
                int orow = row0 + quad * 4 + r;
                if (orow < M)
                    stf(&C[(long)orow * HID + ct * 16 + lr], acc[ct][r] + bc);
            }
        }
    } else {
        float part = 0.f;
        #pragma unroll
        for (int ct = 0; ct < 8; ct++) {
            float bc = Bb ? Bb[ct * 16 + lr] : 0.f;
            float qc = qv[ct * 16 + lr];
            #pragma unroll
            for (int r = 0; r < 4; r++) {
                int orow = row0 + quad * 4 + r;
                if (orow < M) part += qc * tanhf(acc[ct][r] + bc);
            }
        }
        __shared__ float red[256];
        red[tid] = part;
        __syncthreads();
        for (int s = 128; s > 0; s >>= 1) {
            if (tid < s) red[tid] += red[tid + s];
            __syncthreads();
        }
        if (tid == 0) atomicAdd(score, red[0]);
    }
}

// ---------------------------------------------------------------------------
// f32 skinny GEMM (kept for the one K=64 input projection)
// ---------------------------------------------------------------------------
template<typename TC, int K, int EPI>
__global__ __launch_bounds__(256) void gemm_kernel(
    const float* __restrict__ A, const float* __restrict__ W, const float* __restrict__ B,
    TC* __restrict__ C, const float* __restrict__ qv, float* __restrict__ score, int M)
{
    __shared__ float As[64][33];
    __shared__ float Ws[32][129];
    const int tid = threadIdx.x;
    const int tx = tid & 15;
    const int ty = tid >> 4;
    const int row0 = blockIdx.x * 64;

    float acc[4][8];
    #pragma unroll
    for (int r = 0; r < 4; r++)
        #pragma unroll
        for (int c = 0; c < 8; c++) acc[r][c] = 0.f;

    for (int k0 = 0; k0 < K; k0 += 32) {
        #pragma unroll
        for (int i = 0; i < 8; i++) {
            int idx = tid * 8 + i;
            int r = idx >> 5, k = idx & 31;
            int gr = row0 + r;
            float v = 0.f;
            if (gr < M) v = A[(long)gr * K + k0 + k];
            As[r][k] = v;
        }
        #pragma unroll
        for (int i = 0; i < 16; i++) {
            int idx = tid * 16 + i;
            int k = idx >> 7, c = idx & 127;
            Ws[k][c] = W[(k0 + k) * HID + c];
        }
        __syncthreads();
        #pragma unroll 8
        for (int kk = 0; kk < 32; kk++) {
            float a0 = As[ty*4+0][kk];
            float a1 = As[ty*4+1][kk];
            float a2 = As[ty*4+2][kk];
            float a3 = As[ty*4+3][kk];
            #pragma unroll
            for (int c = 0; c < 8; c++) {
                float w = Ws[kk][tx*8+c];
                acc[0][c] = fmaf(a0, w, acc[0][c]);
                acc[1][c] = fmaf(a1, w, acc[1][c]);
                acc[2][c] = fmaf(a2, w, acc[2][c]);
                acc[3][c] = fmaf(a3, w, acc[3][c]);
            }
        }
        __syncthreads();
    }

    float bcol[8];
    #pragma unroll
    for (int c = 0; c < 8; c++) bcol[c] = B ? B[tx*8+c] : 0.f;

    #pragma unroll
    for (int r = 0; r < 4; r++) {
        int gr = row0 + ty*4 + r;
        if (gr < M) {
            #pragma unroll
            for (int c = 0; c < 8; c++)
                stf(&C[(long)gr * HID + tx*8 + c], acc[r][c] + bcol[c]);
        }
    }
}

// multi-output node attention dots: O_k[n,h] = sum_d xh[n,h*16+d] * A_k[h,d]
__global__ void node_att_multi_kernel(const bf16* __restrict__ xh,
    const float* __restrict__ A0, const float* __restrict__ A1,
    const float* __restrict__ A2, const float* __restrict__ A3,
    float* __restrict__ O0, float* __restrict__ O1,
    float* __restrict__ O2, float* __restrict__ O3, int N)
{
    int i = blockIdx.x * blockDim.x + threadIdx.x;
    if (i >= N * HEADS) return;
    int n = i >> 3, h = i & 7;
    const bf16* row = xh + (long)n * HID + h * DIMH;
    float x[DIMH];
    #pragma unroll
    for (int d = 0; d < DIMH; d++) x[d] = __bfloat162float(row[d]);
    if (A0) { float s = 0.f;
        #pragma unroll
        for (int d = 0; d < DIMH; d++) s += x[d] * A0[h*DIMH + d];
        O0[i] = s; }
    if (A1) { float s = 0.f;
        #pragma unroll
        for (int d = 0; d < DIMH; d++) s += x[d] * A1[h*DIMH + d];
        O1[i] = s; }
    if (A2) { float s = 0.f;
        #pragma unroll
        for (int d = 0; d < DIMH; d++) s += x[d] * A2[h*DIMH + d];
        O2[i] = s; }
    if (A3) { float s = 0.f;
        #pragma unroll
        for (int d = 0; d < DIMH; d++) s += x[d] * A3[h*DIMH + d];
        O3[i] = s; }
}

// ---------------- CSR build (once; edge lists are layer-invariant) ----------
__global__ void zero_int_kernel(int4* __restrict__ p, int n4)
{
    int i = blockIdx.x * blockDim.x + threadIdx.x;
    if (i < n4) p[i] = make_int4(0, 0, 0, 0);
}

__global__ void hist_kernel(const int* __restrict__ di, int* __restrict__ cnt, int E)
{
    int e = blockIdx.x * blockDim.x + threadIdx.x;
    if (e < E) atomicAdd(&cnt[di[e]], 1);
}

__global__ __launch_bounds__(256) void scan_a_kernel(const int* __restrict__ cnt,
                                                     int* __restrict__ bsum, int n)
{
    __shared__ int s[256];
    int tid = threadIdx.x;
    int i = blockIdx.x * 256 + tid;
    s[tid] = (i < n) ? cnt[i] : 0;
    __syncthreads();
    for (int st = 128; st > 0; st >>= 1) {
        if (tid < st) s[tid] += s[tid + st];
        __syncthreads();
    }
    if (tid == 0) bsum[blockIdx.x] = s[0];
}

__global__ __launch_bounds__(256) void scan_b_kernel(int* __restrict__ bsum,
                                                     int* __restrict__ roff, int nb, int n)
{
    __shared__ int s[256];
    int tid = threadIdx.x;
    int v = (tid < nb) ? bsum[tid] : 0;
    s[tid] = v;
    __syncthreads();
    for (int off = 1; off < 256; off <<= 1) {
        int t = (tid >= off) ? s[tid - off] : 0;
        __syncthreads();
        s[tid] += t;
        __syncthreads();
    }
    if (tid < nb) bsum[tid] = s[tid] - v;
    if (tid == 255) roff[n] = s[255];
}

__global__ __launch_bounds__(256) void scan_c_kernel(const int* __restrict__ cnt,
                                                     const int* __restrict__ bsum,
                                                     int* __restrict__ roff, int n)
{
    __shared__ int s[256];
    int tid = threadIdx.x;
    int i = blockIdx.x * 256 + tid;
    int v = (i < n) ? cnt[i] : 0;
    s[tid] = v;
    __syncthreads();
    for (int off = 1; off < 256; off <<= 1) {
        int t = (tid >= off) ? s[tid - off] : 0;
        __syncthreads();
        s[tid] += t;
        __syncthreads();
    }
    if (i < n) roff[i] = bsum[blockIdx.x] + s[tid] - v;
}

__global__ void csr_fill_kernel(const int* __restrict__ si, const int* __restrict__ di,
                                const int* __restrict__ roff, int* __restrict__ cur,
                                int* __restrict__ csrc, int E)
{
    int e = blockIdx.x * blockDim.x + threadIdx.x;
    if (e >= E) return;
    int d = di[e];
    int pos = roff[d] + atomicAdd(&cur[d], 1);
    csrc[pos] = si[e];
}

// ---------------------------------------------------------------------------
// Fused gather: one wave per destination; single-pass softmax-weighted sum.
// ---------------------------------------------------------------------------
__global__ __launch_bounds__(256) void edge_gather_kernel(
    const int* __restrict__ roff, const int* __restrict__ csrc,
    const float* __restrict__ as_, const float* __restrict__ ad_,
    const bf16* __restrict__ xh, float* __restrict__ out, int Ndst)
{
    int w = blockIdx.x * 4 + (threadIdx.x >> 6);
    int lane = threadIdx.x & 63;
    if (w >= Ndst) return;
    int h = lane >> 3;
    int beg = roff[w], end = roff[w + 1];
    float ad = ad_[(long)w * 8 + h];
    float den = 0.f, acc0 = 0.f, acc1 = 0.f;
    for (int e = beg; e < end; e++) {
        int s = csrc[e];
        float a = as_[(long)s * 8 + h] + ad;
        a = a >= 0.f ? a : 0.2f * a;
        float wt = __expf(fminf(a, 60.f));
        den += wt;
        bf162 x2 = *(const bf162*)(xh + (long)s * HID + lane * 2);
        acc0 = fmaf(__bfloat162float(x2.x), wt, acc0);
        acc1 = fmaf(__bfloat162float(x2.y), wt, acc1);
    }
    float inv = 1.f / (den + 1e-16f);
    out[(long)w * HID + lane * 2]     = fmaxf(acc0 * inv, 0.f);
    out[(long)w * HID + lane * 2 + 1] = fmaxf(acc1 * inv, 0.f);
}

__global__ void combine_kernel(const float* __restrict__ a0, const float* __restrict__ a1,
                               const float* __restrict__ score, float* __restrict__ out, int n)
{
    int i = blockIdx.x * blockDim.x + threadIdx.x;
    if (i >= n) return;
    float s0 = score[0] * (1.f / N_PAPER);
    float s1 = score[1] * (1.f / N_PAPER);
    float m = fmaxf(s0, s1);
    float e0 = __expf(s0 - m), e1 = __expf(s1 - m);
    float inv = 1.f / (e0 + e1);
    out[i] = a0[i] * (e0 * inv) + a1[i] * (e1 * inv);
}

__global__ void zero_f_kernel(float* __restrict__ p, int n)
{
    int i = blockIdx.x * blockDim.x + threadIdx.x;
    if (i < n) p[i] = 0.f;
}

__global__ __launch_bounds__(256) void final_lin_kernel(
    const float* __restrict__ X, const float* __restrict__ W,
    const float* __restrict__ B, float* __restrict__ out)
{
    __shared__ float Ws[HID * NCLS];
    int tid = threadIdx.x;
    for (int i = tid; i < HID * NCLS; i += 256) Ws[i] = W[i];
    __syncthreads();
    int i = blockIdx.x * 256 + tid;
    if (i >= N_PAPER * NCLS) return;
    int n = i >> 4, c = i & 15;
    float acc = B[c];
    const float* x = X + (long)n * HID;
    #pragma unroll 16
    for (int k = 0; k < HID; k++) acc = fmaf(x[k], Ws[k * NCLS + c], acc);
    out[i] = acc;
}

extern "C" void kernel_launch(void* const* d_in, const int* in_sizes, int n_in,
                              void* d_out, int out_size, void* d_ws, size_t ws_size,
                              hipStream_t stream)
{
    const float* x_author = (const float*)d_in[0];
    const float* x_paper  = (const float*)d_in[1];
    const float* Wa       = (const float*)d_in[2];
    const float* proj_w   = (const float*)d_in[3];
    const float* proj_b   = (const float*)d_in[4];
    const float* att_src  = (const float*)d_in[5];
    const float* att_dst  = (const float*)d_in[6];
    const float* klin_w   = (const float*)d_in[7];
    const float* klin_b   = (const float*)d_in[8];
    const float* qv       = (const float*)d_in[9];
    const float* lin_w    = (const float*)d_in[10];
    const float* lin_b    = (const float*)d_in[11];
    const int*  ei_w      = (const int*)d_in[12];
    const int*  ei_wb     = (const int*)d_in[13];
    const int*  ei_c      = (const int*)d_in[14];
    float* out = (float*)d_out;
    (void)ws_size; (void)in_sizes; (void)n_in; (void)out_size;

    char* base = (char*)d_ws;
    size_t off = 0;
    auto alloc = [&](size_t bytes) {
        void* p = base + off;
        off = (off + bytes + 255) & ~(size_t)255;
        return p;
    };
    bf16*  xh_a  = (bf16*) alloc((size_t)N_AUTHOR * HID * 2);
    bf16*  xh_p  = (bf16*) alloc((size_t)N_PAPER  * HID * 2);
    float* a_e0s = (float*)alloc((size_t)N_AUTHOR * HEADS * 4);
    float* a_e0d = (float*)alloc((size_t)N_PAPER  * HEADS * 4);
    float* a_e1s = (float*)alloc((size_t)N_PAPER  * HEADS * 4);
    float* a_e1d = (float*)alloc((size_t)N_AUTHOR * HEADS * 4);
    float* a_e2s = (float*)alloc((size_t)N_PAPER  * HEADS * 4);
    float* a_e2d = (float*)alloc((size_t)N_PAPER  * HEADS * 4);
    float* buf_a  = (float*)alloc((size_t)N_AUTHOR * HID * 4);
    float* buf_p  = (float*)alloc((size_t)N_PAPER  * HID * 4);
    float* agg_p1 = (float*)alloc((size_t)N_PAPER  * HID * 4);
    float* score  = (float*)alloc(64);
    int* roff0 = (int*)alloc((size_t)(N_PAPER  + 1) * 4);
    int* roff1 = (int*)alloc((size_t)(N_AUTHOR + 1) * 4);
    int* roff2 = (int*)alloc((size_t)(N_PAPER  + 1) * 4);
    int* csrc0 = (int*)alloc((size_t)NEDGE * 4);
    int* csrc1 = (int*)alloc((size_t)NEDGE * 4);
    int* csrc2 = (int*)alloc((size_t)NEDGE * 4);
    int* cnt   = (int*)alloc((size_t)N_PAPER * 4);
    int* bsum  = (int*)alloc(256 * 4);

    const int GA = (N_AUTHOR + 63) / 64;   // 313
    const int GP = (N_PAPER  + 63) / 64;   // 625
    const int GE = (NEDGE + 255) / 256;

    // ---- build 3 CSRs ----
    {
        struct { const int* si; const int* di; int* roff; int* csrc; int nd; } jobs[3] = {
            { ei_w,  ei_w  + NEDGE, roff0, csrc0, N_PAPER  },
            { ei_wb, ei_wb + NEDGE, roff1, csrc1, N_AUTHOR },
            { ei_c,  ei_c  + NEDGE, roff2, csrc2, N_PAPER  },
        };
        for (int j = 0; j < 3; j++) {
            int nd = jobs[j].nd;
            int n4 = (nd + 3) / 4;
            int nb = (nd + 255) / 256;
            zero_int_kernel<<<(n4 + 255)/256, 256, 0, stream>>>((int4*)cnt, n4);
            hist_kernel<<<GE, 256, 0, stream>>>(jobs[j].di, cnt, NEDGE);
            scan_a_kernel<<<nb, 256, 0, stream>>>(cnt, bsum, nd);
            scan_b_kernel<<<1, 256, 0, stream>>>(bsum, jobs[j].roff, nb, nd);
            scan_c_kernel<<<nb, 256, 0, stream>>>(cnt, bsum, jobs[j].roff, nd);
            zero_int_kernel<<<(n4 + 255)/256, 256, 0, stream>>>((int4*)cnt, n4);
            csr_fill_kernel<<<GE, 256, 0, stream>>>(jobs[j].si, jobs[j].di, jobs[j].roff, cnt, jobs[j].csrc, NEDGE);
        }
    }

    // input projection: author 64 -> 128 (f32 into buf_a)
    gemm_kernel<float, 64, 0><<<GA, 256, 0, stream>>>(
        x_author, Wa, nullptr, buf_a, nullptr, nullptr, N_AUTHOR);

    for (int l = 0; l < 2; l++) {
        const bool last = (l == 1);
        const float* cur_a = buf_a;
        const float* cur_p = (l == 0) ? x_paper : buf_p;
        const float* pw_a = proj_w + (size_t)(l*2 + 0) * HID * HID;
        const float* pw_p = proj_w + (size_t)(l*2 + 1) * HID * HID;
        const float* pb_a = proj_b + (size_t)(l*2 + 0) * HID;
        const float* pb_p = proj_b + (size_t)(l*2 + 1) * HID;

        // projections via MFMA (bf16 in-register, f32 accum), write bf16 xh
        mfma_gemm_kernel<bf16, false, 0><<<GA, 256, 0, stream>>>(
            cur_a, pw_a, pb_a, xh_a, nullptr, nullptr, N_AUTHOR);
        mfma_gemm_kernel<bf16, false, 0><<<GP, 256, 0, stream>>>(
            cur_p, pw_p, pb_p, xh_p, nullptr, nullptr, N_PAPER);

        zero_f_kernel<<<1, 64, 0, stream>>>(score, 16);

        const float* as0 = att_src + (size_t)(l*3 + 0) * HID;
        const float* ad0 = att_dst + (size_t)(l*3 + 0) * HID;
        const float* as1 = att_src + (size_t)(l*3 + 1) * HID;
        const float* ad1 = att_dst + (size_t)(l*3 + 1) * HID;
        const float* as2 = att_src + (size_t)(l*3 + 2) * HID;
        const float* ad2 = att_dst + (size_t)(l*3 + 2) * HID;

        node_att_multi_kernel<<<(N_AUTHOR*HEADS + 255)/256, 256, 0, stream>>>(
            xh_a, as0, last ? nullptr : ad1, nullptr, nullptr,
            a_e0s, a_e1d, nullptr, nullptr, N_AUTHOR);
        node_att_multi_kernel<<<(N_PAPER*HEADS + 255)/256, 256, 0, stream>>>(
            xh_p, ad0, last ? nullptr : as1, as2, ad2,
            a_e0d, a_e1s, a_e2s, a_e2d, N_PAPER);

        edge_gather_kernel<<<(N_PAPER + 3)/4, 256, 0, stream>>>(
            roff0, csrc0, a_e0s, a_e0d, xh_a, buf_p, N_PAPER);
        if (!last)
            edge_gather_kernel<<<(N_AUTHOR + 3)/4, 256, 0, stream>>>(
                roff1, csrc1, a_e1s, a_e1d, xh_p, buf_a, N_AUTHOR);
        edge_gather_kernel<<<(N_PAPER + 3)/4, 256, 0, stream>>>(
            roff2, csrc2, a_e2s, a_e2d, xh_p, agg_p1, N_PAPER);

        // klin semantic scores via MFMA (relu on A in-register)
        const float* kw = klin_w + (size_t)l * HID * HID;
        const float* kb = klin_b + (size_t)l * HID;
        const float* qq = qv     + (size_t)l * HID;
        mfma_gemm_kernel<float, true, 1><<<GP, 256, 0, stream>>>(
            buf_p, kw, kb, (float*)nullptr, qq, score + 0, N_PAPER);
        mfma_gemm_kernel<float, true, 1><<<GP, 256, 0, stream>>>(
            agg_p1, kw, kb, (float*)nullptr, qq, score + 1, N_PAPER);

        combine_kernel<<<(N_PAPER*HID + 255)/256, 256, 0, stream>>>(buf_p, agg_p1, score, buf_p, N_PAPER*HID);
    }

    final_lin_kernel<<<(N_PAPER*NCLS + 255)/256, 256, 0, stream>>>(buf_p, lin_w, lin_b, out);
}

// Round 7
// 691.458 us; speedup vs baseline: 4.4427x; 1.0233x over previous
//
#include <hip/hip_runtime.h>
#include <hip/hip_bf16.h>

typedef __hip_bfloat16 bf16;
typedef __hip_bfloat162 bf162;

#define N_AUTHOR 20000
#define N_PAPER  40000
#define NEDGE    400000
#define HID      128
#define HEADS    8
#define DIMH     16
#define NCLS     16

typedef short short4v __attribute__((ext_vector_type(4)));
typedef short short8v __attribute__((ext_vector_type(8)));
typedef float f32x4   __attribute__((ext_vector_type(4)));

__device__ __forceinline__ void stf(float* p, float v){ *p = v; }
__device__ __forceinline__ void stf(bf16* p, float v){ *p = __float2bfloat16(v); }

// float -> bf16 bits (round-to-nearest-even; finite inputs only)
__device__ __forceinline__ short f2bs(float v){
    unsigned u = __float_as_uint(v);
    unsigned r = (u + 0x7FFFu + ((u >> 16) & 1u)) >> 16;
    return (short)r;
}

// ---------------------------------------------------------------------------
// MFMA GEMM: C[M,128] = act(A[M,KDIM]) @ W[KDIM,128] + bias
// A,W f32 in global; converted to bf16 in-register; f32 accumulate.
// Block = 256 thr = 4 waves; wave computes 16 rows x 128 cols.
// W staged to LDS transposed Wt[col][k], stride KDIM+8 (16B-aligned rows).
// EPI==0: store C (TC float/bf16).  EPI==1: tanh, dot q, reduce, atomicAdd.
// ---------------------------------------------------------------------------
template<typename TC, int KDIM, bool RELU_A, int EPI>
__global__ __launch_bounds__(256) void mfma_gemm_kernel(
    const float* __restrict__ A, const float* __restrict__ W, const float* __restrict__ Bb,
    TC* __restrict__ C, const float* __restrict__ qv, float* __restrict__ score, int M)
{
    const int STR = KDIM + 8;
    __shared__ short Wt[128 * STR];     // Wt[c][k]
    const int tid = threadIdx.x;
    #pragma unroll
    for (int p = tid; p < 128 * (KDIM / 4); p += 256) {
        int c  = p & 127;
        int k0 = (p >> 7) * 4;
        short4v s;
        #pragma unroll
        for (int j = 0; j < 4; j++)
            s[j] = f2bs(W[(k0 + j) * HID + c]);
        *(short4v*)&Wt[c * STR + k0] = s;
    }
    __syncthreads();

    const int lane = tid & 63;
    const int wv   = tid >> 6;
    const int lr   = lane & 15;
    const int quad = lane >> 4;
    const int row0 = blockIdx.x * 64 + wv * 16;
    const int arow_i = row0 + lr;
    const bool rowok = arow_i < M;
    const float* arow = A + (long)arow_i * KDIM;

    short8v afrag[KDIM / 32];
    #pragma unroll
    for (int kc = 0; kc < KDIM / 32; kc++) {
        short8v f;
        #pragma unroll
        for (int j = 0; j < 8; j++) {
            float v = rowok ? arow[kc * 32 + quad * 8 + j] : 0.f;
            if (RELU_A) v = fmaxf(v, 0.f);
            f[j] = f2bs(v);
        }
        afrag[kc] = f;
    }

    f32x4 acc[8];
    #pragma unroll
    for (int ct = 0; ct < 8; ct++) acc[ct] = (f32x4){0.f, 0.f, 0.f, 0.f};

    #pragma unroll
    for (int ct = 0; ct < 8; ct++) {
        #pragma unroll
        for (int kc = 0; kc < KDIM / 32; kc++) {
            short8v bfrag = *(const short8v*)&Wt[(ct * 16 + lr) * STR + kc * 32 + quad * 8];
            acc[ct] = __builtin_amdgcn_mfma_f32_16x16x32_bf16(afrag[kc], bfrag, acc[ct], 0, 0, 0);
        }
    }

    // D mapping: row = row0 + quad*4 + r, col = ct*16 + lr
    if (EPI == 0) {
        #pragma unroll
        for (int ct = 0; ct < 8; ct++) {
            float bc = Bb ? Bb[ct * 16 + lr] : 0.f;
            #pragma unroll
            for (int r = 0; r < 4; r++) {
                int orow = row0 + quad * 4 + r;
                if (orow < M)
                    stf(&C[(long)orow * HID + ct * 16 + lr], acc[ct][r] + bc);
            }
        }
    } else {
        float part = 0.f;
        #pragma unroll
        for (int ct = 0; ct < 8; ct++) {
            float bc = Bb ? Bb[ct * 16 + lr] : 0.f;
            float qc = qv[ct * 16 + lr];
            #pragma unroll
            for (int r = 0; r < 4; r++) {
                int orow = row0 + quad * 4 + r;
                if (orow < M) part += qc * tanhf(acc[ct][r] + bc);
            }
        }
        __shared__ float red[256];
        red[tid] = part;
        __syncthreads();
        for (int s = 128; s > 0; s >>= 1) {
            if (tid < s) red[tid] += red[tid + s];
            __syncthreads();
        }
        if (tid == 0) atomicAdd(score, red[0]);
    }
}

// multi-output node attention dots: O_k[n,h] = sum_d xh[n,h*16+d] * A_k[h,d]
__global__ void node_att_multi_kernel(const bf16* __restrict__ xh,
    const float* __restrict__ A0, const float* __restrict__ A1,
    const float* __restrict__ A2, const float* __restrict__ A3,
    float* __restrict__ O0, float* __restrict__ O1,
    float* __restrict__ O2, float* __restrict__ O3, int N)
{
    int i = blockIdx.x * blockDim.x + threadIdx.x;
    if (i >= N * HEADS) return;
    int n = i >> 3, h = i & 7;
    const bf16* row = xh + (long)n * HID + h * DIMH;
    float x[DIMH];
    #pragma unroll
    for (int d = 0; d < DIMH; d++) x[d] = __bfloat162float(row[d]);
    if (A0) { float s = 0.f;
        #pragma unroll
        for (int d = 0; d < DIMH; d++) s += x[d] * A0[h*DIMH + d];
        O0[i] = s; }
    if (A1) { float s = 0.f;
        #pragma unroll
        for (int d = 0; d < DIMH; d++) s += x[d] * A1[h*DIMH + d];
        O1[i] = s; }
    if (A2) { float s = 0.f;
        #pragma unroll
        for (int d = 0; d < DIMH; d++) s += x[d] * A2[h*DIMH + d];
        O2[i] = s; }
    if (A3) { float s = 0.f;
        #pragma unroll
        for (int d = 0; d < DIMH; d++) s += x[d] * A3[h*DIMH + d];
        O3[i] = s; }
}

// ---------------- batched CSR build (3 jobs in one set of launches) --------
// cnt layout: [0,N_PAPER) job0, [N_PAPER, N_PAPER+N_AUTHOR) job1,
//             [N_PAPER+N_AUTHOR, 2*N_PAPER+N_AUTHOR) job2
#define CNT_OFF1 N_PAPER
#define CNT_OFF2 (N_PAPER + N_AUTHOR)

__global__ void hist3_kernel(const int* __restrict__ d0, const int* __restrict__ d1,
                             const int* __restrict__ d2, int* __restrict__ cnt)
{
    int i = blockIdx.x * blockDim.x + threadIdx.x;
    if (i < NEDGE)               atomicAdd(&cnt[d0[i]], 1);
    else if (i < 2*NEDGE)        atomicAdd(&cnt[CNT_OFF1 + d1[i - NEDGE]], 1);
    else if (i < 3*NEDGE)        atomicAdd(&cnt[CNT_OFF2 + d2[i - 2*NEDGE]], 1);
}

__device__ __forceinline__ int job_nd(int j){ return j == 1 ? N_AUTHOR : N_PAPER; }
__device__ __forceinline__ int job_off(int j){ return j == 0 ? 0 : (j == 1 ? CNT_OFF1 : CNT_OFF2); }

// 3-phase scan, blockIdx.y = job. bsum[j*256 + b].
__global__ __launch_bounds__(256) void scan_a3_kernel(const int* __restrict__ cnt,
                                                      int* __restrict__ bsum)
{
    int j = blockIdx.y;
    int nd = job_nd(j), off = job_off(j);
    __shared__ int s[256];
    int tid = threadIdx.x;
    int i = blockIdx.x * 256 + tid;
    s[tid] = (i < nd) ? cnt[off + i] : 0;
    __syncthreads();
    for (int st = 128; st > 0; st >>= 1) {
        if (tid < st) s[tid] += s[tid + st];
        __syncthreads();
    }
    if (tid == 0) bsum[j * 256 + blockIdx.x] = s[0];
}

__global__ __launch_bounds__(256) void scan_b3_kernel(int* __restrict__ bsum,
    int* __restrict__ roff0, int* __restrict__ roff1, int* __restrict__ roff2)
{
    int j = blockIdx.x;
    int nd = job_nd(j);
    int nb = (nd + 255) / 256;
    int* roff = j == 0 ? roff0 : (j == 1 ? roff1 : roff2);
    __shared__ int s[256];
    int tid = threadIdx.x;
    int v = (tid < nb) ? bsum[j * 256 + tid] : 0;
    s[tid] = v;
    __syncthreads();
    for (int off = 1; off < 256; off <<= 1) {
        int t = (tid >= off) ? s[tid - off] : 0;
        __syncthreads();
        s[tid] += t;
        __syncthreads();
    }
    if (tid < nb) bsum[j * 256 + tid] = s[tid] - v;
    if (tid == 255) roff[nd] = s[255];
}

__global__ __launch_bounds__(256) void scan_c3_kernel(const int* __restrict__ cnt,
    const int* __restrict__ bsum,
    int* __restrict__ roff0, int* __restrict__ roff1, int* __restrict__ roff2)
{
    int j = blockIdx.y;
    int nd = job_nd(j), off = job_off(j);
    int* roff = j == 0 ? roff0 : (j == 1 ? roff1 : roff2);
    __shared__ int s[256];
    int tid = threadIdx.x;
    int i = blockIdx.x * 256 + tid;
    int v = (i < nd) ? cnt[off + i] : 0;
    s[tid] = v;
    __syncthreads();
    for (int o = 1; o < 256; o <<= 1) {
        int t = (tid >= o) ? s[tid - o] : 0;
        __syncthreads();
        s[tid] += t;
        __syncthreads();
    }
    if (i < nd) roff[i] = bsum[j * 256 + blockIdx.x] + s[tid] - v;
}

__global__ void fill3_kernel(
    const int* __restrict__ s0, const int* __restrict__ d0,
    const int* __restrict__ s1, const int* __restrict__ d1,
    const int* __restrict__ s2, const int* __restrict__ d2,
    const int* __restrict__ roff0, const int* __restrict__ roff1, const int* __restrict__ roff2,
    int* __restrict__ cur,
    int* __restrict__ c0, int* __restrict__ c1, int* __restrict__ c2)
{
    int i = blockIdx.x * blockDim.x + threadIdx.x;
    if (i < NEDGE) {
        int d = d0[i];
        int pos = roff0[d] + atomicAdd(&cur[d], 1);
        c0[pos] = s0[i];
    } else if (i < 2*NEDGE) {
        int e = i - NEDGE, d = d1[e];
        int pos = roff1[d] + atomicAdd(&cur[CNT_OFF1 + d], 1);
        c1[pos] = s1[e];
    } else if (i < 3*NEDGE) {
        int e = i - 2*NEDGE, d = d2[e];
        int pos = roff2[d] + atomicAdd(&cur[CNT_OFF2 + d], 1);
        c2[pos] = s2[e];
    }
}

// ---------------------------------------------------------------------------
// Fused paper gather: one wave per paper dest; runs BOTH metapath edge chains
// (e0 over xh_a, e2 over xh_p) interleaved for 2x memory-level parallelism.
// ---------------------------------------------------------------------------
__global__ __launch_bounds__(256) void paper_gather2_kernel(
    const int* __restrict__ roff0, const int* __restrict__ csrc0,
    const float* __restrict__ as0, const float* __restrict__ ad0,
    const bf16* __restrict__ xha,
    const int* __restrict__ roff2, const int* __restrict__ csrc2,
    const float* __restrict__ as2, const float* __restrict__ ad2,
    const bf16* __restrict__ xhp,
    float* __restrict__ out0, float* __restrict__ out2)
{
    int w = blockIdx.x * 4 + (threadIdx.x >> 6);
    int lane = threadIdx.x & 63;
    if (w >= N_PAPER) return;
    int h = lane >> 3;
    int b0 = roff0[w], n0 = roff0[w + 1] - b0;
    int b2 = roff2[w], n2 = roff2[w + 1] - b2;
    float ad0v = ad0[(long)w * 8 + h];
    float ad2v = ad2[(long)w * 8 + h];
    float den0 = 0.f, p00 = 0.f, p01 = 0.f;
    float den2 = 0.f, p20 = 0.f, p21 = 0.f;
    int nmax = n0 > n2 ? n0 : n2;
    for (int i = 0; i < nmax; i++) {
        if (i < n0) {
            int s = csrc0[b0 + i];
            float a = as0[(long)s * 8 + h] + ad0v;
            a = a >= 0.f ? a : 0.2f * a;
            float wt = __expf(fminf(a, 60.f));
            den0 += wt;
            bf162 x2 = *(const bf162*)(xha + (long)s * HID + lane * 2);
            p00 = fmaf(__bfloat162float(x2.x), wt, p00);
            p01 = fmaf(__bfloat162float(x2.y), wt, p01);
        }
        if (i < n2) {
            int s = csrc2[b2 + i];
            float a = as2[(long)s * 8 + h] + ad2v;
            a = a >= 0.f ? a : 0.2f * a;
            float wt = __expf(fminf(a, 60.f));
            den2 += wt;
            bf162 x2 = *(const bf162*)(xhp + (long)s * HID + lane * 2);
            p20 = fmaf(__bfloat162float(x2.x), wt, p20);
            p21 = fmaf(__bfloat162float(x2.y), wt, p21);
        }
    }
    float inv0 = 1.f / (den0 + 1e-16f);
    float inv2 = 1.f / (den2 + 1e-16f);
    out0[(long)w * HID + lane * 2]     = fmaxf(p00 * inv0, 0.f);
    out0[(long)w * HID + lane * 2 + 1] = fmaxf(p01 * inv0, 0.f);
    out2[(long)w * HID + lane * 2]     = fmaxf(p20 * inv2, 0.f);
    out2[(long)w * HID + lane * 2 + 1] = fmaxf(p21 * inv2, 0.f);
}

// single gather (author dest, layer 0 only)
__global__ __launch_bounds__(256) void edge_gather_kernel(
    const int* __restrict__ roff, const int* __restrict__ csrc,
    const float* __restrict__ as_, const float* __restrict__ ad_,
    const bf16* __restrict__ xh, float* __restrict__ out, int Ndst)
{
    int w = blockIdx.x * 4 + (threadIdx.x >> 6);
    int lane = threadIdx.x & 63;
    if (w >= Ndst) return;
    int h = lane >> 3;
    int beg = roff[w], end = roff[w + 1];
    float ad = ad_[(long)w * 8 + h];
    float den = 0.f, acc0 = 0.f, acc1 = 0.f;
    for (int e = beg; e < end; e++) {
        int s = csrc[e];
        float a = as_[(long)s * 8 + h] + ad;
        a = a >= 0.f ? a : 0.2f * a;
        float wt = __expf(fminf(a, 60.f));
        den += wt;
        bf162 x2 = *(const bf162*)(xh + (long)s * HID + lane * 2);
        acc0 = fmaf(__bfloat162float(x2.x), wt, acc0);
        acc1 = fmaf(__bfloat162float(x2.y), wt, acc1);
    }
    float inv = 1.f / (den + 1e-16f);
    out[(long)w * HID + lane * 2]     = fmaxf(acc0 * inv, 0.f);
    out[(long)w * HID + lane * 2 + 1] = fmaxf(acc1 * inv, 0.f);
}

__global__ void combine_kernel(const float* __restrict__ a0, const float* __restrict__ a1,
                               const float* __restrict__ score, float* __restrict__ out, int n)
{
    int i = blockIdx.x * blockDim.x + threadIdx.x;
    if (i >= n) return;
    float s0 = score[0] * (1.f / N_PAPER);
    float s1 = score[1] * (1.f / N_PAPER);
    float m = fmaxf(s0, s1);
    float e0 = __expf(s0 - m), e1 = __expf(s1 - m);
    float inv = 1.f / (e0 + e1);
    out[i] = a0[i] * (e0 * inv) + a1[i] * (e1 * inv);
}

__global__ __launch_bounds__(256) void final_lin_kernel(
    const float* __restrict__ X, const float* __restrict__ W,
    const float* __restrict__ B, float* __restrict__ out)
{
    __shared__ float Ws[HID * NCLS];
    int tid = threadIdx.x;
    for (int i = tid; i < HID * NCLS; i += 256) Ws[i] = W[i];
    __syncthreads();
    int i = blockIdx.x * 256 + tid;
    if (i >= N_PAPER * NCLS) return;
    int n = i >> 4, c = i & 15;
    float acc = B[c];
    const float* x = X + (long)n * HID;
    #pragma unroll 16
    for (int k = 0; k < HID; k++) acc = fmaf(x[k], Ws[k * NCLS + c], acc);
    out[i] = acc;
}

extern "C" void kernel_launch(void* const* d_in, const int* in_sizes, int n_in,
                              void* d_out, int out_size, void* d_ws, size_t ws_size,
                              hipStream_t stream)
{
    const float* x_author = (const float*)d_in[0];
    const float* x_paper  = (const float*)d_in[1];
    const float* Wa       = (const float*)d_in[2];
    const float* proj_w   = (const float*)d_in[3];
    const float* proj_b   = (const float*)d_in[4];
    const float* att_src  = (const float*)d_in[5];
    const float* att_dst  = (const float*)d_in[6];
    const float* klin_w   = (const float*)d_in[7];
    const float* klin_b   = (const float*)d_in[8];
    const float* qv       = (const float*)d_in[9];
    const float* lin_w    = (const float*)d_in[10];
    const float* lin_b    = (const float*)d_in[11];
    const int*  ei_w      = (const int*)d_in[12];
    const int*  ei_wb     = (const int*)d_in[13];
    const int*  ei_c      = (const int*)d_in[14];
    float* out = (float*)d_out;
    (void)ws_size; (void)in_sizes; (void)n_in; (void)out_size;

    char* base = (char*)d_ws;
    size_t off = 0;
    auto alloc = [&](size_t bytes) {
        void* p = base + off;
        off = (off + bytes + 255) & ~(size_t)255;
        return p;
    };
    bf16*  xh_a  = (bf16*) alloc((size_t)N_AUTHOR * HID * 2);
    bf16*  xh_p  = (bf16*) alloc((size_t)N_PAPER  * HID * 2);
    float* a_e0s = (float*)alloc((size_t)N_AUTHOR * HEADS * 4);
    float* a_e0d = (float*)alloc((size_t)N_PAPER  * HEADS * 4);
    float* a_e1s = (float*)alloc((size_t)N_PAPER  * HEADS * 4);
    float* a_e1d = (float*)alloc((size_t)N_AUTHOR * HEADS * 4);
    float* a_e2s = (float*)alloc((size_t)N_PAPER  * HEADS * 4);
    float* a_e2d = (float*)alloc((size_t)N_PAPER  * HEADS * 4);
    float* buf_a  = (float*)alloc((size_t)N_AUTHOR * HID * 4);
    float* buf_p  = (float*)alloc((size_t)N_PAPER  * HID * 4);
    float* agg_p1 = (float*)alloc((size_t)N_PAPER  * HID * 4);
    float* score  = (float*)alloc(64);
    int* roff0 = (int*)alloc((size_t)(N_PAPER  + 1) * 4);
    int* roff1 = (int*)alloc((size_t)(N_AUTHOR + 1) * 4);
    int* roff2 = (int*)alloc((size_t)(N_PAPER  + 1) * 4);
    int* csrc0 = (int*)alloc((size_t)NEDGE * 4);
    int* csrc1 = (int*)alloc((size_t)NEDGE * 4);
    int* csrc2 = (int*)alloc((size_t)NEDGE * 4);
    int* cnt   = (int*)alloc((size_t)(2 * N_PAPER + N_AUTHOR) * 4);  // 3 jobs contiguous
    int* bsum  = (int*)alloc(3 * 256 * 4);

    const int GA = (N_AUTHOR + 63) / 64;   // 313
    const int GP = (N_PAPER  + 63) / 64;   // 625
    const int G3E = (3 * NEDGE + 255) / 256;
    const int NBMAX = (N_PAPER + 255) / 256;   // 157

    // ---- batched CSR build (7 stream ops) ----
    hipMemsetAsync(cnt, 0, (size_t)(2 * N_PAPER + N_AUTHOR) * 4, stream);
    hist3_kernel<<<G3E, 256, 0, stream>>>(ei_w + NEDGE, ei_wb + NEDGE, ei_c + NEDGE, cnt);
    scan_a3_kernel<<<dim3(NBMAX, 3), 256, 0, stream>>>(cnt, bsum);
    scan_b3_kernel<<<3, 256, 0, stream>>>(bsum, roff0, roff1, roff2);
    scan_c3_kernel<<<dim3(NBMAX, 3), 256, 0, stream>>>(cnt, bsum, roff0, roff1, roff2);
    hipMemsetAsync(cnt, 0, (size_t)(2 * N_PAPER + N_AUTHOR) * 4, stream);
    fill3_kernel<<<G3E, 256, 0, stream>>>(
        ei_w, ei_w + NEDGE, ei_wb, ei_wb + NEDGE, ei_c, ei_c + NEDGE,
        roff0, roff1, roff2, cnt, csrc0, csrc1, csrc2);

    // author input projection 64 -> 128 via MFMA (f32 out into buf_a)
    mfma_gemm_kernel<float, 64, false, 0><<<GA, 256, 0, stream>>>(
        x_author, Wa, nullptr, buf_a, nullptr, nullptr, N_AUTHOR);

    for (int l = 0; l < 2; l++) {
        const bool last = (l == 1);
        const float* cur_a = buf_a;
        const float* cur_p = (l == 0) ? x_paper : buf_p;
        const float* pw_a = proj_w + (size_t)(l*2 + 0) * HID * HID;
        const float* pw_p = proj_w + (size_t)(l*2 + 1) * HID * HID;
        const float* pb_a = proj_b + (size_t)(l*2 + 0) * HID;
        const float* pb_p = proj_b + (size_t)(l*2 + 1) * HID;

        mfma_gemm_kernel<bf16, 128, false, 0><<<GA, 256, 0, stream>>>(
            cur_a, pw_a, pb_a, xh_a, nullptr, nullptr, N_AUTHOR);
        mfma_gemm_kernel<bf16, 128, false, 0><<<GP, 256, 0, stream>>>(
            cur_p, pw_p, pb_p, xh_p, nullptr, nullptr, N_PAPER);

        hipMemsetAsync(score, 0, 64, stream);

        const float* as0 = att_src + (size_t)(l*3 + 0) * HID;
        const float* ad0 = att_dst + (size_t)(l*3 + 0) * HID;
        const float* as1 = att_src + (size_t)(l*3 + 1) * HID;
        const float* ad1 = att_dst + (size_t)(l*3 + 1) * HID;
        const float* as2 = att_src + (size_t)(l*3 + 2) * HID;
        const float* ad2 = att_dst + (size_t)(l*3 + 2) * HID;

        node_att_multi_kernel<<<(N_AUTHOR*HEADS + 255)/256, 256, 0, stream>>>(
            xh_a, as0, last ? nullptr : ad1, nullptr, nullptr,
            a_e0s, a_e1d, nullptr, nullptr, N_AUTHOR);
        node_att_multi_kernel<<<(N_PAPER*HEADS + 255)/256, 256, 0, stream>>>(
            xh_p, ad0, last ? nullptr : as1, as2, ad2,
            a_e0d, a_e1s, a_e2s, a_e2d, N_PAPER);

        // fused paper gather (e0 + e2); author gather (e1) only when needed
        paper_gather2_kernel<<<(N_PAPER + 3)/4, 256, 0, stream>>>(
            roff0, csrc0, a_e0s, a_e0d, xh_a,
            roff2, csrc2, a_e2s, a_e2d, xh_p,
            buf_p, agg_p1);
        if (!last)
            edge_gather_kernel<<<(N_AUTHOR + 3)/4, 256, 0, stream>>>(
                roff1, csrc1, a_e1s, a_e1d, xh_p, buf_a, N_AUTHOR);

        // klin semantic scores via MFMA (relu already applied in gather outputs)
        const float* kw = klin_w + (size_t)l * HID * HID;
        const float* kb = klin_b + (size_t)l * HID;
        const float* qq = qv     + (size_t)l * HID;
        mfma_gemm_kernel<float, 128, false, 1><<<GP, 256, 0, stream>>>(
            buf_p, kw, kb, (float*)nullptr, qq, score + 0, N_PAPER);
        mfma_gemm_kernel<float, 128, false, 1><<<GP, 256, 0, stream>>>(
            agg_p1, kw, kb, (float*)nullptr, qq, score + 1, N_PAPER);

        combine_kernel<<<(N_PAPER*HID + 255)/256, 256, 0, stream>>>(buf_p, agg_p1, score, buf_p, N_PAPER*HID);
    }

    final_lin_kernel<<<(N_PAPER*NCLS + 255)/256, 256, 0, stream>>>(buf_p, lin_w, lin_b, out);
}

// Round 8
// 549.441 us; speedup vs baseline: 5.5911x; 1.2585x over previous
//
#include <hip/hip_runtime.h>
#include <hip/hip_bf16.h>

typedef __hip_bfloat16 bf16;
typedef __hip_bfloat162 bf162;

#define N_AUTHOR 20000
#define N_PAPER  40000
#define NEDGE    400000
#define HID      128
#define HEADS    8
#define DIMH     16
#define NCLS     16

typedef short short4v __attribute__((ext_vector_type(4)));
typedef short short8v __attribute__((ext_vector_type(8)));
typedef float f32x4   __attribute__((ext_vector_type(4)));

__device__ __forceinline__ void stf(float* p, float v){ *p = v; }
__device__ __forceinline__ void stf(bf16* p, float v){ *p = __float2bfloat16(v); }

// float -> bf16 bits (round-to-nearest-even; finite inputs only)
__device__ __forceinline__ short f2bs(float v){
    unsigned u = __float_as_uint(v);
    unsigned r = (u + 0x7FFFu + ((u >> 16) & 1u)) >> 16;
    return (short)r;
}

// fast tanh via exp; |err| ~1e-7, clamp avoids inf/inf
__device__ __forceinline__ float fast_tanh(float x){
    x = fminf(fmaxf(x, -15.f), 15.f);
    float e = __expf(2.f * x);
    return (e - 1.f) / (e + 1.f);
}

// ---------------------------------------------------------------------------
// MFMA GEMM (single): C[M,128] = A[M,KDIM] @ W[KDIM,128] + bias
// ---------------------------------------------------------------------------
template<typename TC, int KDIM>
__global__ __launch_bounds__(256) void mfma_gemm_kernel(
    const float* __restrict__ A, const float* __restrict__ W, const float* __restrict__ Bb,
    TC* __restrict__ C, int M)
{
    const int STR = KDIM + 8;
    __shared__ short Wt[128 * STR];
    const int tid = threadIdx.x;
    #pragma unroll
    for (int p = tid; p < 128 * (KDIM / 4); p += 256) {
        int c  = p & 127;
        int k0 = (p >> 7) * 4;
        short4v s;
        #pragma unroll
        for (int j = 0; j < 4; j++) s[j] = f2bs(W[(k0 + j) * HID + c]);
        *(short4v*)&Wt[c * STR + k0] = s;
    }
    __syncthreads();

    const int lane = tid & 63;
    const int wv   = tid >> 6;
    const int lr   = lane & 15;
    const int quad = lane >> 4;
    const int row0 = blockIdx.x * 64 + wv * 16;
    const int arow_i = row0 + lr;
    const bool rowok = arow_i < M;
    const float* arow = A + (long)arow_i * KDIM;

    short8v afrag[KDIM / 32];
    #pragma unroll
    for (int kc = 0; kc < KDIM / 32; kc++) {
        short8v f;
        #pragma unroll
        for (int j = 0; j < 8; j++)
            f[j] = f2bs(rowok ? arow[kc * 32 + quad * 8 + j] : 0.f);
        afrag[kc] = f;
    }

    f32x4 acc[8];
    #pragma unroll
    for (int ct = 0; ct < 8; ct++) acc[ct] = (f32x4){0.f, 0.f, 0.f, 0.f};
    #pragma unroll
    for (int ct = 0; ct < 8; ct++)
        #pragma unroll
        for (int kc = 0; kc < KDIM / 32; kc++) {
            short8v bfrag = *(const short8v*)&Wt[(ct * 16 + lr) * STR + kc * 32 + quad * 8];
            acc[ct] = __builtin_amdgcn_mfma_f32_16x16x32_bf16(afrag[kc], bfrag, acc[ct], 0, 0, 0);
        }

    #pragma unroll
    for (int ct = 0; ct < 8; ct++) {
        float bc = Bb ? Bb[ct * 16 + lr] : 0.f;
        #pragma unroll
        for (int r = 0; r < 4; r++) {
            int orow = row0 + quad * 4 + r;
            if (orow < M)
                stf(&C[(long)orow * HID + ct * 16 + lr], acc[ct][r] + bc);
        }
    }
}

// ---------------------------------------------------------------------------
// Paired MFMA GEMM: two GEMMs (same shape class) in one launch.
// blocks [0,NB0) -> set 0, [NB0,..) -> set 1.
// EPI==0: store C. EPI==1: tanh epilogue, dot q, block-reduce, atomicAdd score.
// ---------------------------------------------------------------------------
template<typename TC, int KDIM, int EPI>
__global__ __launch_bounds__(256) void mfma_gemm_pair_kernel(
    const float* __restrict__ A0, const float* __restrict__ W0, const float* __restrict__ Bb0,
    TC* __restrict__ C0, float* __restrict__ score0, int M0, int NB0,
    const float* __restrict__ A1, const float* __restrict__ W1, const float* __restrict__ Bb1,
    TC* __restrict__ C1, float* __restrict__ score1, int M1,
    const float* __restrict__ qv)
{
    const int STR = KDIM + 8;
    __shared__ short Wt[128 * STR];
    const int tid = threadIdx.x;
    const int bx = blockIdx.x;
    const bool second = bx >= NB0;
    const float* A = second ? A1 : A0;
    const float* W = second ? W1 : W0;
    const float* Bb = second ? Bb1 : Bb0;
    TC* C = second ? C1 : C0;
    float* score = second ? score1 : score0;
    const int M = second ? M1 : M0;
    const int brow = second ? bx - NB0 : bx;

    #pragma unroll
    for (int p = tid; p < 128 * (KDIM / 4); p += 256) {
        int c  = p & 127;
        int k0 = (p >> 7) * 4;
        short4v s;
        #pragma unroll
        for (int j = 0; j < 4; j++) s[j] = f2bs(W[(k0 + j) * HID + c]);
        *(short4v*)&Wt[c * STR + k0] = s;
    }
    __syncthreads();

    const int lane = tid & 63;
    const int wv   = tid >> 6;
    const int lr   = lane & 15;
    const int quad = lane >> 4;
    const int row0 = brow * 64 + wv * 16;
    const int arow_i = row0 + lr;
    const bool rowok = arow_i < M;
    const float* arow = A + (long)arow_i * KDIM;

    short8v afrag[KDIM / 32];
    #pragma unroll
    for (int kc = 0; kc < KDIM / 32; kc++) {
        short8v f;
        #pragma unroll
        for (int j = 0; j < 8; j++)
            f[j] = f2bs(rowok ? arow[kc * 32 + quad * 8 + j] : 0.f);
        afrag[kc] = f;
    }

    f32x4 acc[8];
    #pragma unroll
    for (int ct = 0; ct < 8; ct++) acc[ct] = (f32x4){0.f, 0.f, 0.f, 0.f};
    #pragma unroll
    for (int ct = 0; ct < 8; ct++)
        #pragma unroll
        for (int kc = 0; kc < KDIM / 32; kc++) {
            short8v bfrag = *(const short8v*)&Wt[(ct * 16 + lr) * STR + kc * 32 + quad * 8];
            acc[ct] = __builtin_amdgcn_mfma_f32_16x16x32_bf16(afrag[kc], bfrag, acc[ct], 0, 0, 0);
        }

    if (EPI == 0) {
        #pragma unroll
        for (int ct = 0; ct < 8; ct++) {
            float bc = Bb ? Bb[ct * 16 + lr] : 0.f;
            #pragma unroll
            for (int r = 0; r < 4; r++) {
                int orow = row0 + quad * 4 + r;
                if (orow < M)
                    stf(&C[(long)orow * HID + ct * 16 + lr], acc[ct][r] + bc);
            }
        }
    } else {
        float part = 0.f;
        #pragma unroll
        for (int ct = 0; ct < 8; ct++) {
            float bc = Bb ? Bb[ct * 16 + lr] : 0.f;
            float qc = qv[ct * 16 + lr];
            #pragma unroll
            for (int r = 0; r < 4; r++) {
                int orow = row0 + quad * 4 + r;
                if (orow < M) part += qc * fast_tanh(acc[ct][r] + bc);
            }
        }
        __shared__ float red[256];
        red[tid] = part;
        __syncthreads();
        for (int s = 128; s > 0; s >>= 1) {
            if (tid < s) red[tid] += red[tid + s];
            __syncthreads();
        }
        if (tid == 0) atomicAdd(score, red[0]);
    }
}

// multi-output node attention dots
__global__ void node_att_multi_kernel(const bf16* __restrict__ xh,
    const float* __restrict__ A0, const float* __restrict__ A1,
    const float* __restrict__ A2, const float* __restrict__ A3,
    float* __restrict__ O0, float* __restrict__ O1,
    float* __restrict__ O2, float* __restrict__ O3, int N)
{
    int i = blockIdx.x * blockDim.x + threadIdx.x;
    if (i >= N * HEADS) return;
    int n = i >> 3, h = i & 7;
    const bf16* row = xh + (long)n * HID + h * DIMH;
    float x[DIMH];
    #pragma unroll
    for (int d = 0; d < DIMH; d++) x[d] = __bfloat162float(row[d]);
    if (A0) { float s = 0.f;
        #pragma unroll
        for (int d = 0; d < DIMH; d++) s += x[d] * A0[h*DIMH + d];
        O0[i] = s; }
    if (A1) { float s = 0.f;
        #pragma unroll
        for (int d = 0; d < DIMH; d++) s += x[d] * A1[h*DIMH + d];
        O1[i] = s; }
    if (A2) { float s = 0.f;
        #pragma unroll
        for (int d = 0; d < DIMH; d++) s += x[d] * A2[h*DIMH + d];
        O2[i] = s; }
    if (A3) { float s = 0.f;
        #pragma unroll
        for (int d = 0; d < DIMH; d++) s += x[d] * A3[h*DIMH + d];
        O3[i] = s; }
}

// ---------------- batched CSR build ----------------
#define CNT_OFF1 N_PAPER
#define CNT_OFF2 (N_PAPER + N_AUTHOR)

__global__ void hist3_kernel(const int* __restrict__ d0, const int* __restrict__ d1,
                             const int* __restrict__ d2, int* __restrict__ cnt)
{
    int i = blockIdx.x * blockDim.x + threadIdx.x;
    if (i < NEDGE)               atomicAdd(&cnt[d0[i]], 1);
    else if (i < 2*NEDGE)        atomicAdd(&cnt[CNT_OFF1 + d1[i - NEDGE]], 1);
    else if (i < 3*NEDGE)        atomicAdd(&cnt[CNT_OFF2 + d2[i - 2*NEDGE]], 1);
}

__device__ __forceinline__ int job_nd(int j){ return j == 1 ? N_AUTHOR : N_PAPER; }
__device__ __forceinline__ int job_off(int j){ return j == 0 ? 0 : (j == 1 ? CNT_OFF1 : CNT_OFF2); }

__global__ __launch_bounds__(256) void scan_a3_kernel(const int* __restrict__ cnt,
                                                      int* __restrict__ bsum)
{
    int j = blockIdx.y;
    int nd = job_nd(j), off = job_off(j);
    __shared__ int s[256];
    int tid = threadIdx.x;
    int i = blockIdx.x * 256 + tid;
    s[tid] = (i < nd) ? cnt[off + i] : 0;
    __syncthreads();
    for (int st = 128; st > 0; st >>= 1) {
        if (tid < st) s[tid] += s[tid + st];
        __syncthreads();
    }
    if (tid == 0) bsum[j * 256 + blockIdx.x] = s[0];
}

__global__ __launch_bounds__(256) void scan_b3_kernel(int* __restrict__ bsum,
    int* __restrict__ roff0, int* __restrict__ roff1, int* __restrict__ roff2)
{
    int j = blockIdx.x;
    int nd = job_nd(j);
    int nb = (nd + 255) / 256;
    int* roff = j == 0 ? roff0 : (j == 1 ? roff1 : roff2);
    __shared__ int s[256];
    int tid = threadIdx.x;
    int v = (tid < nb) ? bsum[j * 256 + tid] : 0;
    s[tid] = v;
    __syncthreads();
    for (int off = 1; off < 256; off <<= 1) {
        int t = (tid >= off) ? s[tid - off] : 0;
        __syncthreads();
        s[tid] += t;
        __syncthreads();
    }
    if (tid < nb) bsum[j * 256 + tid] = s[tid] - v;
    if (tid == 255) roff[nd] = s[255];
}

__global__ __launch_bounds__(256) void scan_c3_kernel(const int* __restrict__ cnt,
    const int* __restrict__ bsum,
    int* __restrict__ roff0, int* __restrict__ roff1, int* __restrict__ roff2)
{
    int j = blockIdx.y;
    int nd = job_nd(j), off = job_off(j);
    int* roff = j == 0 ? roff0 : (j == 1 ? roff1 : roff2);
    __shared__ int s[256];
    int tid = threadIdx.x;
    int i = blockIdx.x * 256 + tid;
    int v = (i < nd) ? cnt[off + i] : 0;
    s[tid] = v;
    __syncthreads();
    for (int o = 1; o < 256; o <<= 1) {
        int t = (tid >= o) ? s[tid - o] : 0;
        __syncthreads();
        s[tid] += t;
        __syncthreads();
    }
    if (i < nd) roff[i] = bsum[j * 256 + blockIdx.x] + s[tid] - v;
}

__global__ void fill3_kernel(
    const int* __restrict__ s0, const int* __restrict__ d0,
    const int* __restrict__ s1, const int* __restrict__ d1,
    const int* __restrict__ s2, const int* __restrict__ d2,
    const int* __restrict__ roff0, const int* __restrict__ roff1, const int* __restrict__ roff2,
    int* __restrict__ cur,
    int* __restrict__ c0, int* __restrict__ c1, int* __restrict__ c2)
{
    int i = blockIdx.x * blockDim.x + threadIdx.x;
    if (i < NEDGE) {
        int d = d0[i];
        int pos = roff0[d] + atomicAdd(&cur[d], 1);
        c0[pos] = s0[i];
    } else if (i < 2*NEDGE) {
        int e = i - NEDGE, d = d1[e];
        int pos = roff1[d] + atomicAdd(&cur[CNT_OFF1 + d], 1);
        c1[pos] = s1[e];
    } else if (i < 3*NEDGE) {
        int e = i - 2*NEDGE, d = d2[e];
        int pos = roff2[d] + atomicAdd(&cur[CNT_OFF2 + d], 1);
        c2[pos] = s2[e];
    }
}

// ---------------------------------------------------------------------------
// Fused paper gather, 4-deep load batching per chain (8 rows in flight).
// Branch-free: indices clamped, pad weights zeroed.
// ---------------------------------------------------------------------------
__global__ __launch_bounds__(256) void paper_gather2_kernel(
    const int* __restrict__ roff0, const int* __restrict__ csrc0,
    const float* __restrict__ as0, const float* __restrict__ ad0,
    const bf16* __restrict__ xha,
    const int* __restrict__ roff2, const int* __restrict__ csrc2,
    const float* __restrict__ as2, const float* __restrict__ ad2,
    const bf16* __restrict__ xhp,
    float* __restrict__ out0, float* __restrict__ out2)
{
    int w = blockIdx.x * 4 + (threadIdx.x >> 6);
    int lane = threadIdx.x & 63;
    if (w >= N_PAPER) return;
    int h = lane >> 3;
    int b0 = roff0[w], n0 = roff0[w + 1] - b0;
    int b2 = roff2[w], n2 = roff2[w + 1] - b2;
    float ad0v = ad0[(long)w * 8 + h];
    float ad2v = ad2[(long)w * 8 + h];
    float den0 = 0.f, p00 = 0.f, p01 = 0.f;
    float den2 = 0.f, p20 = 0.f, p21 = 0.f;
    int nmax = n0 > n2 ? n0 : n2;
    int c0m = n0 > 0 ? n0 - 1 : 0;
    int c2m = n2 > 0 ? n2 - 1 : 0;
    for (int i = 0; i < nmax; i += 4) {
        int sA[4], sB[4];
        #pragma unroll
        for (int u = 0; u < 4; u++) {
            sA[u] = csrc0[b0 + min(i + u, c0m)];
            sB[u] = csrc2[b2 + min(i + u, c2m)];
        }
        float aA[4], aB[4];
        bf162 xA[4], xB[4];
        #pragma unroll
        for (int u = 0; u < 4; u++) {
            aA[u] = as0[(long)sA[u] * 8 + h];
            xA[u] = *(const bf162*)(xha + (long)sA[u] * HID + lane * 2);
            aB[u] = as2[(long)sB[u] * 8 + h];
            xB[u] = *(const bf162*)(xhp + (long)sB[u] * HID + lane * 2);
        }
        #pragma unroll
        for (int u = 0; u < 4; u++) {
            float a = aA[u] + ad0v;
            a = a >= 0.f ? a : 0.2f * a;
            float wt = __expf(fminf(a, 60.f));
            wt = (i + u < n0) ? wt : 0.f;
            den0 += wt;
            p00 = fmaf(__bfloat162float(xA[u].x), wt, p00);
            p01 = fmaf(__bfloat162float(xA[u].y), wt, p01);
            a = aB[u] + ad2v;
            a = a >= 0.f ? a : 0.2f * a;
            wt = __expf(fminf(a, 60.f));
            wt = (i + u < n2) ? wt : 0.f;
            den2 += wt;
            p20 = fmaf(__bfloat162float(xB[u].x), wt, p20);
            p21 = fmaf(__bfloat162float(xB[u].y), wt, p21);
        }
    }
    float inv0 = 1.f / (den0 + 1e-16f);
    float inv2 = 1.f / (den2 + 1e-16f);
    out0[(long)w * HID + lane * 2]     = fmaxf(p00 * inv0, 0.f);
    out0[(long)w * HID + lane * 2 + 1] = fmaxf(p01 * inv0, 0.f);
    out2[(long)w * HID + lane * 2]     = fmaxf(p20 * inv2, 0.f);
    out2[(long)w * HID + lane * 2 + 1] = fmaxf(p21 * inv2, 0.f);
}

// single gather (author dest, layer 0 only), 4-deep batching
__global__ __launch_bounds__(256) void edge_gather_kernel(
    const int* __restrict__ roff, const int* __restrict__ csrc,
    const float* __restrict__ as_, const float* __restrict__ ad_,
    const bf16* __restrict__ xh, float* __restrict__ out, int Ndst)
{
    int w = blockIdx.x * 4 + (threadIdx.x >> 6);
    int lane = threadIdx.x & 63;
    if (w >= Ndst) return;
    int h = lane >> 3;
    int beg = roff[w], n = roff[w + 1] - beg;
    float ad = ad_[(long)w * 8 + h];
    float den = 0.f, acc0 = 0.f, acc1 = 0.f;
    int cm = n > 0 ? n - 1 : 0;
    for (int i = 0; i < n; i += 4) {
        int s[4];
        #pragma unroll
        for (int u = 0; u < 4; u++) s[u] = csrc[beg + min(i + u, cm)];
        float av[4]; bf162 xv[4];
        #pragma unroll
        for (int u = 0; u < 4; u++) {
            av[u] = as_[(long)s[u] * 8 + h];
            xv[u] = *(const bf162*)(xh + (long)s[u] * HID + lane * 2);
        }
        #pragma unroll
        for (int u = 0; u < 4; u++) {
            float a = av[u] + ad;
            a = a >= 0.f ? a : 0.2f * a;
            float wt = __expf(fminf(a, 60.f));
            wt = (i + u < n) ? wt : 0.f;
            den += wt;
            acc0 = fmaf(__bfloat162float(xv[u].x), wt, acc0);
            acc1 = fmaf(__bfloat162float(xv[u].y), wt, acc1);
        }
    }
    float inv = 1.f / (den + 1e-16f);
    out[(long)w * HID + lane * 2]     = fmaxf(acc0 * inv, 0.f);
    out[(long)w * HID + lane * 2 + 1] = fmaxf(acc1 * inv, 0.f);
}

__global__ void combine_kernel(const float* __restrict__ a0, const float* __restrict__ a1,
                               const float* __restrict__ score, float* __restrict__ out, int n)
{
    int i = blockIdx.x * blockDim.x + threadIdx.x;
    if (i >= n) return;
    float s0 = score[0] * (1.f / N_PAPER);
    float s1 = score[1] * (1.f / N_PAPER);
    float m = fmaxf(s0, s1);
    float e0 = __expf(s0 - m), e1 = __expf(s1 - m);
    float inv = 1.f / (e0 + e1);
    out[i] = a0[i] * (e0 * inv) + a1[i] * (e1 * inv);
}

// final linear fused with semantic combine of the last layer
__global__ __launch_bounds__(256) void final_lin_fused_kernel(
    const float* __restrict__ a0, const float* __restrict__ a1,
    const float* __restrict__ score,
    const float* __restrict__ W, const float* __restrict__ B, float* __restrict__ out)
{
    __shared__ float Ws[HID * NCLS];
    int tid = threadIdx.x;
    for (int i = tid; i < HID * NCLS; i += 256) Ws[i] = W[i];
    __syncthreads();
    float s0 = score[0] * (1.f / N_PAPER);
    float s1 = score[1] * (1.f / N_PAPER);
    float m = fmaxf(s0, s1);
    float e0 = __expf(s0 - m), e1 = __expf(s1 - m);
    float inv = 1.f / (e0 + e1);
    float w0 = e0 * inv, w1 = e1 * inv;
    int i = blockIdx.x * 256 + tid;
    if (i >= N_PAPER * NCLS) return;
    int n = i >> 4, c = i & 15;
    float acc = B[c];
    const float* x0 = a0 + (long)n * HID;
    const float* x1 = a1 + (long)n * HID;
    #pragma unroll 16
    for (int k = 0; k < HID; k++)
        acc = fmaf(fmaf(w0, x0[k], w1 * x1[k]), Ws[k * NCLS + c], acc);
    out[i] = acc;
}

extern "C" void kernel_launch(void* const* d_in, const int* in_sizes, int n_in,
                              void* d_out, int out_size, void* d_ws, size_t ws_size,
                              hipStream_t stream)
{
    const float* x_author = (const float*)d_in[0];
    const float* x_paper  = (const float*)d_in[1];
    const float* Wa       = (const float*)d_in[2];
    const float* proj_w   = (const float*)d_in[3];
    const float* proj_b   = (const float*)d_in[4];
    const float* att_src  = (const float*)d_in[5];
    const float* att_dst  = (const float*)d_in[6];
    const float* klin_w   = (const float*)d_in[7];
    const float* klin_b   = (const float*)d_in[8];
    const float* qv       = (const float*)d_in[9];
    const float* lin_w    = (const float*)d_in[10];
    const float* lin_b    = (const float*)d_in[11];
    const int*  ei_w      = (const int*)d_in[12];
    const int*  ei_wb     = (const int*)d_in[13];
    const int*  ei_c      = (const int*)d_in[14];
    float* out = (float*)d_out;
    (void)ws_size; (void)in_sizes; (void)n_in; (void)out_size;

    char* base = (char*)d_ws;
    size_t off = 0;
    auto alloc = [&](size_t bytes) {
        void* p = base + off;
        off = (off + bytes + 255) & ~(size_t)255;
        return p;
    };
    bf16*  xh_a  = (bf16*) alloc((size_t)N_AUTHOR * HID * 2);
    bf16*  xh_p  = (bf16*) alloc((size_t)N_PAPER  * HID * 2);
    float* a_e0s = (float*)alloc((size_t)N_AUTHOR * HEADS * 4);
    float* a_e0d = (float*)alloc((size_t)N_PAPER  * HEADS * 4);
    float* a_e1s = (float*)alloc((size_t)N_PAPER  * HEADS * 4);
    float* a_e1d = (float*)alloc((size_t)N_AUTHOR * HEADS * 4);
    float* a_e2s = (float*)alloc((size_t)N_PAPER  * HEADS * 4);
    float* a_e2d = (float*)alloc((size_t)N_PAPER  * HEADS * 4);
    float* buf_a  = (float*)alloc((size_t)N_AUTHOR * HID * 4);
    float* buf_p  = (float*)alloc((size_t)N_PAPER  * HID * 4);
    float* agg_p1 = (float*)alloc((size_t)N_PAPER  * HID * 4);
    float* score  = (float*)alloc(64);
    int* roff0 = (int*)alloc((size_t)(N_PAPER  + 1) * 4);
    int* roff1 = (int*)alloc((size_t)(N_AUTHOR + 1) * 4);
    int* roff2 = (int*)alloc((size_t)(N_PAPER  + 1) * 4);
    int* csrc0 = (int*)alloc((size_t)NEDGE * 4);
    int* csrc1 = (int*)alloc((size_t)NEDGE * 4);
    int* csrc2 = (int*)alloc((size_t)NEDGE * 4);
    int* cnt   = (int*)alloc((size_t)(2 * N_PAPER + N_AUTHOR) * 4);
    int* bsum  = (int*)alloc(3 * 256 * 4);

    const int GA = (N_AUTHOR + 63) / 64;   // 313
    const int GP = (N_PAPER  + 63) / 64;   // 625
    const int G3E = (3 * NEDGE + 255) / 256;
    const int NBMAX = (N_PAPER + 255) / 256;   // 157

    // ---- batched CSR build ----
    hipMemsetAsync(cnt, 0, (size_t)(2 * N_PAPER + N_AUTHOR) * 4, stream);
    hist3_kernel<<<G3E, 256, 0, stream>>>(ei_w + NEDGE, ei_wb + NEDGE, ei_c + NEDGE, cnt);
    scan_a3_kernel<<<dim3(NBMAX, 3), 256, 0, stream>>>(cnt, bsum);
    scan_b3_kernel<<<3, 256, 0, stream>>>(bsum, roff0, roff1, roff2);
    scan_c3_kernel<<<dim3(NBMAX, 3), 256, 0, stream>>>(cnt, bsum, roff0, roff1, roff2);
    hipMemsetAsync(cnt, 0, (size_t)(2 * N_PAPER + N_AUTHOR) * 4, stream);
    fill3_kernel<<<G3E, 256, 0, stream>>>(
        ei_w, ei_w + NEDGE, ei_wb, ei_wb + NEDGE, ei_c, ei_c + NEDGE,
        roff0, roff1, roff2, cnt, csrc0, csrc1, csrc2);

    // author input projection 64 -> 128 via MFMA
    mfma_gemm_kernel<float, 64><<<GA, 256, 0, stream>>>(
        x_author, Wa, nullptr, buf_a, N_AUTHOR);

    for (int l = 0; l < 2; l++) {
        const bool last = (l == 1);
        const float* cur_a = buf_a;
        const float* cur_p = (l == 0) ? x_paper : buf_p;
        const float* pw_a = proj_w + (size_t)(l*2 + 0) * HID * HID;
        const float* pw_p = proj_w + (size_t)(l*2 + 1) * HID * HID;
        const float* pb_a = proj_b + (size_t)(l*2 + 0) * HID;
        const float* pb_p = proj_b + (size_t)(l*2 + 1) * HID;

        // both projections in one launch
        mfma_gemm_pair_kernel<bf16, 128, 0><<<GA + GP, 256, 0, stream>>>(
            cur_a, pw_a, pb_a, xh_a, nullptr, N_AUTHOR, GA,
            cur_p, pw_p, pb_p, xh_p, nullptr, N_PAPER, nullptr);

        hipMemsetAsync(score, 0, 64, stream);

        const float* as0 = att_src + (size_t)(l*3 + 0) * HID;
        const float* ad0 = att_dst + (size_t)(l*3 + 0) * HID;
        const float* as1 = att_src + (size_t)(l*3 + 1) * HID;
        const float* ad1 = att_dst + (size_t)(l*3 + 1) * HID;
        const float* as2 = att_src + (size_t)(l*3 + 2) * HID;
        const float* ad2 = att_dst + (size_t)(l*3 + 2) * HID;

        node_att_multi_kernel<<<(N_AUTHOR*HEADS + 255)/256, 256, 0, stream>>>(
            xh_a, as0, last ? nullptr : ad1, nullptr, nullptr,
            a_e0s, a_e1d, nullptr, nullptr, N_AUTHOR);
        node_att_multi_kernel<<<(N_PAPER*HEADS + 255)/256, 256, 0, stream>>>(
            xh_p, ad0, last ? nullptr : as1, as2, ad2,
            a_e0d, a_e1s, a_e2s, a_e2d, N_PAPER);

        paper_gather2_kernel<<<(N_PAPER + 3)/4, 256, 0, stream>>>(
            roff0, csrc0, a_e0s, a_e0d, xh_a,
            roff2, csrc2, a_e2s, a_e2d, xh_p,
            buf_p, agg_p1);
        if (!last)
            edge_gather_kernel<<<(N_AUTHOR + 3)/4, 256, 0, stream>>>(
                roff1, csrc1, a_e1s, a_e1d, xh_p, buf_a, N_AUTHOR);

        // both klin score GEMMs in one launch (fast tanh epilogue)
        const float* kw = klin_w + (size_t)l * HID * HID;
        const float* kb = klin_b + (size_t)l * HID;
        const float* qq = qv     + (size_t)l * HID;
        mfma_gemm_pair_kernel<float, 128, 1><<<2 * GP, 256, 0, stream>>>(
            buf_p, kw, kb, (float*)nullptr, score + 0, N_PAPER, GP,
            agg_p1, kw, kb, (float*)nullptr, score + 1, N_PAPER, qq);

        if (!last)
            combine_kernel<<<(N_PAPER*HID + 255)/256, 256, 0, stream>>>(
                buf_p, agg_p1, score, buf_p, N_PAPER*HID);
    }

    // last layer: combine fused into the classifier
    final_lin_fused_kernel<<<(N_PAPER*NCLS + 255)/256, 256, 0, stream>>>(
        buf_p, agg_p1, score, lin_w, lin_b, out);
}

// Round 9
// 502.215 us; speedup vs baseline: 6.1168x; 1.0940x over previous
//
#include <hip/hip_runtime.h>
#include <hip/hip_bf16.h>

typedef __hip_bfloat16 bf16;
typedef __hip_bfloat162 bf162;

#define N_AUTHOR 20000
#define N_PAPER  40000
#define NEDGE    400000
#define HID      128
#define HEADS    8
#define DIMH     16
#define NCLS     16

typedef short short4v __attribute__((ext_vector_type(4)));
typedef short short8v __attribute__((ext_vector_type(8)));
typedef float f32x4   __attribute__((ext_vector_type(4)));

__device__ __forceinline__ void stf(float* p, float v){ *p = v; }
__device__ __forceinline__ void stf(bf16* p, float v){ *p = __float2bfloat16(v); }

// float -> bf16 bits (round-to-nearest-even; finite inputs only)
__device__ __forceinline__ short f2bs(float v){
    unsigned u = __float_as_uint(v);
    unsigned r = (u + 0x7FFFu + ((u >> 16) & 1u)) >> 16;
    return (short)r;
}

// fast tanh via exp; |err| ~1e-7, clamp avoids inf/inf
__device__ __forceinline__ float fast_tanh(float x){
    x = fminf(fmaxf(x, -15.f), 15.f);
    float e = __expf(2.f * x);
    return (e - 1.f) / (e + 1.f);
}

// ---------------------------------------------------------------------------
// MFMA GEMM (single): C[M,128] = A[M,KDIM] @ W[KDIM,128] + bias
// ---------------------------------------------------------------------------
template<typename TC, int KDIM>
__global__ __launch_bounds__(256) void mfma_gemm_kernel(
    const float* __restrict__ A, const float* __restrict__ W, const float* __restrict__ Bb,
    TC* __restrict__ C, int M)
{
    const int STR = KDIM + 8;
    __shared__ short Wt[128 * STR];
    const int tid = threadIdx.x;
    #pragma unroll
    for (int p = tid; p < 128 * (KDIM / 4); p += 256) {
        int c  = p & 127;
        int k0 = (p >> 7) * 4;
        short4v s;
        #pragma unroll
        for (int j = 0; j < 4; j++) s[j] = f2bs(W[(k0 + j) * HID + c]);
        *(short4v*)&Wt[c * STR + k0] = s;
    }
    __syncthreads();

    const int lane = tid & 63;
    const int wv   = tid >> 6;
    const int lr   = lane & 15;
    const int quad = lane >> 4;
    const int row0 = blockIdx.x * 64 + wv * 16;
    const int arow_i = row0 + lr;
    const bool rowok = arow_i < M;
    const float* arow = A + (long)arow_i * KDIM;

    short8v afrag[KDIM / 32];
    #pragma unroll
    for (int kc = 0; kc < KDIM / 32; kc++) {
        short8v f;
        #pragma unroll
        for (int j = 0; j < 8; j++)
            f[j] = f2bs(rowok ? arow[kc * 32 + quad * 8 + j] : 0.f);
        afrag[kc] = f;
    }

    f32x4 acc[8];
    #pragma unroll
    for (int ct = 0; ct < 8; ct++) acc[ct] = (f32x4){0.f, 0.f, 0.f, 0.f};
    #pragma unroll
    for (int ct = 0; ct < 8; ct++)
        #pragma unroll
        for (int kc = 0; kc < KDIM / 32; kc++) {
            short8v bfrag = *(const short8v*)&Wt[(ct * 16 + lr) * STR + kc * 32 + quad * 8];
            acc[ct] = __builtin_amdgcn_mfma_f32_16x16x32_bf16(afrag[kc], bfrag, acc[ct], 0, 0, 0);
        }

    #pragma unroll
    for (int ct = 0; ct < 8; ct++) {
        float bc = Bb ? Bb[ct * 16 + lr] : 0.f;
        #pragma unroll
        for (int r = 0; r < 4; r++) {
            int orow = row0 + quad * 4 + r;
            if (orow < M)
                stf(&C[(long)orow * HID + ct * 16 + lr], acc[ct][r] + bc);
        }
    }
}

// ---------------------------------------------------------------------------
// Paired MFMA GEMM: two GEMMs in one launch; blocks [0,NB0) -> set 0.
// EPI==0: store C. EPI==1: tanh epilogue, dot q, block-reduce, atomicAdd score.
// ---------------------------------------------------------------------------
template<typename TC, int KDIM, int EPI>
__global__ __launch_bounds__(256) void mfma_gemm_pair_kernel(
    const float* __restrict__ A0, const float* __restrict__ W0, const float* __restrict__ Bb0,
    TC* __restrict__ C0, float* __restrict__ score0, int M0, int NB0,
    const float* __restrict__ A1, const float* __restrict__ W1, const float* __restrict__ Bb1,
    TC* __restrict__ C1, float* __restrict__ score1, int M1,
    const float* __restrict__ qv)
{
    const int STR = KDIM + 8;
    __shared__ short Wt[128 * STR];
    const int tid = threadIdx.x;
    const int bx = blockIdx.x;
    const bool second = bx >= NB0;
    const float* A = second ? A1 : A0;
    const float* W = second ? W1 : W0;
    const float* Bb = second ? Bb1 : Bb0;
    TC* C = second ? C1 : C0;
    float* score = second ? score1 : score0;
    const int M = second ? M1 : M0;
    const int brow = second ? bx - NB0 : bx;

    #pragma unroll
    for (int p = tid; p < 128 * (KDIM / 4); p += 256) {
        int c  = p & 127;
        int k0 = (p >> 7) * 4;
        short4v s;
        #pragma unroll
        for (int j = 0; j < 4; j++) s[j] = f2bs(W[(k0 + j) * HID + c]);
        *(short4v*)&Wt[c * STR + k0] = s;
    }
    __syncthreads();

    const int lane = tid & 63;
    const int wv   = tid >> 6;
    const int lr   = lane & 15;
    const int quad = lane >> 4;
    const int row0 = brow * 64 + wv * 16;
    const int arow_i = row0 + lr;
    const bool rowok = arow_i < M;
    const float* arow = A + (long)arow_i * KDIM;

    short8v afrag[KDIM / 32];
    #pragma unroll
    for (int kc = 0; kc < KDIM / 32; kc++) {
        short8v f;
        #pragma unroll
        for (int j = 0; j < 8; j++)
            f[j] = f2bs(rowok ? arow[kc * 32 + quad * 8 + j] : 0.f);
        afrag[kc] = f;
    }

    f32x4 acc[8];
    #pragma unroll
    for (int ct = 0; ct < 8; ct++) acc[ct] = (f32x4){0.f, 0.f, 0.f, 0.f};
    #pragma unroll
    for (int ct = 0; ct < 8; ct++)
        #pragma unroll
        for (int kc = 0; kc < KDIM / 32; kc++) {
            short8v bfrag = *(const short8v*)&Wt[(ct * 16 + lr) * STR + kc * 32 + quad * 8];
            acc[ct] = __builtin_amdgcn_mfma_f32_16x16x32_bf16(afrag[kc], bfrag, acc[ct], 0, 0, 0);
        }

    if (EPI == 0) {
        #pragma unroll
        for (int ct = 0; ct < 8; ct++) {
            float bc = Bb ? Bb[ct * 16 + lr] : 0.f;
            #pragma unroll
            for (int r = 0; r < 4; r++) {
                int orow = row0 + quad * 4 + r;
                if (orow < M)
                    stf(&C[(long)orow * HID + ct * 16 + lr], acc[ct][r] + bc);
            }
        }
    } else {
        float part = 0.f;
        #pragma unroll
        for (int ct = 0; ct < 8; ct++) {
            float bc = Bb ? Bb[ct * 16 + lr] : 0.f;
            float qc = qv[ct * 16 + lr];
            #pragma unroll
            for (int r = 0; r < 4; r++) {
                int orow = row0 + quad * 4 + r;
                if (orow < M) part += qc * fast_tanh(acc[ct][r] + bc);
            }
        }
        __shared__ float red[256];
        red[tid] = part;
        __syncthreads();
        for (int s = 128; s > 0; s >>= 1) {
            if (tid < s) red[tid] += red[tid + s];
            __syncthreads();
        }
        if (tid == 0) atomicAdd(score, red[0]);
    }
}

// multi-output node attention dots
__global__ void node_att_multi_kernel(const bf16* __restrict__ xh,
    const float* __restrict__ A0, const float* __restrict__ A1,
    const float* __restrict__ A2, const float* __restrict__ A3,
    float* __restrict__ O0, float* __restrict__ O1,
    float* __restrict__ O2, float* __restrict__ O3, int N)
{
    int i = blockIdx.x * blockDim.x + threadIdx.x;
    if (i >= N * HEADS) return;
    int n = i >> 3, h = i & 7;
    const bf16* row = xh + (long)n * HID + h * DIMH;
    float x[DIMH];
    #pragma unroll
    for (int d = 0; d < DIMH; d++) x[d] = __bfloat162float(row[d]);
    if (A0) { float s = 0.f;
        #pragma unroll
        for (int d = 0; d < DIMH; d++) s += x[d] * A0[h*DIMH + d];
        O0[i] = s; }
    if (A1) { float s = 0.f;
        #pragma unroll
        for (int d = 0; d < DIMH; d++) s += x[d] * A1[h*DIMH + d];
        O1[i] = s; }
    if (A2) { float s = 0.f;
        #pragma unroll
        for (int d = 0; d < DIMH; d++) s += x[d] * A2[h*DIMH + d];
        O2[i] = s; }
    if (A3) { float s = 0.f;
        #pragma unroll
        for (int d = 0; d < DIMH; d++) s += x[d] * A3[h*DIMH + d];
        O3[i] = s; }
}

// ---------------- batched CSR build ----------------
#define CNT_OFF1 N_PAPER
#define CNT_OFF2 (N_PAPER + N_AUTHOR)

// histogram + per-edge rank (atomicAdd return value = rank within dest bucket)
__global__ void hist3_kernel(const int* __restrict__ d0, const int* __restrict__ d1,
                             const int* __restrict__ d2, int* __restrict__ cnt,
                             int* __restrict__ rank)
{
    int i = blockIdx.x * blockDim.x + threadIdx.x;
    if (i < NEDGE)               rank[i] = atomicAdd(&cnt[d0[i]], 1);
    else if (i < 2*NEDGE)        rank[i] = atomicAdd(&cnt[CNT_OFF1 + d1[i - NEDGE]], 1);
    else if (i < 3*NEDGE)        rank[i] = atomicAdd(&cnt[CNT_OFF2 + d2[i - 2*NEDGE]], 1);
}

__device__ __forceinline__ int job_nd(int j){ return j == 1 ? N_AUTHOR : N_PAPER; }
__device__ __forceinline__ int job_off(int j){ return j == 0 ? 0 : (j == 1 ? CNT_OFF1 : CNT_OFF2); }

__global__ __launch_bounds__(256) void scan_a3_kernel(const int* __restrict__ cnt,
                                                      int* __restrict__ bsum)
{
    int j = blockIdx.y;
    int nd = job_nd(j), off = job_off(j);
    __shared__ int s[256];
    int tid = threadIdx.x;
    int i = blockIdx.x * 256 + tid;
    s[tid] = (i < nd) ? cnt[off + i] : 0;
    __syncthreads();
    for (int st = 128; st > 0; st >>= 1) {
        if (tid < st) s[tid] += s[tid + st];
        __syncthreads();
    }
    if (tid == 0) bsum[j * 256 + blockIdx.x] = s[0];
}

__global__ __launch_bounds__(256) void scan_b3_kernel(int* __restrict__ bsum,
    int* __restrict__ roff0, int* __restrict__ roff1, int* __restrict__ roff2)
{
    int j = blockIdx.x;
    int nd = job_nd(j);
    int nb = (nd + 255) / 256;
    int* roff = j == 0 ? roff0 : (j == 1 ? roff1 : roff2);
    __shared__ int s[256];
    int tid = threadIdx.x;
    int v = (tid < nb) ? bsum[j * 256 + tid] : 0;
    s[tid] = v;
    __syncthreads();
    for (int off = 1; off < 256; off <<= 1) {
        int t = (tid >= off) ? s[tid - off] : 0;
        __syncthreads();
        s[tid] += t;
        __syncthreads();
    }
    if (tid < nb) bsum[j * 256 + tid] = s[tid] - v;
    if (tid == 255) roff[nd] = s[255];
}

__global__ __launch_bounds__(256) void scan_c3_kernel(const int* __restrict__ cnt,
    const int* __restrict__ bsum,
    int* __restrict__ roff0, int* __restrict__ roff1, int* __restrict__ roff2)
{
    int j = blockIdx.y;
    int nd = job_nd(j), off = job_off(j);
    int* roff = j == 0 ? roff0 : (j == 1 ? roff1 : roff2);
    __shared__ int s[256];
    int tid = threadIdx.x;
    int i = blockIdx.x * 256 + tid;
    int v = (i < nd) ? cnt[off + i] : 0;
    s[tid] = v;
    __syncthreads();
    for (int o = 1; o < 256; o <<= 1) {
        int t = (tid >= o) ? s[tid - o] : 0;
        __syncthreads();
        s[tid] += t;
        __syncthreads();
    }
    if (i < nd) roff[i] = bsum[j * 256 + blockIdx.x] + s[tid] - v;
}

// fill via precomputed rank: no atomics, ushort payload (all indices < 65536)
__global__ void fill3_kernel(
    const int* __restrict__ s0, const int* __restrict__ d0,
    const int* __restrict__ s1, const int* __restrict__ d1,
    const int* __restrict__ s2, const int* __restrict__ d2,
    const int* __restrict__ roff0, const int* __restrict__ roff1, const int* __restrict__ roff2,
    const int* __restrict__ rank,
    unsigned short* __restrict__ c0, unsigned short* __restrict__ c1, unsigned short* __restrict__ c2)
{
    int i = blockIdx.x * blockDim.x + threadIdx.x;
    if (i < NEDGE) {
        int d = d0[i];
        c0[roff0[d] + rank[i]] = (unsigned short)s0[i];
    } else if (i < 2*NEDGE) {
        int e = i - NEDGE, d = d1[e];
        c1[roff1[d] + rank[i]] = (unsigned short)s1[e];
    } else if (i < 3*NEDGE) {
        int e = i - 2*NEDGE, d = d2[e];
        c2[roff2[d] + rank[i]] = (unsigned short)s2[e];
    }
}

// ---------------------------------------------------------------------------
// Fused paper gather, 8-deep load batching per chain (16 rows in flight).
// ---------------------------------------------------------------------------
__global__ __launch_bounds__(256) void paper_gather2_kernel(
    const int* __restrict__ roff0, const unsigned short* __restrict__ csrc0,
    const float* __restrict__ as0, const float* __restrict__ ad0,
    const bf16* __restrict__ xha,
    const int* __restrict__ roff2, const unsigned short* __restrict__ csrc2,
    const float* __restrict__ as2, const float* __restrict__ ad2,
    const bf16* __restrict__ xhp,
    float* __restrict__ out0, float* __restrict__ out2)
{
    int w = blockIdx.x * 4 + (threadIdx.x >> 6);
    int lane = threadIdx.x & 63;
    if (w >= N_PAPER) return;
    int h = lane >> 3;
    int b0 = roff0[w], n0 = roff0[w + 1] - b0;
    int b2 = roff2[w], n2 = roff2[w + 1] - b2;
    float ad0v = ad0[(long)w * 8 + h];
    float ad2v = ad2[(long)w * 8 + h];
    float den0 = 0.f, p00 = 0.f, p01 = 0.f;
    float den2 = 0.f, p20 = 0.f, p21 = 0.f;
    int nmax = n0 > n2 ? n0 : n2;
    int c0m = n0 > 0 ? n0 - 1 : 0;
    int c2m = n2 > 0 ? n2 - 1 : 0;
    for (int i = 0; i < nmax; i += 8) {
        int sA[8], sB[8];
        #pragma unroll
        for (int u = 0; u < 8; u++) {
            sA[u] = csrc0[b0 + min(i + u, c0m)];
            sB[u] = csrc2[b2 + min(i + u, c2m)];
        }
        float aA[8], aB[8];
        bf162 xA[8], xB[8];
        #pragma unroll
        for (int u = 0; u < 8; u++) {
            aA[u] = as0[(long)sA[u] * 8 + h];
            xA[u] = *(const bf162*)(xha + (long)sA[u] * HID + lane * 2);
            aB[u] = as2[(long)sB[u] * 8 + h];
            xB[u] = *(const bf162*)(xhp + (long)sB[u] * HID + lane * 2);
        }
        #pragma unroll
        for (int u = 0; u < 8; u++) {
            float a = aA[u] + ad0v;
            a = a >= 0.f ? a : 0.2f * a;
            float wt = __expf(fminf(a, 60.f));
            wt = (i + u < n0) ? wt : 0.f;
            den0 += wt;
            p00 = fmaf(__bfloat162float(xA[u].x), wt, p00);
            p01 = fmaf(__bfloat162float(xA[u].y), wt, p01);
            a = aB[u] + ad2v;
            a = a >= 0.f ? a : 0.2f * a;
            wt = __expf(fminf(a, 60.f));
            wt = (i + u < n2) ? wt : 0.f;
            den2 += wt;
            p20 = fmaf(__bfloat162float(xB[u].x), wt, p20);
            p21 = fmaf(__bfloat162float(xB[u].y), wt, p21);
        }
    }
    float inv0 = 1.f / (den0 + 1e-16f);
    float inv2 = 1.f / (den2 + 1e-16f);
    out0[(long)w * HID + lane * 2]     = fmaxf(p00 * inv0, 0.f);
    out0[(long)w * HID + lane * 2 + 1] = fmaxf(p01 * inv0, 0.f);
    out2[(long)w * HID + lane * 2]     = fmaxf(p20 * inv2, 0.f);
    out2[(long)w * HID + lane * 2 + 1] = fmaxf(p21 * inv2, 0.f);
}

// single gather (author dest, layer 0 only), 8-deep batching
__global__ __launch_bounds__(256) void edge_gather_kernel(
    const int* __restrict__ roff, const unsigned short* __restrict__ csrc,
    const float* __restrict__ as_, const float* __restrict__ ad_,
    const bf16* __restrict__ xh, float* __restrict__ out, int Ndst)
{
    int w = blockIdx.x * 4 + (threadIdx.x >> 6);
    int lane = threadIdx.x & 63;
    if (w >= Ndst) return;
    int h = lane >> 3;
    int beg = roff[w], n = roff[w + 1] - beg;
    float ad = ad_[(long)w * 8 + h];
    float den = 0.f, acc0 = 0.f, acc1 = 0.f;
    int cm = n > 0 ? n - 1 : 0;
    for (int i = 0; i < n; i += 8) {
        int s[8];
        #pragma unroll
        for (int u = 0; u < 8; u++) s[u] = csrc[beg + min(i + u, cm)];
        float av[8]; bf162 xv[8];
        #pragma unroll
        for (int u = 0; u < 8; u++) {
            av[u] = as_[(long)s[u] * 8 + h];
            xv[u] = *(const bf162*)(xh + (long)s[u] * HID + lane * 2);
        }
        #pragma unroll
        for (int u = 0; u < 8; u++) {
            float a = av[u] + ad;
            a = a >= 0.f ? a : 0.2f * a;
            float wt = __expf(fminf(a, 60.f));
            wt = (i + u < n) ? wt : 0.f;
            den += wt;
            acc0 = fmaf(__bfloat162float(xv[u].x), wt, acc0);
            acc1 = fmaf(__bfloat162float(xv[u].y), wt, acc1);
        }
    }
    float inv = 1.f / (den + 1e-16f);
    out[(long)w * HID + lane * 2]     = fmaxf(acc0 * inv, 0.f);
    out[(long)w * HID + lane * 2 + 1] = fmaxf(acc1 * inv, 0.f);
}

__global__ void combine_kernel(const float* __restrict__ a0, const float* __restrict__ a1,
                               const float* __restrict__ score, float* __restrict__ out, int n)
{
    int i = blockIdx.x * blockDim.x + threadIdx.x;
    if (i >= n) return;
    float s0 = score[0] * (1.f / N_PAPER);
    float s1 = score[1] * (1.f / N_PAPER);
    float m = fmaxf(s0, s1);
    float e0 = __expf(s0 - m), e1 = __expf(s1 - m);
    float inv = 1.f / (e0 + e1);
    out[i] = a0[i] * (e0 * inv) + a1[i] * (e1 * inv);
}

// final linear fused with semantic combine of the last layer
__global__ __launch_bounds__(256) void final_lin_fused_kernel(
    const float* __restrict__ a0, const float* __restrict__ a1,
    const float* __restrict__ score,
    const float* __restrict__ W, const float* __restrict__ B, float* __restrict__ out)
{
    __shared__ float Ws[HID * NCLS];
    int tid = threadIdx.x;
    for (int i = tid; i < HID * NCLS; i += 256) Ws[i] = W[i];
    __syncthreads();
    float s0 = score[0] * (1.f / N_PAPER);
    float s1 = score[1] * (1.f / N_PAPER);
    float m = fmaxf(s0, s1);
    float e0 = __expf(s0 - m), e1 = __expf(s1 - m);
    float inv = 1.f / (e0 + e1);
    float w0 = e0 * inv, w1 = e1 * inv;
    int i = blockIdx.x * 256 + tid;
    if (i >= N_PAPER * NCLS) return;
    int n = i >> 4, c = i & 15;
    float acc = B[c];
    const float* x0 = a0 + (long)n * HID;
    const float* x1 = a1 + (long)n * HID;
    #pragma unroll 16
    for (int k = 0; k < HID; k++)
        acc = fmaf(fmaf(w0, x0[k], w1 * x1[k]), Ws[k * NCLS + c], acc);
    out[i] = acc;
}

extern "C" void kernel_launch(void* const* d_in, const int* in_sizes, int n_in,
                              void* d_out, int out_size, void* d_ws, size_t ws_size,
                              hipStream_t stream)
{
    const float* x_author = (const float*)d_in[0];
    const float* x_paper  = (const float*)d_in[1];
    const float* Wa       = (const float*)d_in[2];
    const float* proj_w   = (const float*)d_in[3];
    const float* proj_b   = (const float*)d_in[4];
    const float* att_src  = (const float*)d_in[5];
    const float* att_dst  = (const float*)d_in[6];
    const float* klin_w   = (const float*)d_in[7];
    const float* klin_b   = (const float*)d_in[8];
    const float* qv       = (const float*)d_in[9];
    const float* lin_w    = (const float*)d_in[10];
    const float* lin_b    = (const float*)d_in[11];
    const int*  ei_w      = (const int*)d_in[12];
    const int*  ei_wb     = (const int*)d_in[13];
    const int*  ei_c      = (const int*)d_in[14];
    float* out = (float*)d_out;
    (void)ws_size; (void)in_sizes; (void)n_in; (void)out_size;

    char* base = (char*)d_ws;
    size_t off = 0;
    auto alloc = [&](size_t bytes) {
        void* p = base + off;
        off = (off + bytes + 255) & ~(size_t)255;
        return p;
    };
    bf16*  xh_a  = (bf16*) alloc((size_t)N_AUTHOR * HID * 2);
    bf16*  xh_p  = (bf16*) alloc((size_t)N_PAPER  * HID * 2);
    float* a_e0s = (float*)alloc((size_t)N_AUTHOR * HEADS * 4);
    float* a_e0d = (float*)alloc((size_t)N_PAPER  * HEADS * 4);
    float* a_e1s = (float*)alloc((size_t)N_PAPER  * HEADS * 4);
    float* a_e1d = (float*)alloc((size_t)N_AUTHOR * HEADS * 4);
    float* a_e2s = (float*)alloc((size_t)N_PAPER  * HEADS * 4);
    float* a_e2d = (float*)alloc((size_t)N_PAPER  * HEADS * 4);
    float* buf_a  = (float*)alloc((size_t)N_AUTHOR * HID * 4);
    float* buf_p  = (float*)alloc((size_t)N_PAPER  * HID * 4);
    float* agg_p1 = (float*)alloc((size_t)N_PAPER  * HID * 4);
    float* score  = (float*)alloc(64);
    int* roff0 = (int*)alloc((size_t)(N_PAPER  + 1) * 4);
    int* roff1 = (int*)alloc((size_t)(N_AUTHOR + 1) * 4);
    int* roff2 = (int*)alloc((size_t)(N_PAPER  + 1) * 4);
    unsigned short* csrc0 = (unsigned short*)alloc((size_t)NEDGE * 2 + 64);
    unsigned short* csrc1 = (unsigned short*)alloc((size_t)NEDGE * 2 + 64);
    unsigned short* csrc2 = (unsigned short*)alloc((size_t)NEDGE * 2 + 64);
    int* cnt   = (int*)alloc((size_t)(2 * N_PAPER + N_AUTHOR) * 4);
    int* rank  = (int*)alloc((size_t)(3 * NEDGE) * 4);
    int* bsum  = (int*)alloc(3 * 256 * 4);

    const int GA = (N_AUTHOR + 63) / 64;   // 313
    const int GP = (N_PAPER  + 63) / 64;   // 625
    const int G3E = (3 * NEDGE + 255) / 256;
    const int NBMAX = (N_PAPER + 255) / 256;   // 157

    // ---- batched CSR build (rank captured in hist; no-atomic fill) ----
    hipMemsetAsync(cnt, 0, (size_t)(2 * N_PAPER + N_AUTHOR) * 4, stream);
    hist3_kernel<<<G3E, 256, 0, stream>>>(ei_w + NEDGE, ei_wb + NEDGE, ei_c + NEDGE, cnt, rank);
    scan_a3_kernel<<<dim3(NBMAX, 3), 256, 0, stream>>>(cnt, bsum);
    scan_b3_kernel<<<3, 256, 0, stream>>>(bsum, roff0, roff1, roff2);
    scan_c3_kernel<<<dim3(NBMAX, 3), 256, 0, stream>>>(cnt, bsum, roff0, roff1, roff2);
    fill3_kernel<<<G3E, 256, 0, stream>>>(
        ei_w, ei_w + NEDGE, ei_wb, ei_wb + NEDGE, ei_c, ei_c + NEDGE,
        roff0, roff1, roff2, rank, csrc0, csrc1, csrc2);

    // author input projection 64 -> 128 via MFMA
    mfma_gemm_kernel<float, 64><<<GA, 256, 0, stream>>>(
        x_author, Wa, nullptr, buf_a, N_AUTHOR);

    for (int l = 0; l < 2; l++) {
        const bool last = (l == 1);
        const float* cur_a = buf_a;
        const float* cur_p = (l == 0) ? x_paper : buf_p;
        const float* pw_a = proj_w + (size_t)(l*2 + 0) * HID * HID;
        const float* pw_p = proj_w + (size_t)(l*2 + 1) * HID * HID;
        const float* pb_a = proj_b + (size_t)(l*2 + 0) * HID;
        const float* pb_p = proj_b + (size_t)(l*2 + 1) * HID;

        mfma_gemm_pair_kernel<bf16, 128, 0><<<GA + GP, 256, 0, stream>>>(
            cur_a, pw_a, pb_a, xh_a, nullptr, N_AUTHOR, GA,
            cur_p, pw_p, pb_p, xh_p, nullptr, N_PAPER, nullptr);

        hipMemsetAsync(score, 0, 64, stream);

        const float* as0 = att_src + (size_t)(l*3 + 0) * HID;
        const float* ad0 = att_dst + (size_t)(l*3 + 0) * HID;
        const float* as1 = att_src + (size_t)(l*3 + 1) * HID;
        const float* ad1 = att_dst + (size_t)(l*3 + 1) * HID;
        const float* as2 = att_src + (size_t)(l*3 + 2) * HID;
        const float* ad2 = att_dst + (size_t)(l*3 + 2) * HID;

        node_att_multi_kernel<<<(N_AUTHOR*HEADS + 255)/256, 256, 0, stream>>>(
            xh_a, as0, last ? nullptr : ad1, nullptr, nullptr,
            a_e0s, a_e1d, nullptr, nullptr, N_AUTHOR);
        node_att_multi_kernel<<<(N_PAPER*HEADS + 255)/256, 256, 0, stream>>>(
            xh_p, ad0, last ? nullptr : as1, as2, ad2,
            a_e0d, a_e1s, a_e2s, a_e2d, N_PAPER);

        paper_gather2_kernel<<<(N_PAPER + 3)/4, 256, 0, stream>>>(
            roff0, csrc0, a_e0s, a_e0d, xh_a,
            roff2, csrc2, a_e2s, a_e2d, xh_p,
            buf_p, agg_p1);
        if (!last)
            edge_gather_kernel<<<(N_AUTHOR + 3)/4, 256, 0, stream>>>(
                roff1, csrc1, a_e1s, a_e1d, xh_p, buf_a, N_AUTHOR);

        const float* kw = klin_w + (size_t)l * HID * HID;
        const float* kb = klin_b + (size_t)l * HID;
        const float* qq = qv     + (size_t)l * HID;
        mfma_gemm_pair_kernel<float, 128, 1><<<2 * GP, 256, 0, stream>>>(
            buf_p, kw, kb, (float*)nullptr, score + 0, N_PAPER, GP,
            agg_p1, kw, kb, (float*)nullptr, score + 1, N_PAPER, qq);

        if (!last)
            combine_kernel<<<(N_PAPER*HID + 255)/256, 256, 0, stream>>>(
                buf_p, agg_p1, score, buf_p, N_PAPER*HID);
    }

    final_lin_fused_kernel<<<(N_PAPER*NCLS + 255)/256, 256, 0, stream>>>(
        buf_p, agg_p1, score, lin_w, lin_b, out);
}

// Round 11
// 480.721 us; speedup vs baseline: 6.3903x; 1.0447x over previous
//
#include <hip/hip_runtime.h>
#include <hip/hip_bf16.h>

typedef __hip_bfloat16 bf16;
typedef __hip_bfloat162 bf162;

#define N_AUTHOR 20000
#define N_PAPER  40000
#define NEDGE    400000
#define HID      128
#define HEADS    8
#define DIMH     16
#define NCLS     16

typedef short short4v __attribute__((ext_vector_type(4)));
typedef short short8v __attribute__((ext_vector_type(8)));
typedef float f32x4   __attribute__((ext_vector_type(4)));

__device__ __forceinline__ bf162 mk2(float a, float b){
    bf162 r; r.x = __float2bfloat16(a); r.y = __float2bfloat16(b); return r;
}

// fast tanh via exp; |err| ~1e-7
__device__ __forceinline__ float fast_tanh(float x){
    x = fminf(fmaxf(x, -15.f), 15.f);
    float e = __expf(2.f * x);
    return (e - 1.f) / (e + 1.f);
}

// ---------------------------------------------------------------------------
// LDS-free bf16 MFMA GEMM body: C[M,128] = A[M,KDIM] @ Wt^T + bias
// A bf16 row-major [M][KDIM]; Wt bf16 TRANSPOSED [128][KDIM] (row = out col).
// Wave computes 16 rows x 128 cols. A-frag: 1 x 16B load per kc.
// B-frag: 16B global loads from Wt (hot in L2; 64B sectors fully used).
// EPI==0: store bf16 C + bias. EPI==1: tanh, dot q, block-reduce, atomicAdd.
// ---------------------------------------------------------------------------
template<int KDIM, int EPI>
__device__ __forceinline__ void bgemm_body(
    const bf16* __restrict__ A, const bf16* __restrict__ Wt, const float* __restrict__ Bb,
    bf16* __restrict__ C, const float* __restrict__ qv, float* __restrict__ score,
    int M, int brow, float* red)
{
    const int tid  = threadIdx.x;
    const int lane = tid & 63;
    const int wv   = tid >> 6;
    const int lr   = lane & 15;
    const int quad = lane >> 4;
    const int row0 = brow * 64 + wv * 16;
    const int arow_i = row0 + lr;
    const bool rowok = arow_i < M;
    const bf16* arow = A + (long)arow_i * KDIM;

    short8v afrag[KDIM / 32];
    #pragma unroll
    for (int kc = 0; kc < KDIM / 32; kc++) {
        short8v f = {0,0,0,0,0,0,0,0};
        if (rowok) f = *(const short8v*)(arow + kc * 32 + quad * 8);
        afrag[kc] = f;
    }

    f32x4 acc[8];
    #pragma unroll
    for (int ct = 0; ct < 8; ct++) acc[ct] = (f32x4){0.f, 0.f, 0.f, 0.f};

    #pragma unroll
    for (int ct = 0; ct < 8; ct++) {
        const bf16* wrow = Wt + (long)(ct * 16 + lr) * KDIM + quad * 8;
        #pragma unroll
        for (int kc = 0; kc < KDIM / 32; kc++) {
            short8v bfrag = *(const short8v*)(wrow + kc * 32);
            acc[ct] = __builtin_amdgcn_mfma_f32_16x16x32_bf16(afrag[kc], bfrag, acc[ct], 0, 0, 0);
        }
    }

    // D mapping: row = row0 + quad*4 + r, col = ct*16 + lr
    if (EPI == 0) {
        #pragma unroll
        for (int ct = 0; ct < 8; ct++) {
            float bc = Bb ? Bb[ct * 16 + lr] : 0.f;
            #pragma unroll
            for (int r = 0; r < 4; r++) {
                int orow = row0 + quad * 4 + r;
                if (orow < M)
                    C[(long)orow * HID + ct * 16 + lr] = __float2bfloat16(acc[ct][r] + bc);
            }
        }
    } else {
        float part = 0.f;
        #pragma unroll
        for (int ct = 0; ct < 8; ct++) {
            float bc = Bb ? Bb[ct * 16 + lr] : 0.f;
            float qc = qv[ct * 16 + lr];
            #pragma unroll
            for (int r = 0; r < 4; r++) {
                int orow = row0 + quad * 4 + r;
                if (orow < M) part += qc * fast_tanh(acc[ct][r] + bc);
            }
        }
        red[tid] = part;
        __syncthreads();
        for (int s = 128; s > 0; s >>= 1) {
            if (tid < s) red[tid] += red[tid + s];
            __syncthreads();
        }
        if (tid == 0) atomicAdd(score, red[0]);
    }
}

template<int KDIM, int EPI>
__global__ __launch_bounds__(256) void bgemm_kernel(
    const bf16* __restrict__ A, const bf16* __restrict__ Wt, const float* __restrict__ Bb,
    bf16* __restrict__ C, const float* __restrict__ qv, float* __restrict__ score, int M)
{
    __shared__ float red[256];
    bgemm_body<KDIM, EPI>(A, Wt, Bb, C, qv, score, M, blockIdx.x, red);
}

template<int KDIM, int EPI>
__global__ __launch_bounds__(256) void bgemm_pair_kernel(
    const bf16* __restrict__ A0, const bf16* __restrict__ Wt0, const float* __restrict__ Bb0,
    bf16* __restrict__ C0, float* __restrict__ score0, int M0, int NB0,
    const bf16* __restrict__ A1, const bf16* __restrict__ Wt1, const float* __restrict__ Bb1,
    bf16* __restrict__ C1, float* __restrict__ score1, int M1,
    const float* __restrict__ qv)
{
    __shared__ float red[256];
    const int bx = blockIdx.x;
    if (bx < NB0)
        bgemm_body<KDIM, EPI>(A0, Wt0, Bb0, C0, qv, score0, M0, bx, red);
    else
        bgemm_body<KDIM, EPI>(A1, Wt1, Bb1, C1, qv, score1, M1, bx - NB0, red);
}

// ---------------------------------------------------------------------------
// one-time conversions: weights f32 -> bf16 transposed; activations f32 -> bf16
// ---------------------------------------------------------------------------
#define R_WA  (128 * 64)
#define R_PW  (4 * 128 * 128)
#define R_KW  (2 * 128 * 128)

__global__ void conv_weights_kernel(const float* __restrict__ Wa,
                                    const float* __restrict__ proj_w,
                                    const float* __restrict__ klin_w,
                                    bf16* __restrict__ wt_wa,
                                    bf16* __restrict__ wt_proj,
                                    bf16* __restrict__ wt_klin)
{
    int i = blockIdx.x * blockDim.x + threadIdx.x;
    if (i < R_WA) {
        int n = i >> 6, k = i & 63;                     // [128][64] <- Wa[64][128]
        wt_wa[i] = __float2bfloat16(Wa[k * 128 + n]);
    } else if (i < R_WA + R_PW) {
        int j = i - R_WA;
        int m = j >> 14, r = j & 16383;
        int n = r >> 7, k = r & 127;
        wt_proj[j] = __float2bfloat16(proj_w[m * 16384 + k * 128 + n]);
    } else if (i < R_WA + R_PW + R_KW) {
        int j = i - R_WA - R_PW;
        int m = j >> 14, r = j & 16383;
        int n = r >> 7, k = r & 127;
        wt_klin[j] = __float2bfloat16(klin_w[m * 16384 + k * 128 + n]);
    }
}

#define NXA (N_AUTHOR * 64)
#define NXP (N_PAPER * HID)

__global__ void conv_x_kernel(const float* __restrict__ xa_f, const float* __restrict__ xp_f,
                              bf16* __restrict__ xa, bf16* __restrict__ xp)
{
    int i4 = blockIdx.x * blockDim.x + threadIdx.x;
    int i = i4 * 4;
    if (i < NXA) {
        float4 v = *(const float4*)(xa_f + i);
        xa[i]   = __float2bfloat16(v.x); xa[i+1] = __float2bfloat16(v.y);
        xa[i+2] = __float2bfloat16(v.z); xa[i+3] = __float2bfloat16(v.w);
    } else if (i < NXA + NXP) {
        int j = i - NXA;
        float4 v = *(const float4*)(xp_f + j);
        xp[j]   = __float2bfloat16(v.x); xp[j+1] = __float2bfloat16(v.y);
        xp[j+2] = __float2bfloat16(v.z); xp[j+3] = __float2bfloat16(v.w);
    }
}

// multi-output node attention dots
__global__ void node_att_multi_kernel(const bf16* __restrict__ xh,
    const float* __restrict__ A0, const float* __restrict__ A1,
    const float* __restrict__ A2, const float* __restrict__ A3,
    float* __restrict__ O0, float* __restrict__ O1,
    float* __restrict__ O2, float* __restrict__ O3, int N)
{
    int i = blockIdx.x * blockDim.x + threadIdx.x;
    if (i >= N * HEADS) return;
    int n = i >> 3, h = i & 7;
    const bf16* row = xh + (long)n * HID + h * DIMH;
    float x[DIMH];
    #pragma unroll
    for (int d = 0; d < DIMH; d++) x[d] = __bfloat162float(row[d]);
    if (A0) { float s = 0.f;
        #pragma unroll
        for (int d = 0; d < DIMH; d++) s += x[d] * A0[h*DIMH + d];
        O0[i] = s; }
    if (A1) { float s = 0.f;
        #pragma unroll
        for (int d = 0; d < DIMH; d++) s += x[d] * A1[h*DIMH + d];
        O1[i] = s; }
    if (A2) { float s = 0.f;
        #pragma unroll
        for (int d = 0; d < DIMH; d++) s += x[d] * A2[h*DIMH + d];
        O2[i] = s; }
    if (A3) { float s = 0.f;
        #pragma unroll
        for (int d = 0; d < DIMH; d++) s += x[d] * A3[h*DIMH + d];
        O3[i] = s; }
}

// ---------------- batched CSR build ----------------
#define CNT_OFF1 N_PAPER
#define CNT_OFF2 (N_PAPER + N_AUTHOR)

__global__ void hist3_kernel(const int* __restrict__ d0, const int* __restrict__ d1,
                             const int* __restrict__ d2, int* __restrict__ cnt,
                             unsigned short* __restrict__ rank)
{
    int i = blockIdx.x * blockDim.x + threadIdx.x;
    if (i < NEDGE)               rank[i] = (unsigned short)atomicAdd(&cnt[d0[i]], 1);
    else if (i < 2*NEDGE)        rank[i] = (unsigned short)atomicAdd(&cnt[CNT_OFF1 + d1[i - NEDGE]], 1);
    else if (i < 3*NEDGE)        rank[i] = (unsigned short)atomicAdd(&cnt[CNT_OFF2 + d2[i - 2*NEDGE]], 1);
}

__device__ __forceinline__ int job_nd(int j){ return j == 1 ? N_AUTHOR : N_PAPER; }
__device__ __forceinline__ int job_off(int j){ return j == 0 ? 0 : (j == 1 ? CNT_OFF1 : CNT_OFF2); }

__global__ __launch_bounds__(256) void scan_a3_kernel(const int* __restrict__ cnt,
                                                      int* __restrict__ bsum)
{
    int j = blockIdx.y;
    int nd = job_nd(j), off = job_off(j);
    __shared__ int s[256];
    int tid = threadIdx.x;
    int i = blockIdx.x * 256 + tid;
    s[tid] = (i < nd) ? cnt[off + i] : 0;
    __syncthreads();
    for (int st = 128; st > 0; st >>= 1) {
        if (tid < st) s[tid] += s[tid + st];
        __syncthreads();
    }
    if (tid == 0) bsum[j * 256 + blockIdx.x] = s[0];
}

__global__ __launch_bounds__(256) void scan_b3_kernel(int* __restrict__ bsum,
    int* __restrict__ roff0, int* __restrict__ roff1, int* __restrict__ roff2)
{
    int j = blockIdx.x;
    int nd = job_nd(j);
    int nb = (nd + 255) / 256;
    int* roff = j == 0 ? roff0 : (j == 1 ? roff1 : roff2);
    __shared__ int s[256];
    int tid = threadIdx.x;
    int v = (tid < nb) ? bsum[j * 256 + tid] : 0;
    s[tid] = v;
    __syncthreads();
    for (int off = 1; off < 256; off <<= 1) {
        int t = (tid >= off) ? s[tid - off] : 0;
        __syncthreads();
        s[tid] += t;
        __syncthreads();
    }
    if (tid < nb) bsum[j * 256 + tid] = s[tid] - v;
    if (tid == 255) roff[nd] = s[255];
}

__global__ __launch_bounds__(256) void scan_c3_kernel(const int* __restrict__ cnt,
    const int* __restrict__ bsum,
    int* __restrict__ roff0, int* __restrict__ roff1, int* __restrict__ roff2)
{
    int j = blockIdx.y;
    int nd = job_nd(j), off = job_off(j);
    int* roff = j == 0 ? roff0 : (j == 1 ? roff1 : roff2);
    __shared__ int s[256];
    int tid = threadIdx.x;
    int i = blockIdx.x * 256 + tid;
    int v = (i < nd) ? cnt[off + i] : 0;
    s[tid] = v;
    __syncthreads();
    for (int o = 1; o < 256; o <<= 1) {
        int t = (tid >= o) ? s[tid - o] : 0;
        __syncthreads();
        s[tid] += t;
        __syncthreads();
    }
    if (i < nd) roff[i] = bsum[j * 256 + blockIdx.x] + s[tid] - v;
}

__global__ void fill3_kernel(
    const int* __restrict__ s0, const int* __restrict__ d0,
    const int* __restrict__ s1, const int* __restrict__ d1,
    const int* __restrict__ s2, const int* __restrict__ d2,
    const int* __restrict__ roff0, const int* __restrict__ roff1, const int* __restrict__ roff2,
    const unsigned short* __restrict__ rank,
    unsigned short* __restrict__ c0, unsigned short* __restrict__ c1, unsigned short* __restrict__ c2)
{
    int i = blockIdx.x * blockDim.x + threadIdx.x;
    if (i < NEDGE) {
        int d = d0[i];
        c0[roff0[d] + rank[i]] = (unsigned short)s0[i];
    } else if (i < 2*NEDGE) {
        int e = i - NEDGE, d = d1[e];
        c1[roff1[d] + rank[i]] = (unsigned short)s1[e];
    } else if (i < 3*NEDGE) {
        int e = i - 2*NEDGE, d = d2[e];
        c2[roff2[d] + rank[i]] = (unsigned short)s2[e];
    }
}

// ---------------------------------------------------------------------------
// Fused paper gather, 8-deep load batching; bf16 outputs.
// ---------------------------------------------------------------------------
__global__ __launch_bounds__(256) void paper_gather2_kernel(
    const int* __restrict__ roff0, const unsigned short* __restrict__ csrc0,
    const float* __restrict__ as0, const float* __restrict__ ad0,
    const bf16* __restrict__ xha,
    const int* __restrict__ roff2, const unsigned short* __restrict__ csrc2,
    const float* __restrict__ as2, const float* __restrict__ ad2,
    const bf16* __restrict__ xhp,
    bf16* __restrict__ out0, bf16* __restrict__ out2)
{
    int w = blockIdx.x * 4 + (threadIdx.x >> 6);
    int lane = threadIdx.x & 63;
    if (w >= N_PAPER) return;
    int h = lane >> 3;
    int b0 = roff0[w], n0 = roff0[w + 1] - b0;
    int b2 = roff2[w], n2 = roff2[w + 1] - b2;
    float ad0v = ad0[(long)w * 8 + h];
    float ad2v = ad2[(long)w * 8 + h];
    float den0 = 0.f, p00 = 0.f, p01 = 0.f;
    float den2 = 0.f, p20 = 0.f, p21 = 0.f;
    int nmax = n0 > n2 ? n0 : n2;
    int c0m = n0 > 0 ? n0 - 1 : 0;
    int c2m = n2 > 0 ? n2 - 1 : 0;
    for (int i = 0; i < nmax; i += 8) {
        int sA[8], sB[8];
        #pragma unroll
        for (int u = 0; u < 8; u++) {
            sA[u] = csrc0[b0 + min(i + u, c0m)];
            sB[u] = csrc2[b2 + min(i + u, c2m)];
        }
        float aA[8], aB[8];
        bf162 xA[8], xB[8];
        #pragma unroll
        for (int u = 0; u < 8; u++) {
            aA[u] = as0[(long)sA[u] * 8 + h];
            xA[u] = *(const bf162*)(xha + (long)sA[u] * HID + lane * 2);
            aB[u] = as2[(long)sB[u] * 8 + h];
            xB[u] = *(const bf162*)(xhp + (long)sB[u] * HID + lane * 2);
        }
        #pragma unroll
        for (int u = 0; u < 8; u++) {
            float a = aA[u] + ad0v;
            a = a >= 0.f ? a : 0.2f * a;
            float wt = __expf(fminf(a, 60.f));
            wt = (i + u < n0) ? wt : 0.f;
            den0 += wt;
            p00 = fmaf(__bfloat162float(xA[u].x), wt, p00);
            p01 = fmaf(__bfloat162float(xA[u].y), wt, p01);
            a = aB[u] + ad2v;
            a = a >= 0.f ? a : 0.2f * a;
            wt = __expf(fminf(a, 60.f));
            wt = (i + u < n2) ? wt : 0.f;
            den2 += wt;
            p20 = fmaf(__bfloat162float(xB[u].x), wt, p20);
            p21 = fmaf(__bfloat162float(xB[u].y), wt, p21);
        }
    }
    float inv0 = 1.f / (den0 + 1e-16f);
    float inv2 = 1.f / (den2 + 1e-16f);
    *(bf162*)(out0 + (long)w * HID + lane * 2) = mk2(fmaxf(p00 * inv0, 0.f), fmaxf(p01 * inv0, 0.f));
    *(bf162*)(out2 + (long)w * HID + lane * 2) = mk2(fmaxf(p20 * inv2, 0.f), fmaxf(p21 * inv2, 0.f));
}

// single gather (author dest, layer 0 only), 8-deep batching, bf16 out
__global__ __launch_bounds__(256) void edge_gather_kernel(
    const int* __restrict__ roff, const unsigned short* __restrict__ csrc,
    const float* __restrict__ as_, const float* __restrict__ ad_,
    const bf16* __restrict__ xh, bf16* __restrict__ out, int Ndst)
{
    int w = blockIdx.x * 4 + (threadIdx.x >> 6);
    int lane = threadIdx.x & 63;
    if (w >= Ndst) return;
    int h = lane >> 3;
    int beg = roff[w], n = roff[w + 1] - beg;
    float ad = ad_[(long)w * 8 + h];
    float den = 0.f, acc0 = 0.f, acc1 = 0.f;
    int cm = n > 0 ? n - 1 : 0;
    for (int i = 0; i < n; i += 8) {
        int s[8];
        #pragma unroll
        for (int u = 0; u < 8; u++) s[u] = csrc[beg + min(i + u, cm)];
        float av[8]; bf162 xv[8];
        #pragma unroll
        for (int u = 0; u < 8; u++) {
            av[u] = as_[(long)s[u] * 8 + h];
            xv[u] = *(const bf162*)(xh + (long)s[u] * HID + lane * 2);
        }
        #pragma unroll
        for (int u = 0; u < 8; u++) {
            float a = av[u] + ad;
            a = a >= 0.f ? a : 0.2f * a;
            float wt = __expf(fminf(a, 60.f));
            wt = (i + u < n) ? wt : 0.f;
            den += wt;
            acc0 = fmaf(__bfloat162float(xv[u].x), wt, acc0);
            acc1 = fmaf(__bfloat162float(xv[u].y), wt, acc1);
        }
    }
    float inv = 1.f / (den + 1e-16f);
    *(bf162*)(out + (long)w * HID + lane * 2) = mk2(fmaxf(acc0 * inv, 0.f), fmaxf(acc1 * inv, 0.f));
}

// semantic combine: bf16 in, bf16 out, 2 elems/thread
__global__ void combine_kernel(const bf16* __restrict__ a0, const bf16* __restrict__ a1,
                               const float* __restrict__ score, bf16* __restrict__ out, int n2)
{
    int i = blockIdx.x * blockDim.x + threadIdx.x;
    if (i >= n2) return;
    float s0 = score[0] * (1.f / N_PAPER);
    float s1 = score[1] * (1.f / N_PAPER);
    float m = fmaxf(s0, s1);
    float e0 = __expf(s0 - m), e1 = __expf(s1 - m);
    float inv = 1.f / (e0 + e1);
    float w0 = e0 * inv, w1 = e1 * inv;
    bf162 v0 = ((const bf162*)a0)[i];
    bf162 v1 = ((const bf162*)a1)[i];
    ((bf162*)out)[i] = mk2(w0 * __bfloat162float(v0.x) + w1 * __bfloat162float(v1.x),
                           w0 * __bfloat162float(v0.y) + w1 * __bfloat162float(v1.y));
}

// final linear fused with last-layer semantic combine; bf16 activations
__global__ __launch_bounds__(256) void final_lin_fused_kernel(
    const bf16* __restrict__ a0, const bf16* __restrict__ a1,
    const float* __restrict__ score,
    const float* __restrict__ W, const float* __restrict__ B, float* __restrict__ out)
{
    __shared__ float Ws[HID * NCLS];
    int tid = threadIdx.x;
    for (int i = tid; i < HID * NCLS; i += 256) Ws[i] = W[i];
    __syncthreads();
    float s0 = score[0] * (1.f / N_PAPER);
    float s1 = score[1] * (1.f / N_PAPER);
    float m = fmaxf(s0, s1);
    float e0 = __expf(s0 - m), e1 = __expf(s1 - m);
    float inv = 1.f / (e0 + e1);
    float w0 = e0 * inv, w1 = e1 * inv;
    int i = blockIdx.x * 256 + tid;
    if (i >= N_PAPER * NCLS) return;
    int n = i >> 4, c = i & 15;
    float acc = B[c];
    const bf16* x0 = a0 + (long)n * HID;
    const bf16* x1 = a1 + (long)n * HID;
    #pragma unroll 16
    for (int k = 0; k < HID; k++)
        acc = fmaf(fmaf(w0, __bfloat162float(x0[k]), w1 * __bfloat162float(x1[k])),
                   Ws[k * NCLS + c], acc);
    out[i] = acc;
}

extern "C" void kernel_launch(void* const* d_in, const int* in_sizes, int n_in,
                              void* d_out, int out_size, void* d_ws, size_t ws_size,
                              hipStream_t stream)
{
    const float* x_author = (const float*)d_in[0];
    const float* x_paper  = (const float*)d_in[1];
    const float* Wa       = (const float*)d_in[2];
    const float* proj_w   = (const float*)d_in[3];
    const float* proj_b   = (const float*)d_in[4];
    const float* att_src  = (const float*)d_in[5];
    const float* att_dst  = (const float*)d_in[6];
    const float* klin_w   = (const float*)d_in[7];
    const float* klin_b   = (const float*)d_in[8];
    const float* qv       = (const float*)d_in[9];
    const float* lin_w    = (const float*)d_in[10];
    const float* lin_b    = (const float*)d_in[11];
    const int*  ei_w      = (const int*)d_in[12];
    const int*  ei_wb     = (const int*)d_in[13];
    const int*  ei_c      = (const int*)d_in[14];
    float* out = (float*)d_out;
    (void)ws_size; (void)in_sizes; (void)n_in; (void)out_size;

    char* base = (char*)d_ws;
    size_t off = 0;
    auto alloc = [&](size_t bytes) {
        void* p = base + off;
        off = (off + bytes + 255) & ~(size_t)255;
        return p;
    };
    bf16*  xh_a  = (bf16*) alloc((size_t)N_AUTHOR * HID * 2);
    bf16*  xh_p  = (bf16*) alloc((size_t)N_PAPER  * HID * 2);
    bf16*  buf_a = (bf16*) alloc((size_t)N_AUTHOR * HID * 2);
    bf16*  buf_p = (bf16*) alloc((size_t)N_PAPER  * HID * 2);
    bf16*  agg_p1= (bf16*) alloc((size_t)N_PAPER  * HID * 2);
    bf16*  xa    = (bf16*) alloc((size_t)N_AUTHOR * 64  * 2);
    bf16*  xp    = (bf16*) alloc((size_t)N_PAPER  * HID * 2);
    bf16*  wt_wa   = (bf16*)alloc((size_t)R_WA * 2);
    bf16*  wt_proj = (bf16*)alloc((size_t)R_PW * 2);
    bf16*  wt_klin = (bf16*)alloc((size_t)R_KW * 2);
    float* a_e0s = (float*)alloc((size_t)N_AUTHOR * HEADS * 4);
    float* a_e0d = (float*)alloc((size_t)N_PAPER  * HEADS * 4);
    float* a_e1s = (float*)alloc((size_t)N_PAPER  * HEADS * 4);
    float* a_e1d = (float*)alloc((size_t)N_AUTHOR * HEADS * 4);
    float* a_e2s = (float*)alloc((size_t)N_PAPER  * HEADS * 4);
    float* a_e2d = (float*)alloc((size_t)N_PAPER  * HEADS * 4);
    float* score  = (float*)alloc(64);
    int* roff0 = (int*)alloc((size_t)(N_PAPER  + 1) * 4);
    int* roff1 = (int*)alloc((size_t)(N_AUTHOR + 1) * 4);
    int* roff2 = (int*)alloc((size_t)(N_PAPER  + 1) * 4);
    unsigned short* csrc0 = (unsigned short*)alloc((size_t)NEDGE * 2 + 64);
    unsigned short* csrc1 = (unsigned short*)alloc((size_t)NEDGE * 2 + 64);
    unsigned short* csrc2 = (unsigned short*)alloc((size_t)NEDGE * 2 + 64);
    int* cnt   = (int*)alloc((size_t)(2 * N_PAPER + N_AUTHOR) * 4);
    unsigned short* rank = (unsigned short*)alloc((size_t)(3 * NEDGE) * 2);
    int* bsum  = (int*)alloc(3 * 256 * 4);

    const int GA = (N_AUTHOR + 63) / 64;   // 313
    const int GP = (N_PAPER  + 63) / 64;   // 625
    const int G3E = (3 * NEDGE + 255) / 256;
    const int NBMAX = (N_PAPER + 255) / 256;   // 157

    // ---- one-time conversions ----
    conv_weights_kernel<<<(R_WA + R_PW + R_KW + 255)/256, 256, 0, stream>>>(
        Wa, proj_w, klin_w, wt_wa, wt_proj, wt_klin);
    conv_x_kernel<<<((NXA + NXP)/4 + 255)/256, 256, 0, stream>>>(x_author, x_paper, xa, xp);

    // ---- batched CSR build ----
    hipMemsetAsync(cnt, 0, (size_t)(2 * N_PAPER + N_AUTHOR) * 4, stream);
    hist3_kernel<<<G3E, 256, 0, stream>>>(ei_w + NEDGE, ei_wb + NEDGE, ei_c + NEDGE, cnt, rank);
    scan_a3_kernel<<<dim3(NBMAX, 3), 256, 0, stream>>>(cnt, bsum);
    scan_b3_kernel<<<3, 256, 0, stream>>>(bsum, roff0, roff1, roff2);
    scan_c3_kernel<<<dim3(NBMAX, 3), 256, 0, stream>>>(cnt, bsum, roff0, roff1, roff2);
    fill3_kernel<<<G3E, 256, 0, stream>>>(
        ei_w, ei_w + NEDGE, ei_wb, ei_wb + NEDGE, ei_c, ei_c + NEDGE,
        roff0, roff1, roff2, rank, csrc0, csrc1, csrc2);

    // author input projection 64 -> 128 (bf16 out)
    bgemm_kernel<64, 0><<<GA, 256, 0, stream>>>(
        xa, wt_wa, nullptr, buf_a, nullptr, nullptr, N_AUTHOR);

    for (int l = 0; l < 2; l++) {
        const bool last = (l == 1);
        const bf16* cur_a = buf_a;
        const bf16* cur_p = (l == 0) ? xp : buf_p;
        const bf16* pw_a = wt_proj + (size_t)(l*2 + 0) * HID * HID;
        const bf16* pw_p = wt_proj + (size_t)(l*2 + 1) * HID * HID;
        const float* pb_a = proj_b + (size_t)(l*2 + 0) * HID;
        const float* pb_p = proj_b + (size_t)(l*2 + 1) * HID;

        bgemm_pair_kernel<128, 0><<<GA + GP, 256, 0, stream>>>(
            cur_a, pw_a, pb_a, xh_a, nullptr, N_AUTHOR, GA,
            cur_p, pw_p, pb_p, xh_p, nullptr, N_PAPER, nullptr);

        hipMemsetAsync(score, 0, 64, stream);

        const float* as0 = att_src + (size_t)(l*3 + 0) * HID;
        const float* ad0 = att_dst + (size_t)(l*3 + 0) * HID;
        const float* as1 = att_src + (size_t)(l*3 + 1) * HID;
        const float* ad1 = att_dst + (size_t)(l*3 + 1) * HID;
        const float* as2 = att_src + (size_t)(l*3 + 2) * HID;
        const float* ad2 = att_dst + (size_t)(l*3 + 2) * HID;

        node_att_multi_kernel<<<(N_AUTHOR*HEADS + 255)/256, 256, 0, stream>>>(
            xh_a, as0, last ? nullptr : ad1, nullptr, nullptr,
            a_e0s, a_e1d, nullptr, nullptr, N_AUTHOR);
        node_att_multi_kernel<<<(N_PAPER*HEADS + 255)/256, 256, 0, stream>>>(
            xh_p, ad0, last ? nullptr : as1, as2, ad2,
            a_e0d, a_e1s, a_e2s, a_e2d, N_PAPER);

        paper_gather2_kernel<<<(N_PAPER + 3)/4, 256, 0, stream>>>(
            roff0, csrc0, a_e0s, a_e0d, xh_a,
            roff2, csrc2, a_e2s, a_e2d, xh_p,
            buf_p, agg_p1);
        if (!last)
            edge_gather_kernel<<<(N_AUTHOR + 3)/4, 256, 0, stream>>>(
                roff1, csrc1, a_e1s, a_e1d, xh_p, buf_a, N_AUTHOR);

        const bf16* kw = wt_klin + (size_t)l * HID * HID;
        const float* kb = klin_b + (size_t)l * HID;
        const float* qq = qv     + (size_t)l * HID;
        bgemm_pair_kernel<128, 1><<<2 * GP, 256, 0, stream>>>(
            buf_p, kw, kb, (bf16*)nullptr, score + 0, N_PAPER, GP,
            agg_p1, kw, kb, (bf16*)nullptr, score + 1, N_PAPER, qq);

        if (!last)
            combine_kernel<<<(N_PAPER*HID/2 + 255)/256, 256, 0, stream>>>(
                buf_p, agg_p1, score, buf_p, N_PAPER*HID/2);
    }

    final_lin_fused_kernel<<<(N_PAPER*NCLS + 255)/256, 256, 0, stream>>>(
        buf_p, agg_p1, score, lin_w, lin_b, out);
}

// Round 12
// 451.246 us; speedup vs baseline: 6.8078x; 1.0653x over previous
//
#include <hip/hip_runtime.h>
#include <hip/hip_bf16.h>

typedef __hip_bfloat16 bf16;
typedef __hip_bfloat162 bf162;

#define N_AUTHOR 20000
#define N_PAPER  40000
#define NEDGE    400000
#define HID      128
#define HEADS    8
#define DIMH     16
#define NCLS     16

typedef short short4v __attribute__((ext_vector_type(4)));
typedef short short8v __attribute__((ext_vector_type(8)));
typedef float f32x4   __attribute__((ext_vector_type(4)));

__device__ __forceinline__ bf162 mk2(float a, float b){
    bf162 r; r.x = __float2bfloat16(a); r.y = __float2bfloat16(b); return r;
}
// bf16 bits -> float (1 shift)
__device__ __forceinline__ float b2f(short s){
    return __uint_as_float(((unsigned)(unsigned short)s) << 16);
}
// float -> bf16 bits (RNE)
__device__ __forceinline__ short f2bs(float v){
    unsigned u = __float_as_uint(v);
    unsigned r = (u + 0x7FFFu + ((u >> 16) & 1u)) >> 16;
    return (short)r;
}
__device__ __forceinline__ float fastrcp(float x){ return __builtin_amdgcn_rcpf(x); }

// fast tanh: 1 - 2*rcp(e^{2x}+1); |err| ~1e-6
__device__ __forceinline__ float fast_tanh(float x){
    x = fminf(fmaxf(x, -15.f), 15.f);
    float e = __expf(2.f * x);
    return 1.f - 2.f * fastrcp(e + 1.f);
}

// ---------------------------------------------------------------------------
// LDS-free bf16 MFMA GEMM body, kc-outer loop interchange:
// per kc: 8 independent B-loads in flight, then 8 MFMAs (serial depth 4).
// A bf16 [M][KDIM]; Wt bf16 TRANSPOSED [128][KDIM].
// ---------------------------------------------------------------------------
template<int KDIM, int EPI>
__device__ __forceinline__ void bgemm_body(
    const bf16* __restrict__ A, const bf16* __restrict__ Wt, const float* __restrict__ Bb,
    bf16* __restrict__ C, const float* __restrict__ qv, float* __restrict__ score,
    int M, int brow, float* red)
{
    const int tid  = threadIdx.x;
    const int lane = tid & 63;
    const int wv   = tid >> 6;
    const int lr   = lane & 15;
    const int quad = lane >> 4;
    const int row0 = brow * 64 + wv * 16;
    const int arow_i = row0 + lr;
    const bool rowok = arow_i < M;
    const bf16* arow = A + (long)arow_i * KDIM;

    short8v afrag[KDIM / 32];
    #pragma unroll
    for (int kc = 0; kc < KDIM / 32; kc++) {
        short8v f = {0,0,0,0,0,0,0,0};
        if (rowok) f = *(const short8v*)(arow + kc * 32 + quad * 8);
        afrag[kc] = f;
    }

    f32x4 acc[8];
    #pragma unroll
    for (int ct = 0; ct < 8; ct++) acc[ct] = (f32x4){0.f, 0.f, 0.f, 0.f};

    #pragma unroll
    for (int kc = 0; kc < KDIM / 32; kc++) {
        short8v bfrag[8];
        #pragma unroll
        for (int ct = 0; ct < 8; ct++)
            bfrag[ct] = *(const short8v*)(Wt + (long)(ct * 16 + lr) * KDIM + kc * 32 + quad * 8);
        #pragma unroll
        for (int ct = 0; ct < 8; ct++)
            acc[ct] = __builtin_amdgcn_mfma_f32_16x16x32_bf16(afrag[kc], bfrag[ct], acc[ct], 0, 0, 0);
    }

    // D mapping: row = row0 + quad*4 + r, col = ct*16 + lr
    if (EPI == 0) {
        #pragma unroll
        for (int ct = 0; ct < 8; ct++) {
            float bc = Bb ? Bb[ct * 16 + lr] : 0.f;
            #pragma unroll
            for (int r = 0; r < 4; r++) {
                int orow = row0 + quad * 4 + r;
                if (orow < M)
                    C[(long)orow * HID + ct * 16 + lr] = __float2bfloat16(acc[ct][r] + bc);
            }
        }
    } else {
        float part = 0.f;
        #pragma unroll
        for (int ct = 0; ct < 8; ct++) {
            float bc = Bb ? Bb[ct * 16 + lr] : 0.f;
            float qc = qv[ct * 16 + lr];
            #pragma unroll
            for (int r = 0; r < 4; r++) {
                int orow = row0 + quad * 4 + r;
                if (orow < M) part += qc * fast_tanh(acc[ct][r] + bc);
            }
        }
        red[tid] = part;
        __syncthreads();
        for (int s = 128; s > 0; s >>= 1) {
            if (tid < s) red[tid] += red[tid + s];
            __syncthreads();
        }
        if (tid == 0) atomicAdd(score, red[0]);
    }
}

template<int KDIM, int EPI>
__global__ __launch_bounds__(256) void bgemm_kernel(
    const bf16* __restrict__ A, const bf16* __restrict__ Wt, const float* __restrict__ Bb,
    bf16* __restrict__ C, const float* __restrict__ qv, float* __restrict__ score, int M)
{
    __shared__ float red[256];
    bgemm_body<KDIM, EPI>(A, Wt, Bb, C, qv, score, M, blockIdx.x, red);
}

template<int KDIM, int EPI>
__global__ __launch_bounds__(256) void bgemm_pair_kernel(
    const bf16* __restrict__ A0, const bf16* __restrict__ Wt0, const float* __restrict__ Bb0,
    bf16* __restrict__ C0, float* __restrict__ score0, int M0, int NB0,
    const bf16* __restrict__ A1, const bf16* __restrict__ Wt1, const float* __restrict__ Bb1,
    bf16* __restrict__ C1, float* __restrict__ score1, int M1,
    const float* __restrict__ qv)
{
    __shared__ float red[256];
    const int bx = blockIdx.x;
    if (bx < NB0)
        bgemm_body<KDIM, EPI>(A0, Wt0, Bb0, C0, qv, score0, M0, bx, red);
    else
        bgemm_body<KDIM, EPI>(A1, Wt1, Bb1, C1, qv, score1, M1, bx - NB0, red);
}

// ---------------------------------------------------------------------------
// one-time conversions
// ---------------------------------------------------------------------------
#define R_WA  (128 * 64)
#define R_PW  (4 * 128 * 128)
#define R_KW  (2 * 128 * 128)

__global__ void conv_weights_kernel(const float* __restrict__ Wa,
                                    const float* __restrict__ proj_w,
                                    const float* __restrict__ klin_w,
                                    bf16* __restrict__ wt_wa,
                                    bf16* __restrict__ wt_proj,
                                    bf16* __restrict__ wt_klin)
{
    int i = blockIdx.x * blockDim.x + threadIdx.x;
    if (i < R_WA) {
        int n = i >> 6, k = i & 63;
        wt_wa[i] = __float2bfloat16(Wa[k * 128 + n]);
    } else if (i < R_WA + R_PW) {
        int j = i - R_WA;
        int m = j >> 14, r = j & 16383;
        int n = r >> 7, k = r & 127;
        wt_proj[j] = __float2bfloat16(proj_w[m * 16384 + k * 128 + n]);
    } else if (i < R_WA + R_PW + R_KW) {
        int j = i - R_WA - R_PW;
        int m = j >> 14, r = j & 16383;
        int n = r >> 7, k = r & 127;
        wt_klin[j] = __float2bfloat16(klin_w[m * 16384 + k * 128 + n]);
    }
}

#define NXA (N_AUTHOR * 64)
#define NXP (N_PAPER * HID)

__global__ void conv_x_kernel(const float* __restrict__ xa_f, const float* __restrict__ xp_f,
                              bf16* __restrict__ xa, bf16* __restrict__ xp)
{
    int i4 = blockIdx.x * blockDim.x + threadIdx.x;
    int i = i4 * 4;
    if (i < NXA) {
        float4 v = *(const float4*)(xa_f + i);
        xa[i]   = __float2bfloat16(v.x); xa[i+1] = __float2bfloat16(v.y);
        xa[i+2] = __float2bfloat16(v.z); xa[i+3] = __float2bfloat16(v.w);
    } else if (i < NXA + NXP) {
        int j = i - NXA;
        float4 v = *(const float4*)(xp_f + j);
        xp[j]   = __float2bfloat16(v.x); xp[j+1] = __float2bfloat16(v.y);
        xp[j+2] = __float2bfloat16(v.z); xp[j+3] = __float2bfloat16(v.w);
    }
}

// multi-output node attention dots
__global__ void node_att_multi_kernel(const bf16* __restrict__ xh,
    const float* __restrict__ A0, const float* __restrict__ A1,
    const float* __restrict__ A2, const float* __restrict__ A3,
    float* __restrict__ O0, float* __restrict__ O1,
    float* __restrict__ O2, float* __restrict__ O3, int N)
{
    int i = blockIdx.x * blockDim.x + threadIdx.x;
    if (i >= N * HEADS) return;
    int n = i >> 3, h = i & 7;
    const bf16* row = xh + (long)n * HID + h * DIMH;
    float x[DIMH];
    #pragma unroll
    for (int d = 0; d < DIMH; d++) x[d] = __bfloat162float(row[d]);
    if (A0) { float s = 0.f;
        #pragma unroll
        for (int d = 0; d < DIMH; d++) s += x[d] * A0[h*DIMH + d];
        O0[i] = s; }
    if (A1) { float s = 0.f;
        #pragma unroll
        for (int d = 0; d < DIMH; d++) s += x[d] * A1[h*DIMH + d];
        O1[i] = s; }
    if (A2) { float s = 0.f;
        #pragma unroll
        for (int d = 0; d < DIMH; d++) s += x[d] * A2[h*DIMH + d];
        O2[i] = s; }
    if (A3) { float s = 0.f;
        #pragma unroll
        for (int d = 0; d < DIMH; d++) s += x[d] * A3[h*DIMH + d];
        O3[i] = s; }
}

// ---------------- batched CSR build ----------------
#define CNT_OFF1 N_PAPER
#define CNT_OFF2 (N_PAPER + N_AUTHOR)

__global__ void hist3_kernel(const int* __restrict__ d0, const int* __restrict__ d1,
                             const int* __restrict__ d2, int* __restrict__ cnt,
                             unsigned short* __restrict__ rank)
{
    int i = blockIdx.x * blockDim.x + threadIdx.x;
    if (i < NEDGE)               rank[i] = (unsigned short)atomicAdd(&cnt[d0[i]], 1);
    else if (i < 2*NEDGE)        rank[i] = (unsigned short)atomicAdd(&cnt[CNT_OFF1 + d1[i - NEDGE]], 1);
    else if (i < 3*NEDGE)        rank[i] = (unsigned short)atomicAdd(&cnt[CNT_OFF2 + d2[i - 2*NEDGE]], 1);
}

__device__ __forceinline__ int job_nd(int j){ return j == 1 ? N_AUTHOR : N_PAPER; }
__device__ __forceinline__ int job_off(int j){ return j == 0 ? 0 : (j == 1 ? CNT_OFF1 : CNT_OFF2); }

__global__ __launch_bounds__(256) void scan_a3_kernel(const int* __restrict__ cnt,
                                                      int* __restrict__ bsum)
{
    int j = blockIdx.y;
    int nd = job_nd(j), off = job_off(j);
    __shared__ int s[256];
    int tid = threadIdx.x;
    int i = blockIdx.x * 256 + tid;
    s[tid] = (i < nd) ? cnt[off + i] : 0;
    __syncthreads();
    for (int st = 128; st > 0; st >>= 1) {
        if (tid < st) s[tid] += s[tid + st];
        __syncthreads();
    }
    if (tid == 0) bsum[j * 256 + blockIdx.x] = s[0];
}

__global__ __launch_bounds__(256) void scan_b3_kernel(int* __restrict__ bsum,
    int* __restrict__ roff0, int* __restrict__ roff1, int* __restrict__ roff2)
{
    int j = blockIdx.x;
    int nd = job_nd(j);
    int nb = (nd + 255) / 256;
    int* roff = j == 0 ? roff0 : (j == 1 ? roff1 : roff2);
    __shared__ int s[256];
    int tid = threadIdx.x;
    int v = (tid < nb) ? bsum[j * 256 + tid] : 0;
    s[tid] = v;
    __syncthreads();
    for (int off = 1; off < 256; off <<= 1) {
        int t = (tid >= off) ? s[tid - off] : 0;
        __syncthreads();
        s[tid] += t;
        __syncthreads();
    }
    if (tid < nb) bsum[j * 256 + tid] = s[tid] - v;
    if (tid == 255) roff[nd] = s[255];
}

__global__ __launch_bounds__(256) void scan_c3_kernel(const int* __restrict__ cnt,
    const int* __restrict__ bsum,
    int* __restrict__ roff0, int* __restrict__ roff1, int* __restrict__ roff2)
{
    int j = blockIdx.y;
    int nd = job_nd(j), off = job_off(j);
    int* roff = j == 0 ? roff0 : (j == 1 ? roff1 : roff2);
    __shared__ int s[256];
    int tid = threadIdx.x;
    int i = blockIdx.x * 256 + tid;
    int v = (i < nd) ? cnt[off + i] : 0;
    s[tid] = v;
    __syncthreads();
    for (int o = 1; o < 256; o <<= 1) {
        int t = (tid >= o) ? s[tid - o] : 0;
        __syncthreads();
        s[tid] += t;
        __syncthreads();
    }
    if (i < nd) roff[i] = bsum[j * 256 + blockIdx.x] + s[tid] - v;
}

__global__ void fill3_kernel(
    const int* __restrict__ s0, const int* __restrict__ d0,
    const int* __restrict__ s1, const int* __restrict__ d1,
    const int* __restrict__ s2, const int* __restrict__ d2,
    const int* __restrict__ roff0, const int* __restrict__ roff1, const int* __restrict__ roff2,
    const unsigned short* __restrict__ rank,
    unsigned short* __restrict__ c0, unsigned short* __restrict__ c1, unsigned short* __restrict__ c2)
{
    int i = blockIdx.x * blockDim.x + threadIdx.x;
    if (i < NEDGE) {
        int d = d0[i];
        c0[roff0[d] + rank[i]] = (unsigned short)s0[i];
    } else if (i < 2*NEDGE) {
        int e = i - NEDGE, d = d1[e];
        c1[roff1[d] + rank[i]] = (unsigned short)s1[e];
    } else if (i < 3*NEDGE) {
        int e = i - 2*NEDGE, d = d2[e];
        c2[roff2[d] + rank[i]] = (unsigned short)s2[e];
    }
}

// ---------------------------------------------------------------------------
// Fused paper gather: 16 lanes per dest (4 dests/wave), lane owns 8 features
// (one 16B load/edge). Weight chain computed 2x per head (was 8x). 4-deep batch.
// ---------------------------------------------------------------------------
__global__ __launch_bounds__(256) void paper_gather2_kernel(
    const int* __restrict__ roff0, const unsigned short* __restrict__ csrc0,
    const float* __restrict__ as0, const float* __restrict__ ad0,
    const bf16* __restrict__ xha,
    const int* __restrict__ roff2, const unsigned short* __restrict__ csrc2,
    const float* __restrict__ as2, const float* __restrict__ ad2,
    const bf16* __restrict__ xhp,
    bf16* __restrict__ out0, bf16* __restrict__ out2)
{
    int lane = threadIdx.x & 63;
    int li   = lane & 15;                 // feature slot: features [li*8, li*8+8)
    int sub  = lane >> 4;                 // which of the wave's 4 dests
    int w = blockIdx.x * 16 + (threadIdx.x >> 6) * 4 + sub;
    if (w >= N_PAPER) return;
    int h = li >> 1;                      // head of this lane's features

    int b0 = roff0[w], n0 = roff0[w + 1] - b0;
    int b2 = roff2[w], n2 = roff2[w + 1] - b2;
    float ad0v = ad0[(long)w * 8 + h];
    float ad2v = ad2[(long)w * 8 + h];
    float den0 = 0.f, den2 = 0.f;
    float acc0[8], acc2[8];
    #pragma unroll
    for (int j = 0; j < 8; j++) { acc0[j] = 0.f; acc2[j] = 0.f; }

    int nmax = n0 > n2 ? n0 : n2;
    int c0m = n0 > 0 ? n0 - 1 : 0;
    int c2m = n2 > 0 ? n2 - 1 : 0;
    for (int i = 0; i < nmax; i += 4) {
        int sA[4], sB[4];
        #pragma unroll
        for (int u = 0; u < 4; u++) {
            sA[u] = csrc0[b0 + min(i + u, c0m)];
            sB[u] = csrc2[b2 + min(i + u, c2m)];
        }
        float aA[4], aB[4];
        short8v xA[4], xB[4];
        #pragma unroll
        for (int u = 0; u < 4; u++) {
            aA[u] = as0[(long)sA[u] * 8 + h];
            xA[u] = *(const short8v*)(xha + (long)sA[u] * HID + li * 8);
            aB[u] = as2[(long)sB[u] * 8 + h];
            xB[u] = *(const short8v*)(xhp + (long)sB[u] * HID + li * 8);
        }
        #pragma unroll
        for (int u = 0; u < 4; u++) {
            float a = aA[u] + ad0v;
            a = a >= 0.f ? a : 0.2f * a;
            float wt = __expf(fminf(a, 60.f));
            wt = (i + u < n0) ? wt : 0.f;
            den0 += wt;
            #pragma unroll
            for (int j = 0; j < 8; j++)
                acc0[j] = fmaf(b2f(xA[u][j]), wt, acc0[j]);
            a = aB[u] + ad2v;
            a = a >= 0.f ? a : 0.2f * a;
            wt = __expf(fminf(a, 60.f));
            wt = (i + u < n2) ? wt : 0.f;
            den2 += wt;
            #pragma unroll
            for (int j = 0; j < 8; j++)
                acc2[j] = fmaf(b2f(xB[u][j]), wt, acc2[j]);
        }
    }
    float inv0 = fastrcp(den0 + 1e-16f);
    float inv2 = fastrcp(den2 + 1e-16f);
    short8v o0, o2;
    #pragma unroll
    for (int j = 0; j < 8; j++) {
        o0[j] = f2bs(fmaxf(acc0[j] * inv0, 0.f));
        o2[j] = f2bs(fmaxf(acc2[j] * inv2, 0.f));
    }
    *(short8v*)(out0 + (long)w * HID + li * 8) = o0;
    *(short8v*)(out2 + (long)w * HID + li * 8) = o2;
}

// single gather (author dest, layer 0 only), same 16-lane/dest layout
__global__ __launch_bounds__(256) void edge_gather_kernel(
    const int* __restrict__ roff, const unsigned short* __restrict__ csrc,
    const float* __restrict__ as_, const float* __restrict__ ad_,
    const bf16* __restrict__ xh, bf16* __restrict__ out, int Ndst)
{
    int lane = threadIdx.x & 63;
    int li   = lane & 15;
    int sub  = lane >> 4;
    int w = blockIdx.x * 16 + (threadIdx.x >> 6) * 4 + sub;
    if (w >= Ndst) return;
    int h = li >> 1;
    int beg = roff[w], n = roff[w + 1] - beg;
    float adv = ad_[(long)w * 8 + h];
    float den = 0.f;
    float acc[8];
    #pragma unroll
    for (int j = 0; j < 8; j++) acc[j] = 0.f;
    int cm = n > 0 ? n - 1 : 0;
    for (int i = 0; i < n; i += 4) {
        int s[4];
        #pragma unroll
        for (int u = 0; u < 4; u++) s[u] = csrc[beg + min(i + u, cm)];
        float av[4]; short8v xv[4];
        #pragma unroll
        for (int u = 0; u < 4; u++) {
            av[u] = as_[(long)s[u] * 8 + h];
            xv[u] = *(const short8v*)(xh + (long)s[u] * HID + li * 8);
        }
        #pragma unroll
        for (int u = 0; u < 4; u++) {
            float a = av[u] + adv;
            a = a >= 0.f ? a : 0.2f * a;
            float wt = __expf(fminf(a, 60.f));
            wt = (i + u < n) ? wt : 0.f;
            den += wt;
            #pragma unroll
            for (int j = 0; j < 8; j++)
                acc[j] = fmaf(b2f(xv[u][j]), wt, acc[j]);
        }
    }
    float inv = fastrcp(den + 1e-16f);
    short8v o;
    #pragma unroll
    for (int j = 0; j < 8; j++) o[j] = f2bs(fmaxf(acc[j] * inv, 0.f));
    *(short8v*)(out + (long)w * HID + li * 8) = o;
}

// semantic combine: bf16 in, bf16 out
__global__ void combine_kernel(const bf16* __restrict__ a0, const bf16* __restrict__ a1,
                               const float* __restrict__ score, bf16* __restrict__ out, int n2)
{
    int i = blockIdx.x * blockDim.x + threadIdx.x;
    if (i >= n2) return;
    float s0 = score[0] * (1.f / N_PAPER);
    float s1 = score[1] * (1.f / N_PAPER);
    float m = fmaxf(s0, s1);
    float e0 = __expf(s0 - m), e1 = __expf(s1 - m);
    float inv = fastrcp(e0 + e1);
    float w0 = e0 * inv, w1 = e1 * inv;
    bf162 v0 = ((const bf162*)a0)[i];
    bf162 v1 = ((const bf162*)a1)[i];
    ((bf162*)out)[i] = mk2(w0 * __bfloat162float(v0.x) + w1 * __bfloat162float(v1.x),
                           w0 * __bfloat162float(v0.y) + w1 * __bfloat162float(v1.y));
}

// final linear fused with last-layer semantic combine
__global__ __launch_bounds__(256) void final_lin_fused_kernel(
    const bf16* __restrict__ a0, const bf16* __restrict__ a1,
    const float* __restrict__ score,
    const float* __restrict__ W, const float* __restrict__ B, float* __restrict__ out)
{
    __shared__ float Ws[HID * NCLS];
    int tid = threadIdx.x;
    for (int i = tid; i < HID * NCLS; i += 256) Ws[i] = W[i];
    __syncthreads();
    float s0 = score[0] * (1.f / N_PAPER);
    float s1 = score[1] * (1.f / N_PAPER);
    float m = fmaxf(s0, s1);
    float e0 = __expf(s0 - m), e1 = __expf(s1 - m);
    float inv = 1.f / (e0 + e1);
    float w0 = e0 * inv, w1 = e1 * inv;
    int i = blockIdx.x * 256 + tid;
    if (i >= N_PAPER * NCLS) return;
    int n = i >> 4, c = i & 15;
    float acc = B[c];
    const bf16* x0 = a0 + (long)n * HID;
    const bf16* x1 = a1 + (long)n * HID;
    #pragma unroll 16
    for (int k = 0; k < HID; k++)
        acc = fmaf(fmaf(w0, __bfloat162float(x0[k]), w1 * __bfloat162float(x1[k])),
                   Ws[k * NCLS + c], acc);
    out[i] = acc;
}

extern "C" void kernel_launch(void* const* d_in, const int* in_sizes, int n_in,
                              void* d_out, int out_size, void* d_ws, size_t ws_size,
                              hipStream_t stream)
{
    const float* x_author = (const float*)d_in[0];
    const float* x_paper  = (const float*)d_in[1];
    const float* Wa       = (const float*)d_in[2];
    const float* proj_w   = (const float*)d_in[3];
    const float* proj_b   = (const float*)d_in[4];
    const float* att_src  = (const float*)d_in[5];
    const float* att_dst  = (const float*)d_in[6];
    const float* klin_w   = (const float*)d_in[7];
    const float* klin_b   = (const float*)d_in[8];
    const float* qv       = (const float*)d_in[9];
    const float* lin_w    = (const float*)d_in[10];
    const float* lin_b    = (const float*)d_in[11];
    const int*  ei_w      = (const int*)d_in[12];
    const int*  ei_wb     = (const int*)d_in[13];
    const int*  ei_c      = (const int*)d_in[14];
    float* out = (float*)d_out;
    (void)ws_size; (void)in_sizes; (void)n_in; (void)out_size;

    char* base = (char*)d_ws;
    size_t off = 0;
    auto alloc = [&](size_t bytes) {
        void* p = base + off;
        off = (off + bytes + 255) & ~(size_t)255;
        return p;
    };
    bf16*  xh_a  = (bf16*) alloc((size_t)N_AUTHOR * HID * 2);
    bf16*  xh_p  = (bf16*) alloc((size_t)N_PAPER  * HID * 2);
    bf16*  buf_a = (bf16*) alloc((size_t)N_AUTHOR * HID * 2);
    bf16*  buf_p = (bf16*) alloc((size_t)N_PAPER  * HID * 2);
    bf16*  agg_p1= (bf16*) alloc((size_t)N_PAPER  * HID * 2);
    bf16*  xa    = (bf16*) alloc((size_t)N_AUTHOR * 64  * 2);
    bf16*  xp    = (bf16*) alloc((size_t)N_PAPER  * HID * 2);
    bf16*  wt_wa   = (bf16*)alloc((size_t)R_WA * 2);
    bf16*  wt_proj = (bf16*)alloc((size_t)R_PW * 2);
    bf16*  wt_klin = (bf16*)alloc((size_t)R_KW * 2);
    float* a_e0s = (float*)alloc((size_t)N_AUTHOR * HEADS * 4);
    float* a_e0d = (float*)alloc((size_t)N_PAPER  * HEADS * 4);
    float* a_e1s = (float*)alloc((size_t)N_PAPER  * HEADS * 4);
    float* a_e1d = (float*)alloc((size_t)N_AUTHOR * HEADS * 4);
    float* a_e2s = (float*)alloc((size_t)N_PAPER  * HEADS * 4);
    float* a_e2d = (float*)alloc((size_t)N_PAPER  * HEADS * 4);
    float* score  = (float*)alloc(64);
    int* roff0 = (int*)alloc((size_t)(N_PAPER  + 1) * 4);
    int* roff1 = (int*)alloc((size_t)(N_AUTHOR + 1) * 4);
    int* roff2 = (int*)alloc((size_t)(N_PAPER  + 1) * 4);
    unsigned short* csrc0 = (unsigned short*)alloc((size_t)NEDGE * 2 + 64);
    unsigned short* csrc1 = (unsigned short*)alloc((size_t)NEDGE * 2 + 64);
    unsigned short* csrc2 = (unsigned short*)alloc((size_t)NEDGE * 2 + 64);
    int* cnt   = (int*)alloc((size_t)(2 * N_PAPER + N_AUTHOR) * 4);
    unsigned short* rank = (unsigned short*)alloc((size_t)(3 * NEDGE) * 2);
    int* bsum  = (int*)alloc(3 * 256 * 4);

    const int GA = (N_AUTHOR + 63) / 64;   // 313
    const int GP = (N_PAPER  + 63) / 64;   // 625
    const int G3E = (3 * NEDGE + 255) / 256;
    const int NBMAX = (N_PAPER + 255) / 256;   // 157

    // ---- one-time conversions ----
    conv_weights_kernel<<<(R_WA + R_PW + R_KW + 255)/256, 256, 0, stream>>>(
        Wa, proj_w, klin_w, wt_wa, wt_proj, wt_klin);
    conv_x_kernel<<<((NXA + NXP)/4 + 255)/256, 256, 0, stream>>>(x_author, x_paper, xa, xp);

    // ---- batched CSR build ----
    hipMemsetAsync(cnt, 0, (size_t)(2 * N_PAPER + N_AUTHOR) * 4, stream);
    hist3_kernel<<<G3E, 256, 0, stream>>>(ei_w + NEDGE, ei_wb + NEDGE, ei_c + NEDGE, cnt, rank);
    scan_a3_kernel<<<dim3(NBMAX, 3), 256, 0, stream>>>(cnt, bsum);
    scan_b3_kernel<<<3, 256, 0, stream>>>(bsum, roff0, roff1, roff2);
    scan_c3_kernel<<<dim3(NBMAX, 3), 256, 0, stream>>>(cnt, bsum, roff0, roff1, roff2);
    fill3_kernel<<<G3E, 256, 0, stream>>>(
        ei_w, ei_w + NEDGE, ei_wb, ei_wb + NEDGE, ei_c, ei_c + NEDGE,
        roff0, roff1, roff2, rank, csrc0, csrc1, csrc2);

    // author input projection 64 -> 128 (bf16 out)
    bgemm_kernel<64, 0><<<GA, 256, 0, stream>>>(
        xa, wt_wa, nullptr, buf_a, nullptr, nullptr, N_AUTHOR);

    for (int l = 0; l < 2; l++) {
        const bool last = (l == 1);
        const bf16* cur_a = buf_a;
        const bf16* cur_p = (l == 0) ? xp : buf_p;
        const bf16* pw_a = wt_proj + (size_t)(l*2 + 0) * HID * HID;
        const bf16* pw_p = wt_proj + (size_t)(l*2 + 1) * HID * HID;
        const float* pb_a = proj_b + (size_t)(l*2 + 0) * HID;
        const float* pb_p = proj_b + (size_t)(l*2 + 1) * HID;

        bgemm_pair_kernel<128, 0><<<GA + GP, 256, 0, stream>>>(
            cur_a, pw_a, pb_a, xh_a, nullptr, N_AUTHOR, GA,
            cur_p, pw_p, pb_p, xh_p, nullptr, N_PAPER, nullptr);

        hipMemsetAsync(score, 0, 64, stream);

        const float* as0 = att_src + (size_t)(l*3 + 0) * HID;
        const float* ad0 = att_dst + (size_t)(l*3 + 0) * HID;
        const float* as1 = att_src + (size_t)(l*3 + 1) * HID;
        const float* ad1 = att_dst + (size_t)(l*3 + 1) * HID;
        const float* as2 = att_src + (size_t)(l*3 + 2) * HID;
        const float* ad2 = att_dst + (size_t)(l*3 + 2) * HID;

        node_att_multi_kernel<<<(N_AUTHOR*HEADS + 255)/256, 256, 0, stream>>>(
            xh_a, as0, last ? nullptr : ad1, nullptr, nullptr,
            a_e0s, a_e1d, nullptr, nullptr, N_AUTHOR);
        node_att_multi_kernel<<<(N_PAPER*HEADS + 255)/256, 256, 0, stream>>>(
            xh_p, ad0, last ? nullptr : as1, as2, ad2,
            a_e0d, a_e1s, a_e2s, a_e2d, N_PAPER);

        paper_gather2_kernel<<<(N_PAPER + 15)/16, 256, 0, stream>>>(
            roff0, csrc0, a_e0s, a_e0d, xh_a,
            roff2, csrc2, a_e2s, a_e2d, xh_p,
            buf_p, agg_p1);
        if (!last)
            edge_gather_kernel<<<(N_AUTHOR + 15)/16, 256, 0, stream>>>(
                roff1, csrc1, a_e1s, a_e1d, xh_p, buf_a, N_AUTHOR);

        const bf16* kw = wt_klin + (size_t)l * HID * HID;
        const float* kb = klin_b + (size_t)l * HID;
        const float* qq = qv     + (size_t)l * HID;
        bgemm_pair_kernel<128, 1><<<2 * GP, 256, 0, stream>>>(
            buf_p, kw, kb, (bf16*)nullptr, score + 0, N_PAPER, GP,
            agg_p1, kw, kb, (bf16*)nullptr, score + 1, N_PAPER, qq);

        if (!last)
            combine_kernel<<<(N_PAPER*HID/2 + 255)/256, 256, 0, stream>>>(
                buf_p, agg_p1, score, buf_p, N_PAPER*HID/2);
    }

    final_lin_fused_kernel<<<(N_PAPER*NCLS + 255)/256, 256, 0, stream>>>(
        buf_p, agg_p1, score, lin_w, lin_b, out);
}